// Round 2
// baseline (2382.558 us; speedup 1.0000x reference)
//
#include <hip/hip_runtime.h>
#include <float.h>

typedef __bf16 bf16;
typedef __attribute__((ext_vector_type(8))) __bf16 bf16x8;
typedef __attribute__((ext_vector_type(4))) __bf16 bf16x4;
typedef __attribute__((ext_vector_type(4))) float f32x4;

// ---------------- f32 -> bf16 cast ----------------
__global__ void k_cast(const float* __restrict__ s, bf16* __restrict__ d, int n) {
  int i = blockIdx.x * 256 + threadIdx.x;
  if (i < n) d[i] = (bf16)s[i];
}

// ---------------- X (b,32,32,32) -> XR rows (b*1024, 32ch) bf16 ----------------
__global__ void k_prep_x(const float* __restrict__ X, bf16* __restrict__ XR) {
  int idx = blockIdx.x * 256 + threadIdx.x;
  if (idx >= 48 * 1024 * 32) return;
  int b = idx >> 15, r = idx & 32767, pos = r >> 5, ic = r & 31;
  XR[idx] = (bf16)X[((size_t)(b * 32 + ic) << 10) + pos];
}

// ---------------- conv weight pack: (OC,IC,3,3) -> 9 x (OC,IC) bf16 ----------------
__global__ void k_pack_conv(const float* __restrict__ w, bf16* __restrict__ dst,
                            int OC, int IC, int total) {
  int idx = blockIdx.x * 256 + threadIdx.x;
  if (idx >= total) return;
  int t = idx / (OC * IC);
  int rem = idx - t * OC * IC;
  int oc = rem / IC, ic = rem - oc * IC;
  dst[idx] = (bf16)w[(size_t)(oc * IC + ic) * 9 + t];
}

// ---------------- GEMM: C[m, coff+n] = A[M,K] x B[N,K]^T (+bias, relu), bf16 ----------------
__global__ __launch_bounds__(256, 4) void k_gemm(
    const bf16* __restrict__ A, const bf16* __restrict__ B,
    const float* __restrict__ bias, bf16* __restrict__ Cb,
    int M, int N, int K, int relu, int ldc, int coff) {
  __shared__ alignas(16) bf16 As[64 * 32];
  __shared__ alignas(16) bf16 Bs[64 * 32];
  const int t = threadIdx.x;
  const int m0 = blockIdx.x * 64, n0 = blockIdx.y * 64;
  const int wave = t >> 6, lane = t & 63;
  const int wm = wave & 1, wn = wave >> 1;
  const int fr = lane & 15, kq = lane >> 4;
  f32x4 acc[2][2] = {};
  const int srow = t >> 2, kseg = (t & 3) * 8;
  const bf16* gA = A + (size_t)(m0 + srow) * K + kseg;
  const bf16* gB = B + (size_t)(n0 + srow) * K + kseg;
  bf16* sA = As + srow * 32 + kseg;
  bf16* sB = Bs + srow * 32 + kseg;
  for (int k0 = 0; k0 < K; k0 += 32) {
    *(int4*)sA = *(const int4*)gA; gA += 32;
    *(int4*)sB = *(const int4*)gB; gB += 32;
    __syncthreads();
    bf16x8 a0 = *(const bf16x8*)(As + (wm * 32 + fr) * 32 + kq * 8);
    bf16x8 a1 = *(const bf16x8*)(As + (wm * 32 + 16 + fr) * 32 + kq * 8);
    bf16x8 b0 = *(const bf16x8*)(Bs + (wn * 32 + fr) * 32 + kq * 8);
    bf16x8 b1 = *(const bf16x8*)(Bs + (wn * 32 + 16 + fr) * 32 + kq * 8);
    acc[0][0] = __builtin_amdgcn_mfma_f32_16x16x32_bf16(a0, b0, acc[0][0], 0, 0, 0);
    acc[0][1] = __builtin_amdgcn_mfma_f32_16x16x32_bf16(a0, b1, acc[0][1], 0, 0, 0);
    acc[1][0] = __builtin_amdgcn_mfma_f32_16x16x32_bf16(a1, b0, acc[1][0], 0, 0, 0);
    acc[1][1] = __builtin_amdgcn_mfma_f32_16x16x32_bf16(a1, b1, acc[1][1], 0, 0, 0);
    __syncthreads();
  }
  const int rowq = kq * 4;
  for (int mt = 0; mt < 2; ++mt)
    for (int nt = 0; nt < 2; ++nt) {
      int mm = m0 + wm * 32 + mt * 16 + rowq;
      int n = n0 + wn * 32 + nt * 16 + fr;
      float bv = bias ? bias[n] : 0.0f;
      for (int r = 0; r < 4; ++r) {
        float x = acc[mt][nt][r] + bv;
        if (relu) x = fmaxf(x, 0.0f);
        Cb[(size_t)(mm + r) * ldc + coff + n] = (bf16)x;
      }
    }
}

// ---------------- conv as 9-pass shifted GEMM (implicit im2col) ----------------
// A rows: (b, pos, CIN ch) row-major.  Bp: 9 stacked (256, CIN) matrices.
// Output m = b*900 + y*30 + x.  TRANS: write (b, oc, p) flat; else rows (m, 256).
template <int CIN, int PAD, int SRCW, int SRCROWS, int CHECK, int TRANS>
__global__ __launch_bounds__(256, 4) void k_conv_gemm(
    const bf16* __restrict__ A, const bf16* __restrict__ Bp,
    const float* __restrict__ bias, bf16* __restrict__ Cb) {
  __shared__ alignas(16) bf16 As[64 * 32];
  __shared__ alignas(16) bf16 Bs[64 * 32];
  const int t = threadIdx.x;
  const int m0 = blockIdx.x * 64, n0 = blockIdx.y * 64;
  const int wave = t >> 6, lane = t & 63;
  const int wm = wave & 1, wn = wave >> 1;
  const int fr = lane & 15, kq = lane >> 4;
  f32x4 acc[2][2] = {};
  const int srow = t >> 2, kseg = (t & 3) * 8;
  const int m = m0 + srow;
  const int b = m / 900, p = m - b * 900;
  const int y = p / 30, x = p - y * 30;
  bf16* sA = As + srow * 32 + kseg;
  bf16* sB = Bs + srow * 32 + kseg;
  for (int t9 = 0; t9 < 9; ++t9) {
    const int ky = t9 / 3, kx = t9 - ky * 3;
    const int sy = y + ky - PAD, sx = x + kx - PAD;
    bool valid = true;
    if (CHECK) valid = (sy >= 0) && (sy < SRCW) && (sx >= 0) && (sx < SRCW);
    const bf16* ga = A + (size_t)(b * SRCROWS + sy * SRCW + sx) * CIN + kseg;
    const bf16* gb = Bp + (size_t)(t9 * 256 + n0 + srow) * CIN + kseg;
    for (int k0 = 0; k0 < CIN; k0 += 32) {
      int4 av = {0, 0, 0, 0};
      if (valid) av = *(const int4*)(ga + k0);
      *(int4*)sA = av;
      *(int4*)sB = *(const int4*)(gb + k0);
      __syncthreads();
      bf16x8 a0 = *(const bf16x8*)(As + (wm * 32 + fr) * 32 + kq * 8);
      bf16x8 a1 = *(const bf16x8*)(As + (wm * 32 + 16 + fr) * 32 + kq * 8);
      bf16x8 b0 = *(const bf16x8*)(Bs + (wn * 32 + fr) * 32 + kq * 8);
      bf16x8 b1 = *(const bf16x8*)(Bs + (wn * 32 + 16 + fr) * 32 + kq * 8);
      acc[0][0] = __builtin_amdgcn_mfma_f32_16x16x32_bf16(a0, b0, acc[0][0], 0, 0, 0);
      acc[0][1] = __builtin_amdgcn_mfma_f32_16x16x32_bf16(a0, b1, acc[0][1], 0, 0, 0);
      acc[1][0] = __builtin_amdgcn_mfma_f32_16x16x32_bf16(a1, b0, acc[1][0], 0, 0, 0);
      acc[1][1] = __builtin_amdgcn_mfma_f32_16x16x32_bf16(a1, b1, acc[1][1], 0, 0, 0);
      __syncthreads();
    }
  }
  const int rowq = kq * 4;
  for (int mt = 0; mt < 2; ++mt)
    for (int nt = 0; nt < 2; ++nt) {
      int mm = m0 + wm * 32 + mt * 16 + rowq;
      int n = n0 + wn * 32 + nt * 16 + fr;
      float bv = bias[n];
      for (int r = 0; r < 4; ++r) {
        float v = acc[mt][nt][r] + bv;
        int mr = mm + r;
        size_t off;
        if (TRANS) {
          int bb = mr / 900, pp = mr - bb * 900;
          off = (size_t)(bb * 256 + n) * 900 + pp;
        } else {
          off = (size_t)mr * 256 + n;
        }
        Cb[off] = (bf16)v;
      }
    }
}

// ---------------- attention logits z[s,h,i,j] bf16 (skew; optional masked lins) ----------------
// QKV rows of 768: [q|k|v]; q[s,h,i,d] = QKV[(s*48+i)*768 + h*32 + d]
template <int MASKED>
__global__ __launch_bounds__(256, 2) void k_attn_z(
    const bf16* __restrict__ QKV, const float* __restrict__ relw, bf16* __restrict__ Z,
    const float* __restrict__ l1w, const float* __restrict__ l1b,
    const float* __restrict__ l2w, const float* __restrict__ l2b) {
  __shared__ alignas(16) float Qh[48 * 32];
  __shared__ alignas(16) float Kh[48 * 32];
  __shared__ alignas(16) float Rt[48 * 36];   // Rt[j][dd] = rel[dd][j]
  __shared__ alignas(16) float SC[48 * 48];
  __shared__ alignas(16) float EMD[48 * 48];
  __shared__ alignas(16) float T2t[MASKED ? 48 * 52 : 4];  // T2t[a][i], stride 52 >= 48
  __shared__ alignas(16) float L1[MASKED ? 48 * 48 : 4];
  __shared__ alignas(16) float L2[MASKED ? 48 * 48 : 4];
  const int s = blockIdx.x, t = threadIdx.x;
  const float scale = 0.17677669529663687f;  // 1/sqrt(32)
  if constexpr (MASKED) {
    for (int i = t; i < 2304; i += 256) { L1[i] = l1w[i]; L2[i] = l2w[i]; }
  }
  const int ti = t >> 4, tj = t & 15;
  const int ib = ti * 3, jb = tj * 3;
  for (int h = 0; h < 8; ++h) {
    __syncthreads();
    for (int idx = t; idx < 1536; idx += 256) {
      int i = idx >> 5, dd = idx & 31;
      size_t g = (size_t)(s * 48 + i) * 768 + h * 32 + dd;
      Qh[idx] = (float)QKV[g];
      Kh[idx] = (float)QKV[g + 256];
    }
    {
      const float* rb = relw + (size_t)(s * 8 + h) * 1536;
      for (int idx = t; idx < 1536; idx += 256) {
        int dd = idx / 48, j = idx - dd * 48;
        Rt[j * 36 + dd] = rb[idx];
      }
    }
    __syncthreads();
    float a[3][3] = {}, e[3][3] = {};
    for (int dd = 0; dd < 32; dd += 4) {
      f32x4 q[3], k[3], r[3];
      for (int u = 0; u < 3; ++u) {
        q[u] = *(const f32x4*)(Qh + (ib + u) * 32 + dd);
        k[u] = *(const f32x4*)(Kh + (jb + u) * 32 + dd);
        r[u] = *(const f32x4*)(Rt + (jb + u) * 36 + dd);
      }
      for (int ui = 0; ui < 3; ++ui)
        for (int uj = 0; uj < 3; ++uj)
          for (int c = 0; c < 4; ++c) {
            a[ui][uj] += q[ui][c] * k[uj][c];
            e[ui][uj] += q[ui][c] * r[uj][c];
          }
    }
    for (int ui = 0; ui < 3; ++ui)
      for (int uj = 0; uj < 3; ++uj) {
        SC[(ib + ui) * 48 + jb + uj] = a[ui][uj] * scale;
        EMD[(ib + ui) * 48 + jb + uj] = e[ui][uj];
      }
    __syncthreads();
    bf16* zb = Z + (size_t)(s * 8 + h) * 2304;
    if constexpr (!MASKED) {
      for (int ui = 0; ui < 3; ++ui)
        for (int uj = 0; uj < 3; ++uj) {
          int i = ib + ui, j = jb + uj;
          float v = SC[i * 48 + j];
          if (j <= i) v += EMD[i * 48 + 47 + j - i];
          zb[i * 48 + j] = (bf16)v;
        }
    } else {
      // qk1[i][a] = sum_j SC[i][j]*L1[a][j] + l1b[a] -> T2t[a][i]
      float q1[3][3] = {};
      for (int j = 0; j < 48; j += 4) {
        f32x4 sc[3], lw[3];
        for (int u = 0; u < 3; ++u) {
          sc[u] = *(const f32x4*)(SC + (ib + u) * 48 + j);
          lw[u] = *(const f32x4*)(L1 + (jb + u) * 48 + j);
        }
        for (int ui = 0; ui < 3; ++ui)
          for (int uj = 0; uj < 3; ++uj)
            for (int c = 0; c < 4; ++c) q1[ui][uj] += sc[ui][c] * lw[uj][c];
      }
      for (int ui = 0; ui < 3; ++ui)
        for (int uj = 0; uj < 3; ++uj)
          T2t[(jb + uj) * 52 + ib + ui] = q1[ui][uj] + l1b[jb + uj];
      __syncthreads();
      // bmm[a][c] = sum_i T2t[a][i]*L2[c][i] + l2b[c]; + mask + skew
      float bm[3][3] = {};
      for (int i2 = 0; i2 < 48; i2 += 4) {
        f32x4 ta[3], lw[3];
        for (int u = 0; u < 3; ++u) {
          ta[u] = *(const f32x4*)(T2t + (ib + u) * 52 + i2);
          lw[u] = *(const f32x4*)(L2 + (jb + u) * 48 + i2);
        }
        for (int ui = 0; ui < 3; ++ui)
          for (int uj = 0; uj < 3; ++uj)
            for (int c = 0; c < 4; ++c) bm[ui][uj] += ta[ui][c] * lw[uj][c];
      }
      for (int ui = 0; ui < 3; ++ui)
        for (int uj = 0; uj < 3; ++uj) {
          int aa = ib + ui, cc = jb + uj;
          float v;
          if (cc > aa) v = -10000.0f;  // whole column masked -> uniform, matches ref exactly
          else v = bm[ui][uj] + l2b[cc] + EMD[aa * 48 + 47 + cc - aa];
          zb[aa * 48 + cc] = (bf16)v;
        }
    }
  }
}

// ---------------- softmax over s (900) for 18432 columns, bf16 in place ----------------
__global__ __launch_bounds__(256) void k_softmax_s(bf16* __restrict__ Z) {
  __shared__ float red[4][64];
  const int t = threadIdx.x, tc = t & 63, sg = t >> 6;
  bf16* p = Z + (size_t)blockIdx.x * 64 + tc;
  const int s0 = sg * 225, s1 = s0 + 225;
  float m = -FLT_MAX;
  for (int s = s0; s < s1; ++s) m = fmaxf(m, (float)p[(size_t)s * 18432]);
  red[sg][tc] = m;
  __syncthreads();
  m = fmaxf(fmaxf(red[0][tc], red[1][tc]), fmaxf(red[2][tc], red[3][tc]));
  float sum = 0.0f;
  for (int s = s0; s < s1; ++s) sum += __expf((float)p[(size_t)s * 18432] - m);
  __syncthreads();
  red[sg][tc] = sum;
  __syncthreads();
  sum = red[0][tc] + red[1][tc] + red[2][tc] + red[3][tc];
  float inv = 1.0f / sum;
  for (int s = s0; s < s1; ++s) {
    size_t off = (size_t)s * 18432;
    p[off] = (bf16)(__expf((float)p[off] - m) * inv);
  }
}

// ---------------- O[s,h,i,d] = sum_j P[s,h,i,j] * V[s,h,j,d], bf16 ----------------
__global__ __launch_bounds__(256, 2) void k_attn_av(
    const bf16* __restrict__ P, const bf16* __restrict__ QKV, bf16* __restrict__ O) {
  __shared__ alignas(16) float Ph[48 * 48];
  __shared__ alignas(16) float Vt[32 * 48];  // Vt[dd][j]
  const int s = blockIdx.x, t = threadIdx.x;
  const int ti = t >> 4, td = t & 15;
  const int ib = ti * 3, db = td * 2;
  for (int h = 0; h < 8; ++h) {
    __syncthreads();
    for (int idx = t; idx < 2304; idx += 256)
      Ph[idx] = (float)P[(size_t)(s * 8 + h) * 2304 + idx];
    for (int idx = t; idx < 1536; idx += 256) {
      int j = idx >> 5, dd = idx & 31;
      Vt[dd * 48 + j] = (float)QKV[(size_t)(s * 48 + j) * 768 + 512 + h * 32 + dd];
    }
    __syncthreads();
    float a[3][2] = {};
    for (int j = 0; j < 48; j += 4) {
      f32x4 pv[3], vv[2];
      for (int u = 0; u < 3; ++u) pv[u] = *(const f32x4*)(Ph + (ib + u) * 48 + j);
      for (int u = 0; u < 2; ++u) vv[u] = *(const f32x4*)(Vt + (db + u) * 48 + j);
      for (int ui = 0; ui < 3; ++ui)
        for (int ud = 0; ud < 2; ++ud)
          for (int c = 0; c < 4; ++c) a[ui][ud] += pv[ui][c] * vv[ud][c];
    }
    for (int ui = 0; ui < 3; ++ui)
      for (int ud = 0; ud < 2; ++ud)
        O[((size_t)(s * 8 + h) * 48 + ib + ui) * 32 + db + ud] = (bf16)a[ui][ud];
  }
}

// ---------------- out = LN(Xa + Xb), rows of 256, bf16 ----------------
__global__ __launch_bounds__(256) void k_add_ln(
    const bf16* __restrict__ Xa, const bf16* __restrict__ Xb, bf16* __restrict__ out) {
  const int t = threadIdx.x, lane = t & 63, w = t >> 6;
  const size_t off = ((size_t)blockIdx.x * 4 + w) * 256 + lane * 4;
  bf16x4 av = *(const bf16x4*)(Xa + off);
  bf16x4 bv = *(const bf16x4*)(Xb + off);
  f32x4 x;
  for (int c = 0; c < 4; ++c) x[c] = (float)av[c] + (float)bv[c];
  float sum = x[0] + x[1] + x[2] + x[3];
  for (int o = 1; o < 64; o <<= 1) sum += __shfl_xor(sum, o);
  float mean = sum * (1.0f / 256.0f);
  float q = 0.0f;
  for (int c = 0; c < 4; ++c) { float d = x[c] - mean; q += d * d; }
  for (int o = 1; o < 64; o <<= 1) q += __shfl_xor(q, o);
  float rstd = rsqrtf(q * (1.0f / 256.0f) + 1e-5f);
  bf16x4 y;
  for (int c = 0; c < 4; ++c) y[c] = (bf16)((x[c] - mean) * rstd);
  *(bf16x4*)(out + off) = y;
}

// ---------------- y[m] = dot(H[m,:256], w) + b ----------------
__global__ __launch_bounds__(256) void k_ydot(
    const bf16* __restrict__ H, const float* __restrict__ w,
    const float* __restrict__ b, float* __restrict__ Y) {
  const int t = threadIdx.x, lane = t & 63, wv = t >> 6;
  const size_t row = (size_t)blockIdx.x * 4 + wv;
  bf16x4 hx = *(const bf16x4*)(H + row * 256 + lane * 4);
  f32x4 ww = *(const f32x4*)(w + lane * 4);
  float s = (float)hx[0] * ww[0] + (float)hx[1] * ww[1] + (float)hx[2] * ww[2] + (float)hx[3] * ww[3];
  for (int o = 1; o < 64; o <<= 1) s += __shfl_xor(s, o);
  if (lane == 0) Y[row] = s + b[0];
}

// ---------------- softmax over b (48) per column ----------------
__global__ void k_softmax48(const float* __restrict__ Y, float* __restrict__ O) {
  int ss = blockIdx.x * 256 + threadIdx.x;
  if (ss >= 900) return;
  float m = -FLT_MAX;
  for (int b = 0; b < 48; ++b) m = fmaxf(m, Y[b * 900 + ss]);
  float sum = 0.0f;
  for (int b = 0; b < 48; ++b) sum += __expf(Y[b * 900 + ss] - m);
  float inv = 1.0f / sum;
  for (int b = 0; b < 48; ++b) O[b * 900 + ss] = __expf(Y[b * 900 + ss] - m) * inv;
}

extern "C" void kernel_launch(void* const* d_in, const int* in_sizes, int n_in,
                              void* d_out, int out_size, void* d_ws, size_t ws_size,
                              hipStream_t stream) {
  (void)in_sizes; (void)n_in; (void)out_size;
  const float* X_en = (const float*)d_in[0];
  const float* X_de = (const float*)d_in[1];
  const float* conv1_w = (const float*)d_in[2];
  const float* conv1_b = (const float*)d_in[3];
  const float* conv2_w = (const float*)d_in[4];
  const float* conv2_b = (const float*)d_in[5];
  const float* enc_wq = (const float*)d_in[6];
  const float* enc_wk = (const float*)d_in[7];
  const float* enc_wv = (const float*)d_in[8];
  const float* enc_rel = (const float*)d_in[9];
  const float* enc_f1w = (const float*)d_in[10];
  const float* enc_f1b = (const float*)d_in[11];
  const float* enc_f2w = (const float*)d_in[12];
  const float* enc_f2b = (const float*)d_in[13];
  const float* dm_wq = (const float*)d_in[14];
  const float* dm_wk = (const float*)d_in[15];
  const float* dm_wv = (const float*)d_in[16];
  const float* dm_rel = (const float*)d_in[17];
  const float* dm_l1w = (const float*)d_in[18];
  const float* dm_l1b = (const float*)d_in[19];
  const float* dm_l2w = (const float*)d_in[20];
  const float* dm_l2b = (const float*)d_in[21];
  const float* dc_wq = (const float*)d_in[22];
  const float* dc_wk = (const float*)d_in[23];
  const float* dc_wv = (const float*)d_in[24];
  const float* dc_rel = (const float*)d_in[25];
  const float* d_f1w = (const float*)d_in[26];
  const float* d_f1b = (const float*)d_in[27];
  const float* d_f2w = (const float*)d_in[28];
  const float* d_f2b = (const float*)d_in[29];
  const float* out_w = (const float*)d_in[30];
  const float* out_b = (const float*)d_in[31];
  float* OUT = (float*)d_out;

  // ---- workspace layout: 214,901,504 bytes (~205 MiB) ----
  const size_t SLOT = 22118400;  // 43200*256 bf16
  char* ws = (char*)d_ws;
  size_t o = 0;
  bf16* S1 = (bf16*)(ws + o); o += SLOT;  // XEb -> ENCb
  bf16* S2 = (bf16*)(ws + o); o += SLOT;  // XDb
  bf16* S3 = (bf16*)(ws + o); o += SLOT;  // o1 -> h2
  bf16* S4 = (bf16*)(ws + o); o += SLOT;  // h1 -> h3
  bf16* S5 = (bf16*)(ws + o); o += SLOT;  // attn-out / ffn-out
  char* U = ws + o; o += 33177600 + 3 * SLOT;  // Z(bf16) + QKV, union { HID, XR+C1R }
  bf16* Zb = (bf16*)U;
  bf16* QKV = (bf16*)(U + 33177600);
  bf16* XR = (bf16*)U;                    // conv phase only
  bf16* C1R = (bf16*)(U + 3145728);       // conv phase only
  bf16* HID = (bf16*)U;                   // FFN phase only (88.5MB <= 99.5MB)
  bf16* wa = (bf16*)(ws + o); o += 4603904;
  float* Y = (float*)(ws + o); o += 172800;
  if (ws_size < o) return;  // need ~205 MiB

  // weight arena (element offsets)
  bf16* c1p = wa;                 // 9*(256x32)
  bf16* c2p = wa + 73728;         // 9*(256x256)
  bf16* EQKVw = wa + 663552;      // eq|ek|ev (768x256)
  bf16* MQKVw = wa + 860160;      // mq|mk|mv
  bf16* cqw = wa + 1056768;       // 256x256
  bf16* CKVw = wa + 1122304;      // ck|cv (512x256)
  bf16* ef1 = wa + 1253376;
  bf16* ef2 = wa + 1515520;
  bf16* df1 = wa + 1777664;
  bf16* df2 = wa + 2039808;

  auto cast = [&](const float* s, bf16* d, int n) {
    k_cast<<<dim3((n + 255) / 256), dim3(256), 0, stream>>>(s, d, n);
  };
  auto gemm = [&](const bf16* A, const bf16* B, const float* bias, bf16* C,
                  int M, int N, int K, int relu, int ldc, int coff) {
    k_gemm<<<dim3(M / 64, N / 64), dim3(256), 0, stream>>>(A, B, bias, C, M, N, K, relu, ldc, coff);
  };

  // ---- weight prep ----
  k_pack_conv<<<dim3(288), dim3(256), 0, stream>>>(conv1_w, c1p, 256, 32, 73728);
  k_pack_conv<<<dim3(2304), dim3(256), 0, stream>>>(conv2_w, c2p, 256, 256, 589824);
  cast(enc_wq, EQKVw, 65536); cast(enc_wk, EQKVw + 65536, 65536); cast(enc_wv, EQKVw + 131072, 65536);
  cast(dm_wq, MQKVw, 65536); cast(dm_wk, MQKVw + 65536, 65536); cast(dm_wv, MQKVw + 131072, 65536);
  cast(dc_wq, cqw, 65536);
  cast(dc_wk, CKVw, 65536); cast(dc_wv, CKVw + 65536, 65536);
  cast(enc_f1w, ef1, 262144); cast(enc_f2w, ef2, 262144);
  cast(d_f1w, df1, 262144); cast(d_f2w, df2, 262144);

  // ---- conv chains (implicit-im2col GEMM, 9 shifted passes) ----
  auto conv_chain = [&](const float* X, bf16* outB) {
    k_prep_x<<<dim3(6144), dim3(256), 0, stream>>>(X, XR);
    k_conv_gemm<32, 0, 32, 1024, 0, 0><<<dim3(675, 4), dim3(256), 0, stream>>>(XR, c1p, conv1_b, C1R);
    k_conv_gemm<256, 1, 30, 900, 1, 1><<<dim3(675, 4), dim3(256), 0, stream>>>(C1R, c2p, conv2_b, outB);
  };
  conv_chain(X_en, S1);
  conv_chain(X_de, S2);

  // ---- encoder ----
  gemm(S1, EQKVw, nullptr, QKV, 43200, 768, 256, 0, 768, 0);
  k_attn_z<0><<<dim3(900), dim3(256), 0, stream>>>(QKV, enc_rel, Zb, nullptr, nullptr, nullptr, nullptr);
  k_softmax_s<<<dim3(288), dim3(256), 0, stream>>>(Zb);
  k_attn_av<<<dim3(900), dim3(256), 0, stream>>>(Zb, QKV, S5);
  k_add_ln<<<dim3(10800), dim3(256), 0, stream>>>(S1, S5, S3);  // o1
  gemm(S3, ef1, enc_f1b, HID, 43200, 1024, 256, 1, 1024, 0);
  gemm(HID, ef2, enc_f2b, S5, 43200, 256, 1024, 0, 256, 0);
  k_add_ln<<<dim3(10800), dim3(256), 0, stream>>>(S3, S5, S1);  // enc_out

  // ---- decoder masked self-attention ----
  gemm(S2, MQKVw, nullptr, QKV, 43200, 768, 256, 0, 768, 0);
  k_attn_z<1><<<dim3(900), dim3(256), 0, stream>>>(QKV, dm_rel, Zb, dm_l1w, dm_l1b, dm_l2w, dm_l2b);
  k_softmax_s<<<dim3(288), dim3(256), 0, stream>>>(Zb);
  k_attn_av<<<dim3(900), dim3(256), 0, stream>>>(Zb, QKV, S5);
  k_add_ln<<<dim3(10800), dim3(256), 0, stream>>>(S2, S5, S4);  // h1

  // ---- cross attention ----
  gemm(S4, cqw, nullptr, QKV, 43200, 256, 256, 0, 768, 0);
  gemm(S1, CKVw, nullptr, QKV, 43200, 512, 256, 0, 768, 256);
  k_attn_z<0><<<dim3(900), dim3(256), 0, stream>>>(QKV, dc_rel, Zb, nullptr, nullptr, nullptr, nullptr);
  k_softmax_s<<<dim3(288), dim3(256), 0, stream>>>(Zb);
  k_attn_av<<<dim3(900), dim3(256), 0, stream>>>(Zb, QKV, S5);
  k_add_ln<<<dim3(10800), dim3(256), 0, stream>>>(S5, S4, S3);  // h2 = ln(c + h1)

  // ---- decoder FFN + head ----
  gemm(S3, df1, d_f1b, HID, 43200, 1024, 256, 1, 1024, 0);
  gemm(HID, df2, d_f2b, S5, 43200, 256, 1024, 0, 256, 0);
  k_add_ln<<<dim3(10800), dim3(256), 0, stream>>>(S3, S5, S4);  // h3
  k_ydot<<<dim3(10800), dim3(256), 0, stream>>>(S4, out_w, out_b, Y);
  k_softmax48<<<dim3(4), dim3(256), 0, stream>>>(Y, OUT);
}

// Round 3
// 1673.271 us; speedup vs baseline: 1.4239x; 1.4239x over previous
//
#include <hip/hip_runtime.h>
#include <float.h>

typedef __bf16 bf16;
typedef __attribute__((ext_vector_type(8))) __bf16 bf16x8;
typedef __attribute__((ext_vector_type(4))) __bf16 bf16x4;
typedef __attribute__((ext_vector_type(4))) float f32x4;

// ---------------- f32 -> bf16 cast ----------------
__global__ void k_cast(const float* __restrict__ s, bf16* __restrict__ d, int n) {
  int i = blockIdx.x * 256 + threadIdx.x;
  if (i < n) d[i] = (bf16)s[i];
}

// ---------------- X (b,32,32,32) -> XR rows (b*1024, 32ch) bf16 ----------------
__global__ void k_prep_x(const float* __restrict__ X, bf16* __restrict__ XR) {
  int idx = blockIdx.x * 256 + threadIdx.x;
  if (idx >= 48 * 1024 * 32) return;
  int b = idx >> 15, r = idx & 32767, pos = r >> 5, ic = r & 31;
  XR[idx] = (bf16)X[((size_t)(b * 32 + ic) << 10) + pos];
}

// ---------------- conv weight pack: (OC,IC,3,3) -> 9 x (OC,IC) bf16 ----------------
__global__ void k_pack_conv(const float* __restrict__ w, bf16* __restrict__ dst,
                            int OC, int IC, int total) {
  int idx = blockIdx.x * 256 + threadIdx.x;
  if (idx >= total) return;
  int t = idx / (OC * IC);
  int rem = idx - t * OC * IC;
  int oc = rem / IC, ic = rem - oc * IC;
  dst[idx] = (bf16)w[(size_t)(oc * IC + ic) * 9 + t];
}

// ---------------- GEMM: C[m, coff+n] = A[M,K] x B[N,K]^T (+bias, relu), bf16 ----------------
__global__ __launch_bounds__(256, 4) void k_gemm(
    const bf16* __restrict__ A, const bf16* __restrict__ B,
    const float* __restrict__ bias, bf16* __restrict__ Cb,
    int M, int N, int K, int relu, int ldc, int coff) {
  __shared__ alignas(16) bf16 As[64 * 32];
  __shared__ alignas(16) bf16 Bs[64 * 32];
  const int t = threadIdx.x;
  const int m0 = blockIdx.x * 64, n0 = blockIdx.y * 64;
  const int wave = t >> 6, lane = t & 63;
  const int wm = wave & 1, wn = wave >> 1;
  const int fr = lane & 15, kq = lane >> 4;
  f32x4 acc[2][2] = {};
  const int srow = t >> 2, kseg = (t & 3) * 8;
  const bf16* gA = A + (size_t)(m0 + srow) * K + kseg;
  const bf16* gB = B + (size_t)(n0 + srow) * K + kseg;
  bf16* sA = As + srow * 32 + kseg;
  bf16* sB = Bs + srow * 32 + kseg;
  for (int k0 = 0; k0 < K; k0 += 32) {
    *(int4*)sA = *(const int4*)gA; gA += 32;
    *(int4*)sB = *(const int4*)gB; gB += 32;
    __syncthreads();
    bf16x8 a0 = *(const bf16x8*)(As + (wm * 32 + fr) * 32 + kq * 8);
    bf16x8 a1 = *(const bf16x8*)(As + (wm * 32 + 16 + fr) * 32 + kq * 8);
    bf16x8 b0 = *(const bf16x8*)(Bs + (wn * 32 + fr) * 32 + kq * 8);
    bf16x8 b1 = *(const bf16x8*)(Bs + (wn * 32 + 16 + fr) * 32 + kq * 8);
    acc[0][0] = __builtin_amdgcn_mfma_f32_16x16x32_bf16(a0, b0, acc[0][0], 0, 0, 0);
    acc[0][1] = __builtin_amdgcn_mfma_f32_16x16x32_bf16(a0, b1, acc[0][1], 0, 0, 0);
    acc[1][0] = __builtin_amdgcn_mfma_f32_16x16x32_bf16(a1, b0, acc[1][0], 0, 0, 0);
    acc[1][1] = __builtin_amdgcn_mfma_f32_16x16x32_bf16(a1, b1, acc[1][1], 0, 0, 0);
    __syncthreads();
  }
  const int rowq = kq * 4;
  for (int mt = 0; mt < 2; ++mt)
    for (int nt = 0; nt < 2; ++nt) {
      int mm = m0 + wm * 32 + mt * 16 + rowq;
      int n = n0 + wn * 32 + nt * 16 + fr;
      float bv = bias ? bias[n] : 0.0f;
      for (int r = 0; r < 4; ++r) {
        float x = acc[mt][nt][r] + bv;
        if (relu) x = fmaxf(x, 0.0f);
        Cb[(size_t)(mm + r) * ldc + coff + n] = (bf16)x;
      }
    }
}

// ---------------- conv as 9-pass shifted GEMM (implicit im2col) ----------------
template <int CIN, int PAD, int SRCW, int SRCROWS, int CHECK, int TRANS>
__global__ __launch_bounds__(256, 4) void k_conv_gemm(
    const bf16* __restrict__ A, const bf16* __restrict__ Bp,
    const float* __restrict__ bias, bf16* __restrict__ Cb) {
  __shared__ alignas(16) bf16 As[64 * 32];
  __shared__ alignas(16) bf16 Bs[64 * 32];
  const int t = threadIdx.x;
  const int m0 = blockIdx.x * 64, n0 = blockIdx.y * 64;
  const int wave = t >> 6, lane = t & 63;
  const int wm = wave & 1, wn = wave >> 1;
  const int fr = lane & 15, kq = lane >> 4;
  f32x4 acc[2][2] = {};
  const int srow = t >> 2, kseg = (t & 3) * 8;
  const int m = m0 + srow;
  const int b = m / 900, p = m - b * 900;
  const int y = p / 30, x = p - y * 30;
  bf16* sA = As + srow * 32 + kseg;
  bf16* sB = Bs + srow * 32 + kseg;
  for (int t9 = 0; t9 < 9; ++t9) {
    const int ky = t9 / 3, kx = t9 - ky * 3;
    const int sy = y + ky - PAD, sx = x + kx - PAD;
    bool valid = true;
    if (CHECK) valid = (sy >= 0) && (sy < SRCW) && (sx >= 0) && (sx < SRCW);
    const bf16* ga = A + (size_t)(b * SRCROWS + sy * SRCW + sx) * CIN + kseg;
    const bf16* gb = Bp + (size_t)(t9 * 256 + n0 + srow) * CIN + kseg;
    for (int k0 = 0; k0 < CIN; k0 += 32) {
      int4 av = {0, 0, 0, 0};
      if (valid) av = *(const int4*)(ga + k0);
      *(int4*)sA = av;
      *(int4*)sB = *(const int4*)(gb + k0);
      __syncthreads();
      bf16x8 a0 = *(const bf16x8*)(As + (wm * 32 + fr) * 32 + kq * 8);
      bf16x8 a1 = *(const bf16x8*)(As + (wm * 32 + 16 + fr) * 32 + kq * 8);
      bf16x8 b0 = *(const bf16x8*)(Bs + (wn * 32 + fr) * 32 + kq * 8);
      bf16x8 b1 = *(const bf16x8*)(Bs + (wn * 32 + 16 + fr) * 32 + kq * 8);
      acc[0][0] = __builtin_amdgcn_mfma_f32_16x16x32_bf16(a0, b0, acc[0][0], 0, 0, 0);
      acc[0][1] = __builtin_amdgcn_mfma_f32_16x16x32_bf16(a0, b1, acc[0][1], 0, 0, 0);
      acc[1][0] = __builtin_amdgcn_mfma_f32_16x16x32_bf16(a1, b0, acc[1][0], 0, 0, 0);
      acc[1][1] = __builtin_amdgcn_mfma_f32_16x16x32_bf16(a1, b1, acc[1][1], 0, 0, 0);
      __syncthreads();
    }
  }
  const int rowq = kq * 4;
  for (int mt = 0; mt < 2; ++mt)
    for (int nt = 0; nt < 2; ++nt) {
      int mm = m0 + wm * 32 + mt * 16 + rowq;
      int n = n0 + wn * 32 + nt * 16 + fr;
      float bv = bias[n];
      for (int r = 0; r < 4; ++r) {
        float v = acc[mt][nt][r] + bv;
        int mr = mm + r;
        size_t off;
        if (TRANS) {
          int bb = mr / 900, pp = mr - bb * 900;
          off = (size_t)(bb * 256 + n) * 900 + pp;
        } else {
          off = (size_t)mr * 256 + 256;  // placeholder, overwritten below
        }
        if (!TRANS) off = (size_t)mr * 256 + n;
        Cb[off] = (bf16)v;
      }
    }
}

// ---------------- attention logits via MFMA; LDS-staged vectorized Z stores ----------------
// QKV rows of 768: [q|k|v]; q[s,h,i,d] = QKV[(s*48+i)*768 + h*32 + d]
// A-frag: lane reads row (tile*16 + (lane&15)), k = (lane>>4)*8.. ; C: row=(lane>>4)*4+r, col=lane&15
template <int MASKED>
__global__ __launch_bounds__(256, MASKED ? 3 : 4) void k_attn_z(
    const bf16* __restrict__ QKV, const float* __restrict__ relw, bf16* __restrict__ Z,
    const float* __restrict__ l1w, const float* __restrict__ l1b,
    const float* __restrict__ l2w, const float* __restrict__ l2b) {
  __shared__ alignas(16) bf16 Rt[48 * 40];          // Rt[j][k] = rel[k*48+j], stride 40 (16B-aligned rows)
  __shared__ float EMD[48 * 49];                    // skew source, stride 49 (bank spread)
  __shared__ alignas(16) bf16 zst[48 * 48];         // staged z tile
  __shared__ alignas(16) bf16 Sc[MASKED ? 48 * 72 : 8];   // scores bf16, K-padded to 64, stride 72
  __shared__ alignas(16) bf16 L1b[MASKED ? 48 * 72 : 8];
  __shared__ alignas(16) bf16 L2b[MASKED ? 48 * 72 : 8];
  __shared__ alignas(16) bf16 T2b[MASKED ? 48 * 72 : 8];  // qk1 transposed [a][i]
  const int s = blockIdx.x, t = threadIdx.x;
  const int wave = t >> 6, lane = t & 63, fr = lane & 15, kq = lane >> 4;
  const float scale = 0.17677669529663687f;  // 1/sqrt(32)
  if constexpr (MASKED) {
    for (int i = t; i < 48 * 72; i += 256) {
      int r = i / 72, c = i - r * 72;
      bf16 z0 = (bf16)0.0f;
      L1b[i] = (c < 48) ? (bf16)l1w[r * 48 + c] : z0;
      L2b[i] = (c < 48) ? (bf16)l2w[r * 48 + c] : z0;
      Sc[i] = z0;
      T2b[i] = z0;
    }
  }
  int tiles[3];
  int nt = 0;
  for (int t9 = wave; t9 < 9; t9 += 4) tiles[nt++] = t9;
  for (int h = 0; h < 8; ++h) {
    __syncthreads();  // protect Rt/zst from previous iteration
    {
      const float* rb = relw + (size_t)(s * 8 + h) * 1536;
      for (int i = t; i < 1536; i += 256) {
        int k = i / 48, j = i - k * 48;
        Rt[j * 40 + k] = (bf16)rb[i];
      }
    }
    __syncthreads();
    // S = Q K^T * scale ; E = Q R^T   (per-wave tiles)
    f32x4 sreg[3];
    for (int u = 0; u < nt; ++u) {
      int t9 = tiles[u], ti = t9 / 3, tj = t9 - ti * 3;
      bf16x8 af = *(const bf16x8*)(QKV + (size_t)(s * 48 + ti * 16 + fr) * 768 + h * 32 + kq * 8);
      bf16x8 bfk = *(const bf16x8*)(QKV + (size_t)(s * 48 + tj * 16 + fr) * 768 + 256 + h * 32 + kq * 8);
      bf16x8 rf = *(const bf16x8*)(Rt + (tj * 16 + fr) * 40 + kq * 8);
      f32x4 sacc = {}, eacc = {};
      sacc = __builtin_amdgcn_mfma_f32_16x16x32_bf16(af, bfk, sacc, 0, 0, 0);
      eacc = __builtin_amdgcn_mfma_f32_16x16x32_bf16(af, rf, eacc, 0, 0, 0);
      for (int r = 0; r < 4; ++r)
        EMD[(ti * 16 + kq * 4 + r) * 49 + tj * 16 + fr] = eacc[r];
      if constexpr (MASKED) {
        for (int r = 0; r < 4; ++r)
          Sc[(ti * 16 + kq * 4 + r) * 72 + tj * 16 + fr] = (bf16)(sacc[r] * scale);
      } else {
        for (int r = 0; r < 4; ++r) sreg[u][r] = sacc[r] * scale;
      }
    }
    __syncthreads();
    if constexpr (!MASKED) {
      for (int u = 0; u < nt; ++u) {
        int t9 = tiles[u], ti = t9 / 3, tj = t9 - ti * 3;
        for (int r = 0; r < 4; ++r) {
          int i = ti * 16 + kq * 4 + r, j = tj * 16 + fr;
          float v = sreg[u][r];
          if (j <= i) v += EMD[i * 49 + 47 + j - i];
          zst[i * 48 + j] = (bf16)v;
        }
      }
    } else {
      // lin1: qk1[i][a] = sum_j Sc[i][j] L1[a][j]  (K padded to 64) -> T2b[a][i] (+bias)
      for (int u = 0; u < nt; ++u) {
        int t9 = tiles[u], ti = t9 / 3, tj = t9 - ti * 3;
        f32x4 acc = {};
        for (int k0 = 0; k0 < 64; k0 += 32) {
          bf16x8 af = *(const bf16x8*)(Sc + (ti * 16 + fr) * 72 + k0 + kq * 8);
          bf16x8 bw = *(const bf16x8*)(L1b + (tj * 16 + fr) * 72 + k0 + kq * 8);
          acc = __builtin_amdgcn_mfma_f32_16x16x32_bf16(af, bw, acc, 0, 0, 0);
        }
        for (int r = 0; r < 4; ++r) {
          int i = ti * 16 + kq * 4 + r, a = tj * 16 + fr;
          T2b[a * 72 + i] = (bf16)(acc[r] + l1b[a]);
        }
      }
      __syncthreads();
      // lin2: bmm[a][c] = sum_i T2b[a][i] L2[c][i]; + mask/skew
      for (int u = 0; u < nt; ++u) {
        int t9 = tiles[u], ti = t9 / 3, tj = t9 - ti * 3;
        f32x4 acc = {};
        for (int k0 = 0; k0 < 64; k0 += 32) {
          bf16x8 af = *(const bf16x8*)(T2b + (ti * 16 + fr) * 72 + k0 + kq * 8);
          bf16x8 bw = *(const bf16x8*)(L2b + (tj * 16 + fr) * 72 + k0 + kq * 8);
          acc = __builtin_amdgcn_mfma_f32_16x16x32_bf16(af, bw, acc, 0, 0, 0);
        }
        for (int r = 0; r < 4; ++r) {
          int aa = ti * 16 + kq * 4 + r, cc = tj * 16 + fr;
          float v;
          if (cc > aa) v = -10000.0f;  // whole masked column -> exactly uniform, matches ref
          else v = acc[r] + l2b[cc] + EMD[aa * 49 + 47 + cc - aa];
          zst[aa * 48 + cc] = (bf16)v;
        }
      }
    }
    __syncthreads();
    bf16* zb = Z + (size_t)(s * 8 + h) * 2304;
    for (int c = t; c < 288; c += 256)
      *(bf16x8*)(zb + c * 8) = *(const bf16x8*)(zst + c * 8);
  }
}

// ---------------- softmax over s (900) for 18432 columns, bf16 in place ----------------
__global__ __launch_bounds__(256) void k_softmax_s(bf16* __restrict__ Z) {
  __shared__ float red[4][64];
  const int t = threadIdx.x, tc = t & 63, sg = t >> 6;
  bf16* p = Z + (size_t)blockIdx.x * 64 + tc;
  const int s0 = sg * 225, s1 = s0 + 225;
  float m = -FLT_MAX;
  for (int s = s0; s < s1; ++s) m = fmaxf(m, (float)p[(size_t)s * 18432]);
  red[sg][tc] = m;
  __syncthreads();
  m = fmaxf(fmaxf(red[0][tc], red[1][tc]), fmaxf(red[2][tc], red[3][tc]));
  float sum = 0.0f;
  for (int s = s0; s < s1; ++s) sum += __expf((float)p[(size_t)s * 18432] - m);
  __syncthreads();
  red[sg][tc] = sum;
  __syncthreads();
  sum = red[0][tc] + red[1][tc] + red[2][tc] + red[3][tc];
  float inv = 1.0f / sum;
  for (int s = s0; s < s1; ++s) {
    size_t off = (size_t)s * 18432;
    p[off] = (bf16)(__expf((float)p[off] - m) * inv);
  }
}

// ---------------- O[s,h,i,d] = sum_j P[s,h,i,j] V[s,h,j,d] via MFMA ----------------
__global__ __launch_bounds__(256, 4) void k_attn_av(
    const bf16* __restrict__ P, const bf16* __restrict__ QKV, bf16* __restrict__ O) {
  __shared__ alignas(16) bf16 Ps[48 * 72];  // [i][j], K-padded to 64, stride 72
  __shared__ alignas(16) bf16 Vt[32 * 72];  // [d][j], padded
  __shared__ alignas(16) bf16 Ost[48 * 32];
  const int s = blockIdx.x, t = threadIdx.x;
  const int wave = t >> 6, lane = t & 63, fr = lane & 15, kq = lane >> 4;
  for (int i = t; i < 48 * 72; i += 256) Ps[i] = (bf16)0.0f;
  for (int i = t; i < 32 * 72; i += 256) Vt[i] = (bf16)0.0f;
  for (int h = 0; h < 8; ++h) {
    __syncthreads();
    const bf16* pb = P + (size_t)(s * 8 + h) * 2304;
    for (int c = t; c < 288; c += 256) {
      int r = c / 6, seg = c - r * 6;
      *(bf16x8*)(Ps + r * 72 + seg * 8) = *(const bf16x8*)(pb + r * 48 + seg * 8);
    }
    for (int i = t; i < 1536; i += 256) {
      int j = i >> 5, d = i & 31;
      Vt[d * 72 + j] = QKV[(size_t)(s * 48 + j) * 768 + 512 + h * 32 + d];
    }
    __syncthreads();
    for (int t6 = wave; t6 < 6; t6 += 4) {
      int ti = t6 >> 1, td = t6 & 1;
      f32x4 acc = {};
      for (int k0 = 0; k0 < 64; k0 += 32) {
        bf16x8 af = *(const bf16x8*)(Ps + (ti * 16 + fr) * 72 + k0 + kq * 8);
        bf16x8 bv = *(const bf16x8*)(Vt + (td * 16 + fr) * 72 + k0 + kq * 8);
        acc = __builtin_amdgcn_mfma_f32_16x16x32_bf16(af, bv, acc, 0, 0, 0);
      }
      for (int r = 0; r < 4; ++r)
        Ost[(ti * 16 + kq * 4 + r) * 32 + td * 16 + fr] = (bf16)acc[r];
    }
    __syncthreads();
    bf16* ob = O + (size_t)(s * 8 + h) * 1536;
    for (int c = t; c < 192; c += 256)
      *(bf16x8*)(ob + c * 8) = *(const bf16x8*)(Ost + c * 8);
  }
}

// ---------------- out = LN(Xa + Xb), rows of 256, bf16 ----------------
__global__ __launch_bounds__(256) void k_add_ln(
    const bf16* __restrict__ Xa, const bf16* __restrict__ Xb, bf16* __restrict__ out) {
  const int t = threadIdx.x, lane = t & 63, w = t >> 6;
  const size_t off = ((size_t)blockIdx.x * 4 + w) * 256 + lane * 4;
  bf16x4 av = *(const bf16x4*)(Xa + off);
  bf16x4 bv = *(const bf16x4*)(Xb + off);
  f32x4 x;
  for (int c = 0; c < 4; ++c) x[c] = (float)av[c] + (float)bv[c];
  float sum = x[0] + x[1] + x[2] + x[3];
  for (int o = 1; o < 64; o <<= 1) sum += __shfl_xor(sum, o);
  float mean = sum * (1.0f / 256.0f);
  float q = 0.0f;
  for (int c = 0; c < 4; ++c) { float d = x[c] - mean; q += d * d; }
  for (int o = 1; o < 64; o <<= 1) q += __shfl_xor(q, o);
  float rstd = rsqrtf(q * (1.0f / 256.0f) + 1e-5f);
  bf16x4 y;
  for (int c = 0; c < 4; ++c) y[c] = (bf16)((x[c] - mean) * rstd);
  *(bf16x4*)(out + off) = y;
}

// ---------------- y[m] = dot(H[m,:256], w) + b ----------------
__global__ __launch_bounds__(256) void k_ydot(
    const bf16* __restrict__ H, const float* __restrict__ w,
    const float* __restrict__ b, float* __restrict__ Y) {
  const int t = threadIdx.x, lane = t & 63, wv = t >> 6;
  const size_t row = (size_t)blockIdx.x * 4 + wv;
  bf16x4 hx = *(const bf16x4*)(H + row * 256 + lane * 4);
  f32x4 ww = *(const f32x4*)(w + lane * 4);
  float s = (float)hx[0] * ww[0] + (float)hx[1] * ww[1] + (float)hx[2] * ww[2] + (float)hx[3] * ww[3];
  for (int o = 1; o < 64; o <<= 1) s += __shfl_xor(s, o);
  if (lane == 0) Y[row] = s + b[0];
}

// ---------------- softmax over b (48) per column ----------------
__global__ void k_softmax48(const float* __restrict__ Y, float* __restrict__ O) {
  int ss = blockIdx.x * 256 + threadIdx.x;
  if (ss >= 900) return;
  float m = -FLT_MAX;
  for (int b = 0; b < 48; ++b) m = fmaxf(m, Y[b * 900 + ss]);
  float sum = 0.0f;
  for (int b = 0; b < 48; ++b) sum += __expf(Y[b * 900 + ss] - m);
  float inv = 1.0f / sum;
  for (int b = 0; b < 48; ++b) O[b * 900 + ss] = __expf(Y[b * 900 + ss] - m) * inv;
}

extern "C" void kernel_launch(void* const* d_in, const int* in_sizes, int n_in,
                              void* d_out, int out_size, void* d_ws, size_t ws_size,
                              hipStream_t stream) {
  (void)in_sizes; (void)n_in; (void)out_size;
  const float* X_en = (const float*)d_in[0];
  const float* X_de = (const float*)d_in[1];
  const float* conv1_w = (const float*)d_in[2];
  const float* conv1_b = (const float*)d_in[3];
  const float* conv2_w = (const float*)d_in[4];
  const float* conv2_b = (const float*)d_in[5];
  const float* enc_wq = (const float*)d_in[6];
  const float* enc_wk = (const float*)d_in[7];
  const float* enc_wv = (const float*)d_in[8];
  const float* enc_rel = (const float*)d_in[9];
  const float* enc_f1w = (const float*)d_in[10];
  const float* enc_f1b = (const float*)d_in[11];
  const float* enc_f2w = (const float*)d_in[12];
  const float* enc_f2b = (const float*)d_in[13];
  const float* dm_wq = (const float*)d_in[14];
  const float* dm_wk = (const float*)d_in[15];
  const float* dm_wv = (const float*)d_in[16];
  const float* dm_rel = (const float*)d_in[17];
  const float* dm_l1w = (const float*)d_in[18];
  const float* dm_l1b = (const float*)d_in[19];
  const float* dm_l2w = (const float*)d_in[20];
  const float* dm_l2b = (const float*)d_in[21];
  const float* dc_wq = (const float*)d_in[22];
  const float* dc_wk = (const float*)d_in[23];
  const float* dc_wv = (const float*)d_in[24];
  const float* dc_rel = (const float*)d_in[25];
  const float* d_f1w = (const float*)d_in[26];
  const float* d_f1b = (const float*)d_in[27];
  const float* d_f2w = (const float*)d_in[28];
  const float* d_f2b = (const float*)d_in[29];
  const float* out_w = (const float*)d_in[30];
  const float* out_b = (const float*)d_in[31];
  float* OUT = (float*)d_out;

  // ---- workspace layout: ~205 MiB ----
  const size_t SLOT = 22118400;  // 43200*256 bf16
  char* ws = (char*)d_ws;
  size_t o = 0;
  bf16* S1 = (bf16*)(ws + o); o += SLOT;  // XEb -> ENCb
  bf16* S2 = (bf16*)(ws + o); o += SLOT;  // XDb
  bf16* S3 = (bf16*)(ws + o); o += SLOT;  // o1 -> h2
  bf16* S4 = (bf16*)(ws + o); o += SLOT;  // h1 -> h3
  bf16* S5 = (bf16*)(ws + o); o += SLOT;  // attn-out / ffn-out
  char* U = ws + o; o += 33177600 + 3 * SLOT;  // Z(bf16) + QKV, union { HID, XR+C1R }
  bf16* Zb = (bf16*)U;
  bf16* QKV = (bf16*)(U + 33177600);
  bf16* XR = (bf16*)U;                    // conv phase only
  bf16* C1R = (bf16*)(U + 3145728);       // conv phase only
  bf16* HID = (bf16*)U;                   // FFN phase only
  bf16* wa = (bf16*)(ws + o); o += 4603904;
  float* Y = (float*)(ws + o); o += 172800;
  if (ws_size < o) return;  // need ~205 MiB

  // weight arena (element offsets)
  bf16* c1p = wa;                 // 9*(256x32)
  bf16* c2p = wa + 73728;         // 9*(256x256)
  bf16* EQKVw = wa + 663552;      // eq|ek|ev (768x256)
  bf16* MQKVw = wa + 860160;      // mq|mk|mv
  bf16* cqw = wa + 1056768;       // 256x256
  bf16* CKVw = wa + 1122304;      // ck|cv (512x256)
  bf16* ef1 = wa + 1253376;
  bf16* ef2 = wa + 1515520;
  bf16* df1 = wa + 1777664;
  bf16* df2 = wa + 2039808;

  auto cast = [&](const float* s, bf16* d, int n) {
    k_cast<<<dim3((n + 255) / 256), dim3(256), 0, stream>>>(s, d, n);
  };
  auto gemm = [&](const bf16* A, const bf16* B, const float* bias, bf16* C,
                  int M, int N, int K, int relu, int ldc, int coff) {
    k_gemm<<<dim3(M / 64, N / 64), dim3(256), 0, stream>>>(A, B, bias, C, M, N, K, relu, ldc, coff);
  };

  // ---- weight prep ----
  k_pack_conv<<<dim3(288), dim3(256), 0, stream>>>(conv1_w, c1p, 256, 32, 73728);
  k_pack_conv<<<dim3(2304), dim3(256), 0, stream>>>(conv2_w, c2p, 256, 256, 589824);
  cast(enc_wq, EQKVw, 65536); cast(enc_wk, EQKVw + 65536, 65536); cast(enc_wv, EQKVw + 131072, 65536);
  cast(dm_wq, MQKVw, 65536); cast(dm_wk, MQKVw + 65536, 65536); cast(dm_wv, MQKVw + 131072, 65536);
  cast(dc_wq, cqw, 65536);
  cast(dc_wk, CKVw, 65536); cast(dc_wv, CKVw + 65536, 65536);
  cast(enc_f1w, ef1, 262144); cast(enc_f2w, ef2, 262144);
  cast(d_f1w, df1, 262144); cast(d_f2w, df2, 262144);

  // ---- conv chains (implicit-im2col GEMM, 9 shifted passes) ----
  auto conv_chain = [&](const float* X, bf16* outB) {
    k_prep_x<<<dim3(6144), dim3(256), 0, stream>>>(X, XR);
    k_conv_gemm<32, 0, 32, 1024, 0, 0><<<dim3(675, 4), dim3(256), 0, stream>>>(XR, c1p, conv1_b, C1R);
    k_conv_gemm<256, 1, 30, 900, 1, 1><<<dim3(675, 4), dim3(256), 0, stream>>>(C1R, c2p, conv2_b, outB);
  };
  conv_chain(X_en, S1);
  conv_chain(X_de, S2);

  // ---- encoder ----
  gemm(S1, EQKVw, nullptr, QKV, 43200, 768, 256, 0, 768, 0);
  k_attn_z<0><<<dim3(900), dim3(256), 0, stream>>>(QKV, enc_rel, Zb, nullptr, nullptr, nullptr, nullptr);
  k_softmax_s<<<dim3(288), dim3(256), 0, stream>>>(Zb);
  k_attn_av<<<dim3(900), dim3(256), 0, stream>>>(Zb, QKV, S5);
  k_add_ln<<<dim3(10800), dim3(256), 0, stream>>>(S1, S5, S3);  // o1
  gemm(S3, ef1, enc_f1b, HID, 43200, 1024, 256, 1, 1024, 0);
  gemm(HID, ef2, enc_f2b, S5, 43200, 256, 1024, 0, 256, 0);
  k_add_ln<<<dim3(10800), dim3(256), 0, stream>>>(S3, S5, S1);  // enc_out

  // ---- decoder masked self-attention ----
  gemm(S2, MQKVw, nullptr, QKV, 43200, 768, 256, 0, 768, 0);
  k_attn_z<1><<<dim3(900), dim3(256), 0, stream>>>(QKV, dm_rel, Zb, dm_l1w, dm_l1b, dm_l2w, dm_l2b);
  k_softmax_s<<<dim3(288), dim3(256), 0, stream>>>(Zb);
  k_attn_av<<<dim3(900), dim3(256), 0, stream>>>(Zb, QKV, S5);
  k_add_ln<<<dim3(10800), dim3(256), 0, stream>>>(S2, S5, S4);  // h1

  // ---- cross attention ----
  gemm(S4, cqw, nullptr, QKV, 43200, 256, 256, 0, 768, 0);
  gemm(S1, CKVw, nullptr, QKV, 43200, 512, 256, 0, 768, 256);
  k_attn_z<0><<<dim3(900), dim3(256), 0, stream>>>(QKV, dc_rel, Zb, nullptr, nullptr, nullptr, nullptr);
  k_softmax_s<<<dim3(288), dim3(256), 0, stream>>>(Zb);
  k_attn_av<<<dim3(900), dim3(256), 0, stream>>>(Zb, QKV, S5);
  k_add_ln<<<dim3(10800), dim3(256), 0, stream>>>(S5, S4, S3);  // h2 = ln(c + h1)

  // ---- decoder FFN + head ----
  gemm(S3, df1, d_f1b, HID, 43200, 1024, 256, 1, 1024, 0);
  gemm(HID, df2, d_f2b, S5, 43200, 256, 1024, 0, 256, 0);
  k_add_ln<<<dim3(10800), dim3(256), 0, stream>>>(S3, S5, S4);  // h3
  k_ydot<<<dim3(10800), dim3(256), 0, stream>>>(S4, out_w, out_b, Y);
  k_softmax48<<<dim3(4), dim3(256), 0, stream>>>(Y, OUT);
}

// Round 4
// 1130.602 us; speedup vs baseline: 2.1073x; 1.4800x over previous
//
#include <hip/hip_runtime.h>
#include <float.h>

typedef __bf16 bf16;
typedef __attribute__((ext_vector_type(8))) __bf16 bf16x8;
typedef __attribute__((ext_vector_type(4))) __bf16 bf16x4;
typedef __attribute__((ext_vector_type(4))) float f32x4;

__device__ __forceinline__ int imin(int a, int b) { return a < b ? a : b; }

// async global->LDS, 16B per lane; LDS dest = wave-uniform base + lane*16
__device__ __forceinline__ void gl2lds(const bf16* g, bf16* l) {
  __builtin_amdgcn_global_load_lds(
      (const __attribute__((address_space(1))) void*)g,
      (__attribute__((address_space(3))) void*)l, 16, 0, 0);
}

// ---------------- zero the border zero-page (512 B) ----------------
__global__ void k_zero(bf16* zp) { zp[threadIdx.x] = (bf16)0.0f; }

// ---------------- fused f32->bf16 casts (13 segments) ----------------
struct CastSegs { const float* s[13]; bf16* d[13]; int n[13]; };
__global__ void k_cast_all(CastSegs sg, int total) {
  int i = blockIdx.x * 256 + threadIdx.x;
  if (i >= total) return;
  for (int k = 0; k < 13; ++k) {
    if (i < sg.n[k]) { sg.d[k][i] = (bf16)sg.s[k][i]; return; }
    i -= sg.n[k];
  }
}

// ---------------- X (b,32,32,32) -> XR rows (b*1024, 32ch) bf16 ----------------
__global__ void k_prep_x(const float* __restrict__ X, bf16* __restrict__ XR) {
  int idx = blockIdx.x * 256 + threadIdx.x;
  if (idx >= 48 * 1024 * 32) return;
  int b = idx >> 15, r = idx & 32767, pos = r >> 5, ic = r & 31;
  XR[idx] = (bf16)X[((size_t)(b * 32 + ic) << 10) + pos];
}

// ---------------- conv weight pack: (OC,IC,3,3) -> 9 x (OC,IC) bf16 ----------------
__global__ void k_pack_conv(const float* __restrict__ w, bf16* __restrict__ dst,
                            int OC, int IC, int total) {
  int idx = blockIdx.x * 256 + threadIdx.x;
  if (idx >= total) return;
  int t = idx / (OC * IC);
  int rem = idx - t * OC * IC;
  int oc = rem / IC, ic = rem - oc * IC;
  dst[idx] = (bf16)w[(size_t)(oc * IC + ic) * 9 + t];
}

// ---------------- 128x128 GEMM: C[m, coff+n] = A[M,K] x B[N,K]^T ----------------
// BK=32, global_load_lds staging, LDS-staged coalesced epilogue. N%128==0, K%32==0.
__global__ __launch_bounds__(256, 2) void k_gemm128(
    const bf16* __restrict__ A, const bf16* __restrict__ B,
    const float* __restrict__ bias, bf16* __restrict__ C,
    int M, int N, int K, int relu, int ldc, int coff) {
  __shared__ alignas(16) bf16 SM[8192];
  bf16* As = SM;
  bf16* Bs = SM + 4096;
  const int t = threadIdx.x, wave = t >> 6;
  const int lane = t & 63, fr = lane & 15, kq = lane >> 4;
  const int wm = wave & 1, wn = wave >> 1;
  const int m0 = blockIdx.x * 128, n0 = blockIdx.y * 128;
  const int srow = t >> 2, kseg = (t & 3) * 8;
  f32x4 acc[4][4] = {};
  const bf16* gA0 = A + (size_t)imin(m0 + srow, M - 1) * K + kseg;
  const bf16* gA1 = A + (size_t)imin(m0 + 64 + srow, M - 1) * K + kseg;
  const bf16* gB0 = B + (size_t)(n0 + srow) * K + kseg;
  const bf16* gB1 = B + (size_t)(n0 + 64 + srow) * K + kseg;
  bf16* sA0 = As + wave * 512;
  bf16* sA1 = As + 2048 + wave * 512;
  bf16* sB0 = Bs + wave * 512;
  bf16* sB1 = Bs + 2048 + wave * 512;
  for (int k0 = 0; k0 < K; k0 += 32) {
    gl2lds(gA0 + k0, sA0);
    gl2lds(gA1 + k0, sA1);
    gl2lds(gB0 + k0, sB0);
    gl2lds(gB1 + k0, sB1);
    __syncthreads();
    bf16x8 af[4], bw[4];
    for (int mt = 0; mt < 4; ++mt)
      af[mt] = *(const bf16x8*)(As + (wm * 64 + mt * 16 + fr) * 32 + kq * 8);
    for (int nt = 0; nt < 4; ++nt)
      bw[nt] = *(const bf16x8*)(Bs + (wn * 64 + nt * 16 + fr) * 32 + kq * 8);
    for (int mt = 0; mt < 4; ++mt)
      for (int nt = 0; nt < 4; ++nt)
        acc[mt][nt] = __builtin_amdgcn_mfma_f32_16x16x32_bf16(af[mt], bw[nt], acc[mt][nt], 0, 0, 0);
    __syncthreads();
  }
  bf16* Cst = SM;  // 64 x 128
  for (int half = 0; half < 2; ++half) {
    if (wm == half) {
      for (int mt = 0; mt < 4; ++mt)
        for (int nt = 0; nt < 4; ++nt) {
          int n = n0 + wn * 64 + nt * 16 + fr;
          float bv = bias ? bias[n] : 0.0f;
          for (int r = 0; r < 4; ++r) {
            float v = acc[mt][nt][r] + bv;
            if (relu) v = fmaxf(v, 0.0f);
            Cst[(mt * 16 + kq * 4 + r) * 128 + wn * 64 + nt * 16 + fr] = (bf16)v;
          }
        }
    }
    __syncthreads();
    for (int i = t; i < 1024; i += 256) {
      int r = i >> 4, cs = i & 15;
      int gm = m0 + half * 64 + r;
      if (gm < M)
        *(bf16x8*)(C + (size_t)gm * ldc + coff + n0 + cs * 8) = *(const bf16x8*)(Cst + r * 128 + cs * 8);
    }
    __syncthreads();
  }
}

// ---------------- conv as 9-pass shifted 128x128 GEMM (implicit im2col) ----------------
// A rows: (b, srcpos, CIN). Bp: 9 stacked (256, CIN). Output m = b*900+y*30+x.
// TRANS: write NCHW-flat (b, oc, p); else rows (m, 256). M = 43200 fixed.
template <int CIN, int PAD, int SRCW, int SRCROWS, int CHECK, int TRANS>
__global__ __launch_bounds__(256, 2) void k_conv128(
    const bf16* __restrict__ A, const bf16* __restrict__ Bp,
    const float* __restrict__ bias, bf16* __restrict__ C,
    const bf16* __restrict__ zpage) {
  __shared__ alignas(16) bf16 SM[8192];
  bf16* As = SM;
  bf16* Bs = SM + 4096;
  const int t = threadIdx.x, wave = t >> 6;
  const int lane = t & 63, fr = lane & 15, kq = lane >> 4;
  const int wm = wave & 1, wn = wave >> 1;
  const int m0 = blockIdx.x * 128, n0 = blockIdx.y * 128;
  const int srow = t >> 2, kseg = (t & 3) * 8;
  f32x4 acc[4][4] = {};
  int bb[2], yy[2], xx[2];
  for (int hf = 0; hf < 2; ++hf) {
    int m = imin(m0 + hf * 64 + srow, 43199);
    int b = m / 900, p = m - b * 900;
    bb[hf] = b; yy[hf] = p / 30; xx[hf] = p - (p / 30) * 30;
  }
  bf16* sA0 = As + wave * 512;
  bf16* sA1 = As + 2048 + wave * 512;
  bf16* sB0 = Bs + wave * 512;
  bf16* sB1 = Bs + 2048 + wave * 512;
  for (int t9 = 0; t9 < 9; ++t9) {
    const int ky = t9 / 3, kx = t9 - ky * 3;
    const bf16* ga[2];
    for (int hf = 0; hf < 2; ++hf) {
      int sy = yy[hf] + ky - PAD, sx = xx[hf] + kx - PAD;
      bool valid = !CHECK || (sy >= 0 && sy < SRCW && sx >= 0 && sx < SRCW);
      ga[hf] = (valid ? A + (size_t)(bb[hf] * SRCROWS + sy * SRCW + sx) * CIN : zpage) + kseg;
    }
    const bf16* gb = Bp + (size_t)(t9 * 256 + n0 + srow) * CIN + kseg;
    for (int k0 = 0; k0 < CIN; k0 += 32) {
      gl2lds(ga[0] + k0, sA0);
      gl2lds(ga[1] + k0, sA1);
      gl2lds(gb + k0, sB0);
      gl2lds(gb + (size_t)64 * CIN + k0, sB1);
      __syncthreads();
      bf16x8 af[4], bw[4];
      for (int mt = 0; mt < 4; ++mt)
        af[mt] = *(const bf16x8*)(As + (wm * 64 + mt * 16 + fr) * 32 + kq * 8);
      for (int nt = 0; nt < 4; ++nt)
        bw[nt] = *(const bf16x8*)(Bs + (wn * 64 + nt * 16 + fr) * 32 + kq * 8);
      for (int mt = 0; mt < 4; ++mt)
        for (int nt = 0; nt < 4; ++nt)
          acc[mt][nt] = __builtin_amdgcn_mfma_f32_16x16x32_bf16(af[mt], bw[nt], acc[mt][nt], 0, 0, 0);
      __syncthreads();
    }
  }
  bf16* Cst = SM;
  for (int half = 0; half < 2; ++half) {
    if (wm == half) {
      for (int mt = 0; mt < 4; ++mt)
        for (int nt = 0; nt < 4; ++nt) {
          int n = n0 + wn * 64 + nt * 16 + fr;
          float bv = bias[n];
          for (int r = 0; r < 4; ++r) {
            float v = acc[mt][nt][r] + bv;
            if (TRANS)  // Cst[oc 128][p 64]
              Cst[(wn * 64 + nt * 16 + fr) * 64 + mt * 16 + kq * 4 + r] = (bf16)v;
            else        // Cst[row 64][col 128]
              Cst[(mt * 16 + kq * 4 + r) * 128 + wn * 64 + nt * 16 + fr] = (bf16)v;
          }
        }
    }
    __syncthreads();
    if (TRANS) {
      // p%4==0 chunks never cross a batch boundary (900 % 4 == 0)
      for (int i = t; i < 2048; i += 256) {
        int oc = i >> 4, pc = i & 15;
        int gm = m0 + half * 64 + pc * 4;
        if (gm < 43200) {
          int b = gm / 900, p = gm - b * 900;
          *(bf16x4*)(C + (size_t)(b * 256 + n0 + oc) * 900 + p) = *(const bf16x4*)(Cst + oc * 64 + pc * 4);
        }
      }
    } else {
      for (int i = t; i < 1024; i += 256) {
        int r = i >> 4, cs = i & 15;
        int gm = m0 + half * 64 + r;
        if (gm < 43200)
          *(bf16x8*)(C + (size_t)gm * 256 + n0 + cs * 8) = *(const bf16x8*)(Cst + r * 128 + cs * 8);
      }
    }
    __syncthreads();
  }
}

// ---------------- attention logits z for one (s,h); MFMA; vectorized Z stores ----------------
template <int MASKED>
__global__ __launch_bounds__(256, MASKED ? 3 : 4) void k_attn_z(
    const bf16* __restrict__ QKV, const float* __restrict__ relw, bf16* __restrict__ Z,
    const float* __restrict__ l1w, const float* __restrict__ l1b,
    const float* __restrict__ l2w, const float* __restrict__ l2b) {
  __shared__ alignas(16) bf16 Rt[48 * 40];
  __shared__ float EMD[48 * 49];
  __shared__ alignas(16) bf16 zst[48 * 48];
  __shared__ alignas(16) bf16 Sc[MASKED ? 48 * 72 : 8];
  __shared__ alignas(16) bf16 L1b[MASKED ? 48 * 72 : 8];
  __shared__ alignas(16) bf16 L2b[MASKED ? 48 * 72 : 8];
  __shared__ alignas(16) bf16 T2b[MASKED ? 48 * 72 : 8];
  const int sh = blockIdx.x, s = sh >> 3, h = sh & 7;
  const int t = threadIdx.x, wave = t >> 6, lane = t & 63, fr = lane & 15, kq = lane >> 4;
  const float scale = 0.17677669529663687f;  // 1/sqrt(32)
  if constexpr (MASKED) {
    for (int i = t; i < 48 * 72; i += 256) {
      int r = i / 72, c = i - r * 72;
      bf16 z0 = (bf16)0.0f;
      L1b[i] = (c < 48) ? (bf16)l1w[r * 48 + c] : z0;
      L2b[i] = (c < 48) ? (bf16)l2w[r * 48 + c] : z0;
      Sc[i] = z0;
      T2b[i] = z0;
    }
  }
  {
    const float* rb = relw + (size_t)sh * 1536;
    for (int i = t; i < 1536; i += 256) {
      int k = i / 48, j = i - k * 48;
      Rt[j * 40 + k] = (bf16)rb[i];
    }
  }
  __syncthreads();
  f32x4 sreg[3];
  int u = 0;
  for (int t9 = wave; t9 < 9; t9 += 4, ++u) {
    int ti = t9 / 3, tj = t9 - ti * 3;
    bf16x8 af = *(const bf16x8*)(QKV + (size_t)(s * 48 + ti * 16 + fr) * 768 + h * 32 + kq * 8);
    bf16x8 bk = *(const bf16x8*)(QKV + (size_t)(s * 48 + tj * 16 + fr) * 768 + 256 + h * 32 + kq * 8);
    bf16x8 rf = *(const bf16x8*)(Rt + (tj * 16 + fr) * 40 + kq * 8);
    f32x4 sacc = {}, eacc = {};
    sacc = __builtin_amdgcn_mfma_f32_16x16x32_bf16(af, bk, sacc, 0, 0, 0);
    eacc = __builtin_amdgcn_mfma_f32_16x16x32_bf16(af, rf, eacc, 0, 0, 0);
    for (int r = 0; r < 4; ++r)
      EMD[(ti * 16 + kq * 4 + r) * 49 + tj * 16 + fr] = eacc[r];
    if constexpr (MASKED) {
      for (int r = 0; r < 4; ++r)
        Sc[(ti * 16 + kq * 4 + r) * 72 + tj * 16 + fr] = (bf16)(sacc[r] * scale);
    } else {
      for (int r = 0; r < 4; ++r) sreg[u][r] = sacc[r] * scale;
    }
  }
  __syncthreads();
  if constexpr (!MASKED) {
    u = 0;
    for (int t9 = wave; t9 < 9; t9 += 4, ++u) {
      int ti = t9 / 3, tj = t9 - ti * 3;
      for (int r = 0; r < 4; ++r) {
        int i = ti * 16 + kq * 4 + r, j = tj * 16 + fr;
        float v = sreg[u][r];
        if (j <= i) v += EMD[i * 49 + 47 + j - i];
        zst[i * 48 + j] = (bf16)v;
      }
    }
  } else {
    for (int t9 = wave; t9 < 9; t9 += 4) {
      int ti = t9 / 3, tj = t9 - ti * 3;
      f32x4 a2 = {};
      for (int k0 = 0; k0 < 64; k0 += 32) {
        bf16x8 af = *(const bf16x8*)(Sc + (ti * 16 + fr) * 72 + k0 + kq * 8);
        bf16x8 bw = *(const bf16x8*)(L1b + (tj * 16 + fr) * 72 + k0 + kq * 8);
        a2 = __builtin_amdgcn_mfma_f32_16x16x32_bf16(af, bw, a2, 0, 0, 0);
      }
      for (int r = 0; r < 4; ++r) {
        int i = ti * 16 + kq * 4 + r, a = tj * 16 + fr;
        T2b[a * 72 + i] = (bf16)(a2[r] + l1b[a]);
      }
    }
    __syncthreads();
    for (int t9 = wave; t9 < 9; t9 += 4) {
      int ti = t9 / 3, tj = t9 - ti * 3;
      f32x4 a2 = {};
      for (int k0 = 0; k0 < 64; k0 += 32) {
        bf16x8 af = *(const bf16x8*)(T2b + (ti * 16 + fr) * 72 + k0 + kq * 8);
        bf16x8 bw = *(const bf16x8*)(L2b + (tj * 16 + fr) * 72 + k0 + kq * 8);
        a2 = __builtin_amdgcn_mfma_f32_16x16x32_bf16(af, bw, a2, 0, 0, 0);
      }
      for (int r = 0; r < 4; ++r) {
        int aa = ti * 16 + kq * 4 + r, cc = tj * 16 + fr;
        float v;
        if (cc > aa) v = -10000.0f;  // masked column -> exactly uniform after softmax
        else v = a2[r] + l2b[cc] + EMD[aa * 49 + 47 + cc - aa];
        zst[aa * 48 + cc] = (bf16)v;
      }
    }
  }
  __syncthreads();
  bf16* zb = Z + (size_t)sh * 2304;
  for (int c = t; c < 288; c += 256)
    *(bf16x8*)(zb + c * 8) = *(const bf16x8*)(zst + c * 8);
}

// ---------------- per-column (over s=900) online max & inverse-sum ----------------
__global__ __launch_bounds__(256) void k_colstats(const bf16* __restrict__ Z,
                                                  float* __restrict__ Mc, float* __restrict__ Ic) {
  __shared__ float rm[4][64], rs[4][64];
  const int t = threadIdx.x, tc = t & 63, sg = t >> 6;
  const int col = blockIdx.x * 64 + tc;
  const bf16* p = Z + col;
  float m = -FLT_MAX, ssum = 0.0f;
  for (int s = sg * 225; s < sg * 225 + 225; ++s) {
    float v = (float)p[(size_t)s * 18432];
    if (v > m) { ssum *= __expf(m - v); m = v; }
    ssum += __expf(v - m);
  }
  rm[sg][tc] = m; rs[sg][tc] = ssum;
  __syncthreads();
  if (sg == 0) {
    float M2 = fmaxf(fmaxf(rm[0][tc], rm[1][tc]), fmaxf(rm[2][tc], rm[3][tc]));
    float S2 = 0.0f;
    for (int g = 0; g < 4; ++g) S2 += rs[g][tc] * __expf(rm[g][tc] - M2);
    Mc[col] = M2;
    Ic[col] = 1.0f / S2;
  }
}

// ---------------- O[s,h,i,d] = sum_j softmax(Z)[s,h,i,j] V[s,h,j,d] (normalize fused) ----------------
__global__ __launch_bounds__(256, 4) void k_attn_av(
    const bf16* __restrict__ Z, const bf16* __restrict__ QKV,
    const float* __restrict__ Mc, const float* __restrict__ Ic, bf16* __restrict__ O) {
  __shared__ alignas(16) bf16 Ps[48 * 72];
  __shared__ alignas(16) bf16 Vt[32 * 72];
  __shared__ alignas(16) bf16 Ost[48 * 32];
  const int sh = blockIdx.x, s = sh >> 3, h = sh & 7;
  const int t = threadIdx.x, wave = t >> 6, lane = t & 63, fr = lane & 15, kq = lane >> 4;
  for (int i = t; i < 48 * 72; i += 256) Ps[i] = (bf16)0.0f;
  for (int i = t; i < 32 * 72; i += 256) Vt[i] = (bf16)0.0f;
  __syncthreads();
  const bf16* zb = Z + (size_t)sh * 2304;
  const float* mc = Mc + h * 2304;
  const float* ic = Ic + h * 2304;
  for (int c = t; c < 288; c += 256) {
    int r = c / 6, seg = c - r * 6;
    int idx = r * 48 + seg * 8;
    bf16x8 zv = *(const bf16x8*)(zb + idx);
    f32x4 m0v = *(const f32x4*)(mc + idx), m1v = *(const f32x4*)(mc + idx + 4);
    f32x4 i0v = *(const f32x4*)(ic + idx), i1v = *(const f32x4*)(ic + idx + 4);
    bf16x8 pv;
    for (int e = 0; e < 4; ++e) pv[e] = (bf16)(__expf((float)zv[e] - m0v[e]) * i0v[e]);
    for (int e = 0; e < 4; ++e) pv[4 + e] = (bf16)(__expf((float)zv[4 + e] - m1v[e]) * i1v[e]);
    *(bf16x8*)(Ps + r * 72 + seg * 8) = pv;
  }
  for (int i = t; i < 1536; i += 256) {
    int j = i >> 5, d = i & 31;
    Vt[d * 72 + j] = QKV[(size_t)(s * 48 + j) * 768 + 512 + h * 32 + d];
  }
  __syncthreads();
  for (int t6 = wave; t6 < 6; t6 += 4) {
    int ti = t6 >> 1, td = t6 & 1;
    f32x4 a2 = {};
    for (int k0 = 0; k0 < 64; k0 += 32) {
      bf16x8 af = *(const bf16x8*)(Ps + (ti * 16 + fr) * 72 + k0 + kq * 8);
      bf16x8 bv = *(const bf16x8*)(Vt + (td * 16 + fr) * 72 + k0 + kq * 8);
      a2 = __builtin_amdgcn_mfma_f32_16x16x32_bf16(af, bv, a2, 0, 0, 0);
    }
    for (int r = 0; r < 4; ++r)
      Ost[(ti * 16 + kq * 4 + r) * 32 + td * 16 + fr] = (bf16)a2[r];
  }
  __syncthreads();
  bf16* ob = O + (size_t)sh * 1536;
  for (int c = t; c < 192; c += 256)
    *(bf16x8*)(ob + c * 8) = *(const bf16x8*)(Ost + c * 8);
}

// ---------------- out = LN(Xa + Xb), rows of 256, bf16 ----------------
__global__ __launch_bounds__(256) void k_add_ln(
    const bf16* __restrict__ Xa, const bf16* __restrict__ Xb, bf16* __restrict__ out) {
  const int t = threadIdx.x, lane = t & 63, w = t >> 6;
  const size_t off = ((size_t)blockIdx.x * 4 + w) * 256 + lane * 4;
  bf16x4 av = *(const bf16x4*)(Xa + off);
  bf16x4 bv = *(const bf16x4*)(Xb + off);
  f32x4 x;
  for (int c = 0; c < 4; ++c) x[c] = (float)av[c] + (float)bv[c];
  float sum = x[0] + x[1] + x[2] + x[3];
  for (int o = 1; o < 64; o <<= 1) sum += __shfl_xor(sum, o);
  float mean = sum * (1.0f / 256.0f);
  float q = 0.0f;
  for (int c = 0; c < 4; ++c) { float d = x[c] - mean; q += d * d; }
  for (int o = 1; o < 64; o <<= 1) q += __shfl_xor(q, o);
  float rstd = rsqrtf(q * (1.0f / 256.0f) + 1e-5f);
  bf16x4 y;
  for (int c = 0; c < 4; ++c) y[c] = (bf16)((x[c] - mean) * rstd);
  *(bf16x4*)(out + off) = y;
}

// ---------------- y[m] = dot(H[m,:256], w) + b ----------------
__global__ __launch_bounds__(256) void k_ydot(
    const bf16* __restrict__ H, const float* __restrict__ w,
    const float* __restrict__ b, float* __restrict__ Y) {
  const int t = threadIdx.x, lane = t & 63, wv = t >> 6;
  const size_t row = (size_t)blockIdx.x * 4 + wv;
  bf16x4 hx = *(const bf16x4*)(H + row * 256 + lane * 4);
  f32x4 ww = *(const f32x4*)(w + lane * 4);
  float s = (float)hx[0] * ww[0] + (float)hx[1] * ww[1] + (float)hx[2] * ww[2] + (float)hx[3] * ww[3];
  for (int o = 1; o < 64; o <<= 1) s += __shfl_xor(s, o);
  if (lane == 0) Y[row] = s + b[0];
}

// ---------------- softmax over b (48) per column ----------------
__global__ void k_softmax48(const float* __restrict__ Y, float* __restrict__ O) {
  int ss = blockIdx.x * 256 + threadIdx.x;
  if (ss >= 900) return;
  float m = -FLT_MAX;
  for (int b = 0; b < 48; ++b) m = fmaxf(m, Y[b * 900 + ss]);
  float sum = 0.0f;
  for (int b = 0; b < 48; ++b) sum += __expf(Y[b * 900 + ss] - m);
  float inv = 1.0f / sum;
  for (int b = 0; b < 48; ++b) O[b * 900 + ss] = __expf(Y[b * 900 + ss] - m) * inv;
}

extern "C" void kernel_launch(void* const* d_in, const int* in_sizes, int n_in,
                              void* d_out, int out_size, void* d_ws, size_t ws_size,
                              hipStream_t stream) {
  (void)in_sizes; (void)n_in; (void)out_size;
  const float* X_en = (const float*)d_in[0];
  const float* X_de = (const float*)d_in[1];
  const float* conv1_w = (const float*)d_in[2];
  const float* conv1_b = (const float*)d_in[3];
  const float* conv2_w = (const float*)d_in[4];
  const float* conv2_b = (const float*)d_in[5];
  const float* enc_wq = (const float*)d_in[6];
  const float* enc_wk = (const float*)d_in[7];
  const float* enc_wv = (const float*)d_in[8];
  const float* enc_rel = (const float*)d_in[9];
  const float* enc_f1w = (const float*)d_in[10];
  const float* enc_f1b = (const float*)d_in[11];
  const float* enc_f2w = (const float*)d_in[12];
  const float* enc_f2b = (const float*)d_in[13];
  const float* dm_wq = (const float*)d_in[14];
  const float* dm_wk = (const float*)d_in[15];
  const float* dm_wv = (const float*)d_in[16];
  const float* dm_rel = (const float*)d_in[17];
  const float* dm_l1w = (const float*)d_in[18];
  const float* dm_l1b = (const float*)d_in[19];
  const float* dm_l2w = (const float*)d_in[20];
  const float* dm_l2b = (const float*)d_in[21];
  const float* dc_wq = (const float*)d_in[22];
  const float* dc_wk = (const float*)d_in[23];
  const float* dc_wv = (const float*)d_in[24];
  const float* dc_rel = (const float*)d_in[25];
  const float* d_f1w = (const float*)d_in[26];
  const float* d_f1b = (const float*)d_in[27];
  const float* d_f2w = (const float*)d_in[28];
  const float* d_f2b = (const float*)d_in[29];
  const float* out_w = (const float*)d_in[30];
  const float* out_b = (const float*)d_in[31];
  float* OUT = (float*)d_out;

  // ---- workspace layout: 214,901,504 bytes (same as R3) ----
  const size_t SLOT = 22118400;  // 43200*256 bf16
  char* ws = (char*)d_ws;
  size_t o = 0;
  bf16* S1 = (bf16*)(ws + o); o += SLOT;  // XEb -> ENCb
  bf16* S2 = (bf16*)(ws + o); o += SLOT;  // XDb    (dead after dm QKV -> cross stats)
  bf16* S3 = (bf16*)(ws + o); o += SLOT;  // o1 -> h2 (dead during dm attn -> dm stats)
  bf16* S4 = (bf16*)(ws + o); o += SLOT;  // h1 -> h3 (unused during enc -> enc stats)
  bf16* S5 = (bf16*)(ws + o); o += SLOT;  // attn-out / ffn-out
  char* U = ws + o; o += 33177600 + 3 * SLOT;  // Z + QKV, union { HID, XR+C1R }
  bf16* Zb = (bf16*)U;
  bf16* QKV = (bf16*)(U + 33177600);
  bf16* XR = (bf16*)U;                    // conv phase only
  bf16* C1R = (bf16*)(U + 3145728);       // conv phase only
  bf16* HID = (bf16*)U;                   // FFN phase only
  bf16* wa = (bf16*)(ws + o); o += 4603904;
  float* Y = (float*)(ws + o); o += 172800;
  if (ws_size < o) return;

  bf16* zpage = (bf16*)Y;  // 512 B zero page; Y is dead until k_ydot (convs done by then)
  // per-phase softmax stats (147 KB each) in dead activation slots
  float* encM = (float*)S4; float* encI = encM + 18432;
  float* dmM  = (float*)S3; float* dmI  = dmM + 18432;
  float* crM  = (float*)S2; float* crI  = crM + 18432;

  // weight arena (element offsets)
  bf16* c1p = wa;                 // 9*(256x32)
  bf16* c2p = wa + 73728;         // 9*(256x256)
  bf16* EQKVw = wa + 663552;      // eq|ek|ev (768x256)
  bf16* MQKVw = wa + 860160;      // mq|mk|mv
  bf16* cqw = wa + 1056768;       // 256x256
  bf16* CKVw = wa + 1122304;      // ck|cv (512x256)
  bf16* ef1 = wa + 1253376;
  bf16* ef2 = wa + 1515520;
  bf16* df1 = wa + 1777664;
  bf16* df2 = wa + 2039808;

  auto gemm = [&](const bf16* A, const bf16* B, const float* bias, bf16* C,
                  int M, int N, int K, int relu, int ldc, int coff) {
    k_gemm128<<<dim3((M + 127) / 128, N / 128), dim3(256), 0, stream>>>(
        A, B, bias, C, M, N, K, relu, ldc, coff);
  };

  // ---- weight prep (fused) ----
  k_zero<<<dim3(1), dim3(256), 0, stream>>>(zpage);
  k_pack_conv<<<dim3(288), dim3(256), 0, stream>>>(conv1_w, c1p, 256, 32, 73728);
  k_pack_conv<<<dim3(2304), dim3(256), 0, stream>>>(conv2_w, c2p, 256, 256, 589824);
  {
    CastSegs sg;
    const float* srcs[13] = {enc_wq, enc_wk, enc_wv, dm_wq, dm_wk, dm_wv, dc_wq,
                             dc_wk, dc_wv, enc_f1w, enc_f2w, d_f1w, d_f2w};
    bf16* dsts[13] = {EQKVw, EQKVw + 65536, EQKVw + 131072, MQKVw, MQKVw + 65536,
                      MQKVw + 131072, cqw, CKVw, CKVw + 65536, ef1, ef2, df1, df2};
    int ns[13] = {65536, 65536, 65536, 65536, 65536, 65536, 65536, 65536, 65536,
                  262144, 262144, 262144, 262144};
    int total = 0;
    for (int k = 0; k < 13; ++k) { sg.s[k] = srcs[k]; sg.d[k] = dsts[k]; sg.n[k] = ns[k]; total += ns[k]; }
    k_cast_all<<<dim3((total + 255) / 256), dim3(256), 0, stream>>>(sg, total);
  }

  // ---- conv chains ----
  auto conv_chain = [&](const float* X, bf16* outB) {
    k_prep_x<<<dim3(6144), dim3(256), 0, stream>>>(X, XR);
    k_conv128<32, 0, 32, 1024, 0, 0><<<dim3(338, 2), dim3(256), 0, stream>>>(XR, c1p, conv1_b, C1R, zpage);
    k_conv128<256, 1, 30, 900, 1, 1><<<dim3(338, 2), dim3(256), 0, stream>>>(C1R, c2p, conv2_b, outB, zpage);
  };
  conv_chain(X_en, S1);
  conv_chain(X_de, S2);

  // ---- encoder ----
  gemm(S1, EQKVw, nullptr, QKV, 43200, 768, 256, 0, 768, 0);
  k_attn_z<0><<<dim3(7200), dim3(256), 0, stream>>>(QKV, enc_rel, Zb, nullptr, nullptr, nullptr, nullptr);
  k_colstats<<<dim3(288), dim3(256), 0, stream>>>(Zb, encM, encI);
  k_attn_av<<<dim3(7200), dim3(256), 0, stream>>>(Zb, QKV, encM, encI, S5);
  k_add_ln<<<dim3(10800), dim3(256), 0, stream>>>(S1, S5, S3);  // o1
  gemm(S3, ef1, enc_f1b, HID, 43200, 1024, 256, 1, 1024, 0);
  gemm(HID, ef2, enc_f2b, S5, 43200, 256, 1024, 0, 256, 0);
  k_add_ln<<<dim3(10800), dim3(256), 0, stream>>>(S3, S5, S1);  // enc_out

  // ---- decoder masked self-attention ----
  gemm(S2, MQKVw, nullptr, QKV, 43200, 768, 256, 0, 768, 0);
  k_attn_z<1><<<dim3(7200), dim3(256), 0, stream>>>(QKV, dm_rel, Zb, dm_l1w, dm_l1b, dm_l2w, dm_l2b);
  k_colstats<<<dim3(288), dim3(256), 0, stream>>>(Zb, dmM, dmI);
  k_attn_av<<<dim3(7200), dim3(256), 0, stream>>>(Zb, QKV, dmM, dmI, S5);
  k_add_ln<<<dim3(10800), dim3(256), 0, stream>>>(S2, S5, S4);  // h1

  // ---- cross attention ----
  gemm(S4, cqw, nullptr, QKV, 43200, 256, 256, 0, 768, 0);
  gemm(S1, CKVw, nullptr, QKV, 43200, 512, 256, 0, 768, 256);
  k_attn_z<0><<<dim3(7200), dim3(256), 0, stream>>>(QKV, dc_rel, Zb, nullptr, nullptr, nullptr, nullptr);
  k_colstats<<<dim3(288), dim3(256), 0, stream>>>(Zb, crM, crI);
  k_attn_av<<<dim3(7200), dim3(256), 0, stream>>>(Zb, QKV, crM, crI, S5);
  k_add_ln<<<dim3(10800), dim3(256), 0, stream>>>(S5, S4, S3);  // h2 = ln(c + h1)

  // ---- decoder FFN + head ----
  gemm(S3, df1, d_f1b, HID, 43200, 1024, 256, 1, 1024, 0);
  gemm(HID, df2, d_f2b, S5, 43200, 256, 1024, 0, 256, 0);
  k_add_ln<<<dim3(10800), dim3(256), 0, stream>>>(S3, S5, S4);  // h3
  k_ydot<<<dim3(10800), dim3(256), 0, stream>>>(S4, out_w, out_b, Y);
  k_softmax48<<<dim3(4), dim3(256), 0, stream>>>(Y, OUT);
}

// Round 5
// 1124.800 us; speedup vs baseline: 2.1182x; 1.0052x over previous
//
#include <hip/hip_runtime.h>
#include <float.h>

typedef __bf16 bf16;
typedef __attribute__((ext_vector_type(8))) __bf16 bf16x8;
typedef __attribute__((ext_vector_type(4))) __bf16 bf16x4;
typedef __attribute__((ext_vector_type(4))) float f32x4;

__device__ __forceinline__ int imin(int a, int b) { return a < b ? a : b; }

// async global->LDS, 16B per lane; LDS dest = wave-uniform base + lane*16
__device__ __forceinline__ void gl2lds(const bf16* g, bf16* l) {
  __builtin_amdgcn_global_load_lds(
      (const __attribute__((address_space(1))) void*)g,
      (__attribute__((address_space(3))) void*)l, 16, 0, 0);
}

// ---------------- zero the border zero-page (512 B) ----------------
__global__ void k_zero(bf16* zp) { zp[threadIdx.x] = (bf16)0.0f; }

// ---------------- fused f32->bf16 casts (13 segments) ----------------
struct CastSegs { const float* s[13]; bf16* d[13]; int n[13]; };
__global__ void k_cast_all(CastSegs sg, int total) {
  int i = blockIdx.x * 256 + threadIdx.x;
  if (i >= total) return;
  for (int k = 0; k < 13; ++k) {
    if (i < sg.n[k]) { sg.d[k][i] = (bf16)sg.s[k][i]; return; }
    i -= sg.n[k];
  }
}

// ---------------- rel (sh, k*48+j) fp32 -> RelT (sh, j*32+k) bf16 ----------------
__global__ void k_prep_rel(const float* __restrict__ rel, bf16* __restrict__ RelT) {
  int idx = blockIdx.x * 256 + threadIdx.x;  // dest-linear
  if (idx >= 7200 * 1536) return;
  int sh = idx >> 9;  sh /= 3;               // idx / 1536
  int r = idx - sh * 1536;
  int j = r >> 5, k = r & 31;
  RelT[idx] = (bf16)rel[(size_t)sh * 1536 + k * 48 + j];
}

// ---------------- l1w/l2w (48x48 fp32) -> padded bf16 (48x72, K-pad 0) ----------------
__global__ void k_prep_lin(const float* __restrict__ l1w, const float* __restrict__ l2w,
                           bf16* __restrict__ L1p, bf16* __restrict__ L2p) {
  for (int i = threadIdx.x; i < 3456; i += 256) {
    int r = i / 72, c = i - r * 72;
    L1p[i] = (c < 48) ? (bf16)l1w[r * 48 + c] : (bf16)0.0f;
    L2p[i] = (c < 48) ? (bf16)l2w[r * 48 + c] : (bf16)0.0f;
  }
}

// ---------------- X (b,32,32,32) -> XR rows (b*1024, 32ch) bf16 ----------------
__global__ void k_prep_x(const float* __restrict__ X, bf16* __restrict__ XR) {
  int idx = blockIdx.x * 256 + threadIdx.x;
  if (idx >= 48 * 1024 * 32) return;
  int b = idx >> 15, r = idx & 32767, pos = r >> 5, ic = r & 31;
  XR[idx] = (bf16)X[((size_t)(b * 32 + ic) << 10) + pos];
}

// ---------------- conv weight pack: (OC,IC,3,3) -> 9 x (OC,IC) bf16 ----------------
__global__ void k_pack_conv(const float* __restrict__ w, bf16* __restrict__ dst,
                            int OC, int IC, int total) {
  int idx = blockIdx.x * 256 + threadIdx.x;
  if (idx >= total) return;
  int t = idx / (OC * IC);
  int rem = idx - t * OC * IC;
  int oc = rem / IC, ic = rem - oc * IC;
  dst[idx] = (bf16)w[(size_t)(oc * IC + ic) * 9 + t];
}

// ---------------- 128x128 GEMM: C[m, coff+n] = A[M,K] x B[N,K]^T ----------------
__global__ __launch_bounds__(256, 2) void k_gemm128(
    const bf16* __restrict__ A, const bf16* __restrict__ B,
    const float* __restrict__ bias, bf16* __restrict__ C,
    int M, int N, int K, int relu, int ldc, int coff) {
  __shared__ alignas(16) bf16 SM[8192];
  bf16* As = SM;
  bf16* Bs = SM + 4096;
  const int t = threadIdx.x, wave = t >> 6;
  const int lane = t & 63, fr = lane & 15, kq = lane >> 4;
  const int wm = wave & 1, wn = wave >> 1;
  const int m0 = blockIdx.x * 128, n0 = blockIdx.y * 128;
  const int srow = t >> 2, kseg = (t & 3) * 8;
  f32x4 acc[4][4] = {};
  const bf16* gA0 = A + (size_t)imin(m0 + srow, M - 1) * K + kseg;
  const bf16* gA1 = A + (size_t)imin(m0 + 64 + srow, M - 1) * K + kseg;
  const bf16* gB0 = B + (size_t)(n0 + srow) * K + kseg;
  const bf16* gB1 = B + (size_t)(n0 + 64 + srow) * K + kseg;
  bf16* sA0 = As + wave * 512;
  bf16* sA1 = As + 2048 + wave * 512;
  bf16* sB0 = Bs + wave * 512;
  bf16* sB1 = Bs + 2048 + wave * 512;
  for (int k0 = 0; k0 < K; k0 += 32) {
    gl2lds(gA0 + k0, sA0);
    gl2lds(gA1 + k0, sA1);
    gl2lds(gB0 + k0, sB0);
    gl2lds(gB1 + k0, sB1);
    __syncthreads();
    bf16x8 af[4], bw[4];
    for (int mt = 0; mt < 4; ++mt)
      af[mt] = *(const bf16x8*)(As + (wm * 64 + mt * 16 + fr) * 32 + kq * 8);
    for (int nt = 0; nt < 4; ++nt)
      bw[nt] = *(const bf16x8*)(Bs + (wn * 64 + nt * 16 + fr) * 32 + kq * 8);
    for (int mt = 0; mt < 4; ++mt)
      for (int nt = 0; nt < 4; ++nt)
        acc[mt][nt] = __builtin_amdgcn_mfma_f32_16x16x32_bf16(af[mt], bw[nt], acc[mt][nt], 0, 0, 0);
    __syncthreads();
  }
  bf16* Cst = SM;  // 64 x 128
  for (int half = 0; half < 2; ++half) {
    if (wm == half) {
      for (int mt = 0; mt < 4; ++mt)
        for (int nt = 0; nt < 4; ++nt) {
          int n = n0 + wn * 64 + nt * 16 + fr;
          float bv = bias ? bias[n] : 0.0f;
          for (int r = 0; r < 4; ++r) {
            float v = acc[mt][nt][r] + bv;
            if (relu) v = fmaxf(v, 0.0f);
            Cst[(mt * 16 + kq * 4 + r) * 128 + wn * 64 + nt * 16 + fr] = (bf16)v;
          }
        }
    }
    __syncthreads();
    for (int i = t; i < 1024; i += 256) {
      int r = i >> 4, cs = i & 15;
      int gm = m0 + half * 64 + r;
      if (gm < M)
        *(bf16x8*)(C + (size_t)gm * ldc + coff + n0 + cs * 8) = *(const bf16x8*)(Cst + r * 128 + cs * 8);
    }
    __syncthreads();
  }
}

// ---------------- conv as 9-pass shifted 128x128 GEMM (implicit im2col) ----------------
template <int CIN, int PAD, int SRCW, int SRCROWS, int CHECK, int TRANS>
__global__ __launch_bounds__(256, 2) void k_conv128(
    const bf16* __restrict__ A, const bf16* __restrict__ Bp,
    const float* __restrict__ bias, bf16* __restrict__ C,
    const bf16* __restrict__ zpage) {
  __shared__ alignas(16) bf16 SM[8192];
  bf16* As = SM;
  bf16* Bs = SM + 4096;
  const int t = threadIdx.x, wave = t >> 6;
  const int lane = t & 63, fr = lane & 15, kq = lane >> 4;
  const int wm = wave & 1, wn = wave >> 1;
  const int m0 = blockIdx.x * 128, n0 = blockIdx.y * 128;
  const int srow = t >> 2, kseg = (t & 3) * 8;
  f32x4 acc[4][4] = {};
  int bb[2], yy[2], xx[2];
  for (int hf = 0; hf < 2; ++hf) {
    int m = imin(m0 + hf * 64 + srow, 43199);
    int b = m / 900, p = m - b * 900;
    bb[hf] = b; yy[hf] = p / 30; xx[hf] = p - (p / 30) * 30;
  }
  bf16* sA0 = As + wave * 512;
  bf16* sA1 = As + 2048 + wave * 512;
  bf16* sB0 = Bs + wave * 512;
  bf16* sB1 = Bs + 2048 + wave * 512;
  for (int t9 = 0; t9 < 9; ++t9) {
    const int ky = t9 / 3, kx = t9 - ky * 3;
    const bf16* ga[2];
    for (int hf = 0; hf < 2; ++hf) {
      int sy = yy[hf] + ky - PAD, sx = xx[hf] + kx - PAD;
      bool valid = !CHECK || (sy >= 0 && sy < SRCW && sx >= 0 && sx < SRCW);
      ga[hf] = (valid ? A + (size_t)(bb[hf] * SRCROWS + sy * SRCW + sx) * CIN : zpage) + kseg;
    }
    const bf16* gb = Bp + (size_t)(t9 * 256 + n0 + srow) * CIN + kseg;
    for (int k0 = 0; k0 < CIN; k0 += 32) {
      gl2lds(ga[0] + k0, sA0);
      gl2lds(ga[1] + k0, sA1);
      gl2lds(gb + k0, sB0);
      gl2lds(gb + (size_t)64 * CIN + k0, sB1);
      __syncthreads();
      bf16x8 af[4], bw[4];
      for (int mt = 0; mt < 4; ++mt)
        af[mt] = *(const bf16x8*)(As + (wm * 64 + mt * 16 + fr) * 32 + kq * 8);
      for (int nt = 0; nt < 4; ++nt)
        bw[nt] = *(const bf16x8*)(Bs + (wn * 64 + nt * 16 + fr) * 32 + kq * 8);
      for (int mt = 0; mt < 4; ++mt)
        for (int nt = 0; nt < 4; ++nt)
          acc[mt][nt] = __builtin_amdgcn_mfma_f32_16x16x32_bf16(af[mt], bw[nt], acc[mt][nt], 0, 0, 0);
      __syncthreads();
    }
  }
  bf16* Cst = SM;
  for (int half = 0; half < 2; ++half) {
    if (wm == half) {
      for (int mt = 0; mt < 4; ++mt)
        for (int nt = 0; nt < 4; ++nt) {
          int n = n0 + wn * 64 + nt * 16 + fr;
          float bv = bias[n];
          for (int r = 0; r < 4; ++r) {
            float v = acc[mt][nt][r] + bv;
            if (TRANS)
              Cst[(wn * 64 + nt * 16 + fr) * 64 + mt * 16 + kq * 4 + r] = (bf16)v;
            else
              Cst[(mt * 16 + kq * 4 + r) * 128 + wn * 64 + nt * 16 + fr] = (bf16)v;
          }
        }
    }
    __syncthreads();
    if (TRANS) {
      for (int i = t; i < 2048; i += 256) {
        int oc = i >> 4, pc = i & 15;
        int gm = m0 + half * 64 + pc * 4;
        if (gm < 43200) {
          int b = gm / 900, p = gm - b * 900;
          *(bf16x4*)(C + (size_t)(b * 256 + n0 + oc) * 900 + p) = *(const bf16x4*)(Cst + oc * 64 + pc * 4);
        }
      }
    } else {
      for (int i = t; i < 1024; i += 256) {
        int r = i >> 4, cs = i & 15;
        int gm = m0 + half * 64 + r;
        if (gm < 43200)
          *(bf16x8*)(C + (size_t)gm * 256 + n0 + cs * 8) = *(const bf16x8*)(Cst + r * 128 + cs * 8);
      }
    }
    __syncthreads();
  }
}

// ---------------- attention logits z for one (s,h) ----------------
// QKV rows of 768; RelT bf16 [sh][j*32+k]; L1p/L2p bf16 (48x72, K-padded).
template <int MASKED>
__global__ __launch_bounds__(256, MASKED ? 4 : 5) void k_attn_z(
    const bf16* __restrict__ QKV, const bf16* __restrict__ RelT, bf16* __restrict__ Z,
    const bf16* __restrict__ L1p, const bf16* __restrict__ L2p,
    const float* __restrict__ l1b, const float* __restrict__ l2b) {
  __shared__ alignas(16) bf16 QKs[2][48 * 40];  // Q,K staged, stride 40
  __shared__ float EMD[48 * 49];
  __shared__ alignas(16) bf16 zst[48 * 48];
  __shared__ alignas(16) bf16 Sc[MASKED ? 48 * 72 : 8];
  __shared__ alignas(16) bf16 T2b[MASKED ? 48 * 72 : 8];
  const int sh = blockIdx.x, s = sh >> 3, h = sh & 7;
  const int t = threadIdx.x, wave = t >> 6, lane = t & 63, fr = lane & 15, kq = lane >> 4;
  const float scale = 0.17677669529663687f;  // 1/sqrt(32)
  // stage Q (half 0) and K (half 1) coalesced
  for (int c = t; c < 384; c += 256) {
    int half = c >= 192 ? 1 : 0, cc = c - half * 192;
    int row = cc >> 2, seg = cc & 3;
    *(bf16x8*)(&QKs[half][row * 40 + seg * 8]) =
        *(const bf16x8*)(QKV + (size_t)(s * 48 + row) * 768 + half * 256 + h * 32 + seg * 8);
  }
  if constexpr (MASKED) {
    for (int i = t; i < 768; i += 256) {  // zero K-pad cols 48..63
      int r = i >> 4, c = 48 + (i & 15);
      Sc[r * 72 + c] = (bf16)0.0f;
      T2b[r * 72 + c] = (bf16)0.0f;
    }
  }
  __syncthreads();
  // stage 1: S = QK^T * scale ; E = Q R^T
  const bf16* relb = RelT + (size_t)sh * 1536;
  f32x4 sreg[3];
  int u = 0;
  for (int t9 = wave; t9 < 9; t9 += 4, ++u) {
    int ti = t9 / 3, tj = t9 - ti * 3;
    bf16x8 af = *(const bf16x8*)(&QKs[0][(ti * 16 + fr) * 40 + kq * 8]);
    bf16x8 bk = *(const bf16x8*)(&QKs[1][(tj * 16 + fr) * 40 + kq * 8]);
    bf16x8 rf = *(const bf16x8*)(relb + (tj * 16 + fr) * 32 + kq * 8);
    f32x4 sacc = {}, eacc = {};
    sacc = __builtin_amdgcn_mfma_f32_16x16x32_bf16(af, bk, sacc, 0, 0, 0);
    eacc = __builtin_amdgcn_mfma_f32_16x16x32_bf16(af, rf, eacc, 0, 0, 0);
    for (int r = 0; r < 4; ++r)
      EMD[(ti * 16 + kq * 4 + r) * 49 + tj * 16 + fr] = eacc[r];
    if constexpr (MASKED) {
      for (int r = 0; r < 4; ++r)
        Sc[(ti * 16 + kq * 4 + r) * 72 + tj * 16 + fr] = (bf16)(sacc[r] * scale);
    } else {
      for (int r = 0; r < 4; ++r) sreg[u][r] = sacc[r] * scale;
    }
  }
  __syncthreads();
  if constexpr (!MASKED) {
    u = 0;
    for (int t9 = wave; t9 < 9; t9 += 4, ++u) {
      int ti = t9 / 3, tj = t9 - ti * 3;
      for (int r = 0; r < 4; ++r) {
        int i = ti * 16 + kq * 4 + r, j = tj * 16 + fr;
        float v = sreg[u][r];
        if (j <= i) v += EMD[i * 49 + 47 + j - i];
        zst[i * 48 + j] = (bf16)v;
      }
    }
  } else {
    // lin1: qk1[i][a] = sum_j Sc[i][j] L1[a][j] -> T2b[a][i] (+bias)
    for (int t9 = wave; t9 < 9; t9 += 4) {
      int ti = t9 / 3, tj = t9 - ti * 3;
      f32x4 a2 = {};
      for (int k0 = 0; k0 < 64; k0 += 32) {
        bf16x8 af = *(const bf16x8*)(Sc + (ti * 16 + fr) * 72 + k0 + kq * 8);
        bf16x8 bw = *(const bf16x8*)(L1p + (tj * 16 + fr) * 72 + k0 + kq * 8);
        a2 = __builtin_amdgcn_mfma_f32_16x16x32_bf16(af, bw, a2, 0, 0, 0);
      }
      for (int r = 0; r < 4; ++r) {
        int i = ti * 16 + kq * 4 + r, a = tj * 16 + fr;
        T2b[a * 72 + i] = (bf16)(a2[r] + l1b[a]);
      }
    }
    __syncthreads();
    // lin2: bmm[a][c] = sum_i T2b[a][i] L2[c][i]; + mask/skew
    for (int t9 = wave; t9 < 9; t9 += 4) {
      int ti = t9 / 3, tj = t9 - ti * 3;
      f32x4 a2 = {};
      for (int k0 = 0; k0 < 64; k0 += 32) {
        bf16x8 af = *(const bf16x8*)(T2b + (ti * 16 + fr) * 72 + k0 + kq * 8);
        bf16x8 bw = *(const bf16x8*)(L2p + (tj * 16 + fr) * 72 + k0 + kq * 8);
        a2 = __builtin_amdgcn_mfma_f32_16x16x32_bf16(af, bw, a2, 0, 0, 0);
      }
      for (int r = 0; r < 4; ++r) {
        int aa = ti * 16 + kq * 4 + r, cc = tj * 16 + fr;
        float v;
        if (cc > aa) v = -10000.0f;  // masked column -> exactly uniform after softmax
        else v = a2[r] + l2b[cc] + EMD[aa * 49 + 47 + cc - aa];
        zst[aa * 48 + cc] = (bf16)v;
      }
    }
  }
  __syncthreads();
  bf16* zb = Z + (size_t)sh * 2304;
  for (int c = t; c < 288; c += 256)
    *(bf16x8*)(zb + c * 8) = *(const bf16x8*)(zst + c * 8);
}

// ---------------- per-column (over s=900) online max & inverse-sum ----------------
// grid 1152: 16 cols x 16 s-groups of 57
__global__ __launch_bounds__(256) void k_colstats(const bf16* __restrict__ Z,
                                                  float* __restrict__ Mc, float* __restrict__ Ic) {
  __shared__ float rm[16][17], rs[16][17];
  const int t = threadIdx.x, tc = t & 15, sg = t >> 4;
  const int col = blockIdx.x * 16 + tc;
  const bf16* p = Z + col;
  const int s0 = sg * 57, s1 = imin(900, s0 + 57);
  float m = -FLT_MAX, ssum = 0.0f;
  for (int s = s0; s < s1; ++s) {
    float v = (float)p[(size_t)s * 18432];
    if (v > m) { ssum *= __expf(m - v); m = v; }
    ssum += __expf(v - m);
  }
  rm[sg][tc] = m; rs[sg][tc] = ssum;
  __syncthreads();
  if (t < 16) {
    float M2 = -FLT_MAX;
    for (int g = 0; g < 16; ++g) M2 = fmaxf(M2, rm[g][t]);
    float S2 = 0.0f;
    for (int g = 0; g < 16; ++g) S2 += rs[g][t] * __expf(rm[g][t] - M2);
    Mc[blockIdx.x * 16 + t] = M2;
    Ic[blockIdx.x * 16 + t] = 1.0f / S2;
  }
}

// ---------------- O[s,h,i,d] = sum_j softmax(Z)[s,h,i,j] V[s,h,j,d] ----------------
__global__ __launch_bounds__(256, 6) void k_attn_av(
    const bf16* __restrict__ Z, const bf16* __restrict__ QKV,
    const float* __restrict__ Mc, const float* __restrict__ Ic, bf16* __restrict__ O) {
  __shared__ alignas(16) bf16 Ps[48 * 72];
  __shared__ alignas(16) bf16 Vt[32 * 72];
  __shared__ alignas(16) bf16 Ost[48 * 32];
  const int sh = blockIdx.x, s = sh >> 3, h = sh & 7;
  const int t = threadIdx.x, wave = t >> 6, lane = t & 63, fr = lane & 15, kq = lane >> 4;
  // zero only K-pad (cols 48..63)
  for (int i = t; i < 768; i += 256) Ps[(i >> 4) * 72 + 48 + (i & 15)] = (bf16)0.0f;
  for (int i = t; i < 512; i += 256) Vt[(i >> 4) * 72 + 48 + (i & 15)] = (bf16)0.0f;
  const bf16* zb = Z + (size_t)sh * 2304;
  const float* mc = Mc + h * 2304;
  const float* ic = Ic + h * 2304;
  for (int c = t; c < 288; c += 256) {
    int r = c / 6, seg = c - r * 6;
    int idx = r * 48 + seg * 8;
    bf16x8 zv = *(const bf16x8*)(zb + idx);
    f32x4 m0v = *(const f32x4*)(mc + idx), m1v = *(const f32x4*)(mc + idx + 4);
    f32x4 i0v = *(const f32x4*)(ic + idx), i1v = *(const f32x4*)(ic + idx + 4);
    bf16x8 pv;
    for (int e = 0; e < 4; ++e) pv[e] = (bf16)(__expf((float)zv[e] - m0v[e]) * i0v[e]);
    for (int e = 0; e < 4; ++e) pv[4 + e] = (bf16)(__expf((float)zv[4 + e] - m1v[e]) * i1v[e]);
    *(bf16x8*)(Ps + r * 72 + seg * 8) = pv;
  }
  // V staging: vector loads, LDS transpose
  for (int c = t; c < 192; c += 256) {
    int j = c >> 2, seg = c & 3;
    bf16x8 v = *(const bf16x8*)(QKV + (size_t)(s * 48 + j) * 768 + 512 + h * 32 + seg * 8);
    for (int e = 0; e < 8; ++e) Vt[(seg * 8 + e) * 72 + j] = v[e];
  }
  __syncthreads();
  for (int t6 = wave; t6 < 6; t6 += 4) {
    int ti = t6 >> 1, td = t6 & 1;
    f32x4 a2 = {};
    for (int k0 = 0; k0 < 64; k0 += 32) {
      bf16x8 af = *(const bf16x8*)(Ps + (ti * 16 + fr) * 72 + k0 + kq * 8);
      bf16x8 bv = *(const bf16x8*)(Vt + (td * 16 + fr) * 72 + k0 + kq * 8);
      a2 = __builtin_amdgcn_mfma_f32_16x16x32_bf16(af, bv, a2, 0, 0, 0);
    }
    for (int r = 0; r < 4; ++r)
      Ost[(ti * 16 + kq * 4 + r) * 32 + td * 16 + fr] = (bf16)a2[r];
  }
  __syncthreads();
  bf16* ob = O + (size_t)sh * 1536;
  for (int c = t; c < 192; c += 256)
    *(bf16x8*)(ob + c * 8) = *(const bf16x8*)(Ost + c * 8);
}

// ---------------- out = LN(Xa + Xb), rows of 256, bf16 ----------------
__global__ __launch_bounds__(256) void k_add_ln(
    const bf16* __restrict__ Xa, const bf16* __restrict__ Xb, bf16* __restrict__ out) {
  const int t = threadIdx.x, lane = t & 63, w = t >> 6;
  const size_t off = ((size_t)blockIdx.x * 4 + w) * 256 + lane * 4;
  bf16x4 av = *(const bf16x4*)(Xa + off);
  bf16x4 bv = *(const bf16x4*)(Xb + off);
  f32x4 x;
  for (int c = 0; c < 4; ++c) x[c] = (float)av[c] + (float)bv[c];
  float sum = x[0] + x[1] + x[2] + x[3];
  for (int o = 1; o < 64; o <<= 1) sum += __shfl_xor(sum, o);
  float mean = sum * (1.0f / 256.0f);
  float q = 0.0f;
  for (int c = 0; c < 4; ++c) { float d = x[c] - mean; q += d * d; }
  for (int o = 1; o < 64; o <<= 1) q += __shfl_xor(q, o);
  float rstd = rsqrtf(q * (1.0f / 256.0f) + 1e-5f);
  bf16x4 y;
  for (int c = 0; c < 4; ++c) y[c] = (bf16)((x[c] - mean) * rstd);
  *(bf16x4*)(out + off) = y;
}

// ---------------- y[m] = dot(H[m,:256], w) + b ----------------
__global__ __launch_bounds__(256) void k_ydot(
    const bf16* __restrict__ H, const float* __restrict__ w,
    const float* __restrict__ b, float* __restrict__ Y) {
  const int t = threadIdx.x, lane = t & 63, wv = t >> 6;
  const size_t row = (size_t)blockIdx.x * 4 + wv;
  bf16x4 hx = *(const bf16x4*)(H + row * 256 + lane * 4);
  f32x4 ww = *(const f32x4*)(w + lane * 4);
  float s = (float)hx[0] * ww[0] + (float)hx[1] * ww[1] + (float)hx[2] * ww[2] + (float)hx[3] * ww[3];
  for (int o = 1; o < 64; o <<= 1) s += __shfl_xor(s, o);
  if (lane == 0) Y[row] = s + b[0];
}

// ---------------- softmax over b (48) per column ----------------
__global__ void k_softmax48(const float* __restrict__ Y, float* __restrict__ O) {
  int ss = blockIdx.x * 256 + threadIdx.x;
  if (ss >= 900) return;
  float m = -FLT_MAX;
  for (int b = 0; b < 48; ++b) m = fmaxf(m, Y[b * 900 + ss]);
  float sum = 0.0f;
  for (int b = 0; b < 48; ++b) sum += __expf(Y[b * 900 + ss] - m);
  float inv = 1.0f / sum;
  for (int b = 0; b < 48; ++b) O[b * 900 + ss] = __expf(Y[b * 900 + ss] - m) * inv;
}

extern "C" void kernel_launch(void* const* d_in, const int* in_sizes, int n_in,
                              void* d_out, int out_size, void* d_ws, size_t ws_size,
                              hipStream_t stream) {
  (void)in_sizes; (void)n_in; (void)out_size;
  const float* X_en = (const float*)d_in[0];
  const float* X_de = (const float*)d_in[1];
  const float* conv1_w = (const float*)d_in[2];
  const float* conv1_b = (const float*)d_in[3];
  const float* conv2_w = (const float*)d_in[4];
  const float* conv2_b = (const float*)d_in[5];
  const float* enc_wq = (const float*)d_in[6];
  const float* enc_wk = (const float*)d_in[7];
  const float* enc_wv = (const float*)d_in[8];
  const float* enc_rel = (const float*)d_in[9];
  const float* enc_f1w = (const float*)d_in[10];
  const float* enc_f1b = (const float*)d_in[11];
  const float* enc_f2w = (const float*)d_in[12];
  const float* enc_f2b = (const float*)d_in[13];
  const float* dm_wq = (const float*)d_in[14];
  const float* dm_wk = (const float*)d_in[15];
  const float* dm_wv = (const float*)d_in[16];
  const float* dm_rel = (const float*)d_in[17];
  const float* dm_l1w = (const float*)d_in[18];
  const float* dm_l1b = (const float*)d_in[19];
  const float* dm_l2w = (const float*)d_in[20];
  const float* dm_l2b = (const float*)d_in[21];
  const float* dc_wq = (const float*)d_in[22];
  const float* dc_wk = (const float*)d_in[23];
  const float* dc_wv = (const float*)d_in[24];
  const float* dc_rel = (const float*)d_in[25];
  const float* d_f1w = (const float*)d_in[26];
  const float* d_f1b = (const float*)d_in[27];
  const float* d_f2w = (const float*)d_in[28];
  const float* d_f2b = (const float*)d_in[29];
  const float* out_w = (const float*)d_in[30];
  const float* out_b = (const float*)d_in[31];
  float* OUT = (float*)d_out;

  // ---- workspace layout ----
  const size_t SLOT = 22118400;  // 43200*256 bf16
  char* ws = (char*)d_ws;
  size_t o = 0;
  bf16* S1 = (bf16*)(ws + o); o += SLOT;  // XEb -> ENCb
  bf16* S2 = (bf16*)(ws + o); o += SLOT;  // XDb -> (cross stats)
  bf16* S3 = (bf16*)(ws + o); o += SLOT;  // (enc RelT) -> o1 -> (dm stats) -> (cross RelT) -> h2
  bf16* S4 = (bf16*)(ws + o); o += SLOT;  // (enc stats) -> h1 -> h3
  bf16* S5 = (bf16*)(ws + o); o += SLOT;  // attn-out / ffn-out / (dm RelT)
  char* U = ws + o; o += 33177600 + 3 * SLOT;  // Z + QKV, union { HID, XR+C1R }
  bf16* Zb = (bf16*)U;
  bf16* QKV = (bf16*)(U + 33177600);
  bf16* XR = (bf16*)U;                    // conv phase only
  bf16* C1R = (bf16*)(U + 3145728);       // conv phase only
  bf16* HID = (bf16*)U;                   // FFN phase only
  bf16* wa = (bf16*)(ws + o); o += 4603904 + 16384;
  float* Y = (float*)(ws + o); o += 172800;
  if (ws_size < o) return;

  bf16* zpage = (bf16*)Y;  // 512 B zero page; Y dead until k_ydot
  // per-phase softmax stats (147 KB each) in dead activation slots
  float* encM = (float*)S4; float* encI = encM + 18432;
  float* dmM  = (float*)S3; float* dmI  = dmM + 18432;
  float* crM  = (float*)S2; float* crI  = crM + 18432;
  // per-phase RelT (22.1 MB) in dead slots
  bf16* encRel = S3;   // free until o1 written (after attn_av)
  bf16* dmRel  = S5;   // free until dm attn_av writes S5
  bf16* crRel  = S3;   // o1 dead after enc_out; h2 written after attn_av

  // weight arena (element offsets)
  bf16* c1p = wa;                 // 9*(256x32)
  bf16* c2p = wa + 73728;         // 9*(256x256)
  bf16* EQKVw = wa + 663552;      // eq|ek|ev (768x256)
  bf16* MQKVw = wa + 860160;      // mq|mk|mv
  bf16* cqw = wa + 1056768;       // 256x256
  bf16* CKVw = wa + 1122304;      // ck|cv (512x256)
  bf16* ef1 = wa + 1253376;
  bf16* ef2 = wa + 1515520;
  bf16* df1 = wa + 1777664;
  bf16* df2 = wa + 2039808;
  bf16* L1p = wa + 2301952;       // 48x72 padded
  bf16* L2p = wa + 2305408;

  auto gemm = [&](const bf16* A, const bf16* B, const float* bias, bf16* C,
                  int M, int N, int K, int relu, int ldc, int coff) {
    k_gemm128<<<dim3((M + 127) / 128, N / 128), dim3(256), 0, stream>>>(
        A, B, bias, C, M, N, K, relu, ldc, coff);
  };

  // ---- weight prep ----
  k_zero<<<dim3(1), dim3(256), 0, stream>>>(zpage);
  k_pack_conv<<<dim3(288), dim3(256), 0, stream>>>(conv1_w, c1p, 256, 32, 73728);
  k_pack_conv<<<dim3(2304), dim3(256), 0, stream>>>(conv2_w, c2p, 256, 256, 589824);
  k_prep_lin<<<dim3(1), dim3(256), 0, stream>>>(dm_l1w, dm_l2w, L1p, L2p);
  {
    CastSegs sg;
    const float* srcs[13] = {enc_wq, enc_wk, enc_wv, dm_wq, dm_wk, dm_wv, dc_wq,
                             dc_wk, dc_wv, enc_f1w, enc_f2w, d_f1w, d_f2w};
    bf16* dsts[13] = {EQKVw, EQKVw + 65536, EQKVw + 131072, MQKVw, MQKVw + 65536,
                      MQKVw + 131072, cqw, CKVw, CKVw + 65536, ef1, ef2, df1, df2};
    int ns[13] = {65536, 65536, 65536, 65536, 65536, 65536, 65536, 65536, 65536,
                  262144, 262144, 262144, 262144};
    int total = 0;
    for (int k = 0; k < 13; ++k) { sg.s[k] = srcs[k]; sg.d[k] = dsts[k]; sg.n[k] = ns[k]; total += ns[k]; }
    k_cast_all<<<dim3((total + 255) / 256), dim3(256), 0, stream>>>(sg, total);
  }

  // ---- conv chains ----
  auto conv_chain = [&](const float* X, bf16* outB) {
    k_prep_x<<<dim3(6144), dim3(256), 0, stream>>>(X, XR);
    k_conv128<32, 0, 32, 1024, 0, 0><<<dim3(338, 2), dim3(256), 0, stream>>>(XR, c1p, conv1_b, C1R, zpage);
    k_conv128<256, 1, 30, 900, 1, 1><<<dim3(338, 2), dim3(256), 0, stream>>>(C1R, c2p, conv2_b, outB, zpage);
  };
  conv_chain(X_en, S1);
  conv_chain(X_de, S2);

  // ---- encoder ----
  gemm(S1, EQKVw, nullptr, QKV, 43200, 768, 256, 0, 768, 0);
  k_prep_rel<<<dim3(43200), dim3(256), 0, stream>>>(enc_rel, encRel);
  k_attn_z<0><<<dim3(7200), dim3(256), 0, stream>>>(QKV, encRel, Zb, nullptr, nullptr, nullptr, nullptr);
  k_colstats<<<dim3(1152), dim3(256), 0, stream>>>(Zb, encM, encI);
  k_attn_av<<<dim3(7200), dim3(256), 0, stream>>>(Zb, QKV, encM, encI, S5);
  k_add_ln<<<dim3(10800), dim3(256), 0, stream>>>(S1, S5, S3);  // o1
  gemm(S3, ef1, enc_f1b, HID, 43200, 1024, 256, 1, 1024, 0);
  gemm(HID, ef2, enc_f2b, S5, 43200, 256, 1024, 0, 256, 0);
  k_add_ln<<<dim3(10800), dim3(256), 0, stream>>>(S3, S5, S1);  // enc_out

  // ---- decoder masked self-attention ----
  gemm(S2, MQKVw, nullptr, QKV, 43200, 768, 256, 0, 768, 0);
  k_prep_rel<<<dim3(43200), dim3(256), 0, stream>>>(dm_rel, dmRel);
  k_attn_z<1><<<dim3(7200), dim3(256), 0, stream>>>(QKV, dmRel, Zb, L1p, L2p, dm_l1b, dm_l2b);
  k_colstats<<<dim3(1152), dim3(256), 0, stream>>>(Zb, dmM, dmI);
  k_attn_av<<<dim3(7200), dim3(256), 0, stream>>>(Zb, QKV, dmM, dmI, S5);
  k_add_ln<<<dim3(10800), dim3(256), 0, stream>>>(S2, S5, S4);  // h1

  // ---- cross attention ----
  gemm(S4, cqw, nullptr, QKV, 43200, 256, 256, 0, 768, 0);
  gemm(S1, CKVw, nullptr, QKV, 43200, 512, 256, 0, 768, 256);
  k_prep_rel<<<dim3(43200), dim3(256), 0, stream>>>(dc_rel, crRel);
  k_attn_z<0><<<dim3(7200), dim3(256), 0, stream>>>(QKV, crRel, Zb, nullptr, nullptr, nullptr, nullptr);
  k_colstats<<<dim3(1152), dim3(256), 0, stream>>>(Zb, crM, crI);
  k_attn_av<<<dim3(7200), dim3(256), 0, stream>>>(Zb, QKV, crM, crI, S5);
  k_add_ln<<<dim3(10800), dim3(256), 0, stream>>>(S5, S4, S3);  // h2 = ln(c + h1)

  // ---- decoder FFN + head ----
  gemm(S3, df1, d_f1b, HID, 43200, 1024, 256, 1, 1024, 0);
  gemm(HID, df2, d_f2b, S5, 43200, 256, 1024, 0, 256, 0);
  k_add_ln<<<dim3(10800), dim3(256), 0, stream>>>(S3, S5, S4);  // h3
  k_ydot<<<dim3(10800), dim3(256), 0, stream>>>(S4, out_w, out_b, Y);
  k_softmax48<<<dim3(4), dim3(256), 0, stream>>>(Y, OUT);
}

// Round 6
// 1104.515 us; speedup vs baseline: 2.1571x; 1.0184x over previous
//
#include <hip/hip_runtime.h>
#include <float.h>

typedef __bf16 bf16;
typedef __attribute__((ext_vector_type(8))) __bf16 bf16x8;
typedef __attribute__((ext_vector_type(4))) __bf16 bf16x4;
typedef __attribute__((ext_vector_type(4))) float f32x4;

__device__ __forceinline__ int imin(int a, int b) { return a < b ? a : b; }

// async global->LDS, 16B per lane; LDS dest = wave-uniform base + lane*16
__device__ __forceinline__ void gl2lds(const bf16* g, bf16* l) {
  __builtin_amdgcn_global_load_lds(
      (const __attribute__((address_space(1))) void*)g,
      (__attribute__((address_space(3))) void*)l, 16, 0, 0);
}

// ---------------- zero the border zero-page (512 B) ----------------
__global__ void k_zero(bf16* zp) { zp[threadIdx.x] = (bf16)0.0f; }

// ---------------- fused f32->bf16 casts (13 segments) ----------------
struct CastSegs { const float* s[13]; bf16* d[13]; int n[13]; };
__global__ void k_cast_all(CastSegs sg, int total) {
  int i = blockIdx.x * 256 + threadIdx.x;
  if (i >= total) return;
  for (int k = 0; k < 13; ++k) {
    if (i < sg.n[k]) { sg.d[k][i] = (bf16)sg.s[k][i]; return; }
    i -= sg.n[k];
  }
}

// ---------------- rel transpose via LDS: (sh, k*48+j) fp32 -> (sh, j*32+k) bf16 ----------------
// grid 900, 8 sh per block; coalesced read AND write, conflict-free LDS.
__global__ __launch_bounds__(256) void k_prep_rel(const float* __restrict__ rel,
                                                  bf16* __restrict__ RelT) {
  __shared__ float tile[32 * 49];
  const int t = threadIdx.x;
  for (int u = 0; u < 8; ++u) {
    const size_t sh = (size_t)blockIdx.x * 8 + u;
    const float* src = rel + sh * 1536;
    bf16* dst = RelT + sh * 1536;
    __syncthreads();
    for (int i = t; i < 1536; i += 256) {
      int k = i / 48, j = i - k * 48;
      tile[k * 49 + j] = src[i];
    }
    __syncthreads();
    for (int i = t; i < 1536; i += 256) {
      int j = i >> 5, k = i & 31;
      dst[i] = (bf16)tile[k * 49 + j];
    }
  }
}

// ---------------- l1w/l2w (48x48 fp32) -> padded bf16 (48x72, K-pad 0) ----------------
__global__ void k_prep_lin(const float* __restrict__ l1w, const float* __restrict__ l2w,
                           bf16* __restrict__ L1p, bf16* __restrict__ L2p) {
  for (int i = threadIdx.x; i < 3456; i += 256) {
    int r = i / 72, c = i - r * 72;
    L1p[i] = (c < 48) ? (bf16)l1w[r * 48 + c] : (bf16)0.0f;
    L2p[i] = (c < 48) ? (bf16)l2w[r * 48 + c] : (bf16)0.0f;
  }
}

// ---------------- X (b,32,32,32) -> XR rows (b*1024, 32ch) bf16 ----------------
__global__ void k_prep_x(const float* __restrict__ X, bf16* __restrict__ XR) {
  int idx = blockIdx.x * 256 + threadIdx.x;
  if (idx >= 48 * 1024 * 32) return;
  int b = idx >> 15, r = idx & 32767, pos = r >> 5, ic = r & 31;
  XR[idx] = (bf16)X[((size_t)(b * 32 + ic) << 10) + pos];
}

// ---------------- conv weight pack: (OC,IC,3,3) -> 9 x (OC,IC) bf16 ----------------
__global__ void k_pack_conv(const float* __restrict__ w, bf16* __restrict__ dst,
                            int OC, int IC, int total) {
  int idx = blockIdx.x * 256 + threadIdx.x;
  if (idx >= total) return;
  int t = idx / (OC * IC);
  int rem = idx - t * OC * IC;
  int oc = rem / IC, ic = rem - oc * IC;
  dst[idx] = (bf16)w[(size_t)(oc * IC + ic) * 9 + t];
}

// ---------------- 128x128 GEMM: C[m, coff+n] = A[M,K] x B[N,K]^T ----------------
__global__ __launch_bounds__(256, 2) void k_gemm128(
    const bf16* __restrict__ A, const bf16* __restrict__ B,
    const float* __restrict__ bias, bf16* __restrict__ C,
    int M, int N, int K, int relu, int ldc, int coff) {
  __shared__ alignas(16) bf16 SM[8192];
  bf16* As = SM;
  bf16* Bs = SM + 4096;
  const int t = threadIdx.x, wave = t >> 6;
  const int lane = t & 63, fr = lane & 15, kq = lane >> 4;
  const int wm = wave & 1, wn = wave >> 1;
  const int m0 = blockIdx.x * 128, n0 = blockIdx.y * 128;
  const int srow = t >> 2, kseg = (t & 3) * 8;
  f32x4 acc[4][4] = {};
  const bf16* gA0 = A + (size_t)imin(m0 + srow, M - 1) * K + kseg;
  const bf16* gA1 = A + (size_t)imin(m0 + 64 + srow, M - 1) * K + kseg;
  const bf16* gB0 = B + (size_t)(n0 + srow) * K + kseg;
  const bf16* gB1 = B + (size_t)(n0 + 64 + srow) * K + kseg;
  bf16* sA0 = As + wave * 512;
  bf16* sA1 = As + 2048 + wave * 512;
  bf16* sB0 = Bs + wave * 512;
  bf16* sB1 = Bs + 2048 + wave * 512;
  for (int k0 = 0; k0 < K; k0 += 32) {
    gl2lds(gA0 + k0, sA0);
    gl2lds(gA1 + k0, sA1);
    gl2lds(gB0 + k0, sB0);
    gl2lds(gB1 + k0, sB1);
    __syncthreads();
    bf16x8 af[4], bw[4];
    for (int mt = 0; mt < 4; ++mt)
      af[mt] = *(const bf16x8*)(As + (wm * 64 + mt * 16 + fr) * 32 + kq * 8);
    for (int nt = 0; nt < 4; ++nt)
      bw[nt] = *(const bf16x8*)(Bs + (wn * 64 + nt * 16 + fr) * 32 + kq * 8);
    for (int mt = 0; mt < 4; ++mt)
      for (int nt = 0; nt < 4; ++nt)
        acc[mt][nt] = __builtin_amdgcn_mfma_f32_16x16x32_bf16(af[mt], bw[nt], acc[mt][nt], 0, 0, 0);
    __syncthreads();
  }
  bf16* Cst = SM;  // 64 x 128
  for (int half = 0; half < 2; ++half) {
    if (wm == half) {
      for (int mt = 0; mt < 4; ++mt)
        for (int nt = 0; nt < 4; ++nt) {
          int n = n0 + wn * 64 + nt * 16 + fr;
          float bv = bias ? bias[n] : 0.0f;
          for (int r = 0; r < 4; ++r) {
            float v = acc[mt][nt][r] + bv;
            if (relu) v = fmaxf(v, 0.0f);
            Cst[(mt * 16 + kq * 4 + r) * 128 + wn * 64 + nt * 16 + fr] = (bf16)v;
          }
        }
    }
    __syncthreads();
    for (int i = t; i < 1024; i += 256) {
      int r = i >> 4, cs = i & 15;
      int gm = m0 + half * 64 + r;
      if (gm < M)
        *(bf16x8*)(C + (size_t)gm * ldc + coff + n0 + cs * 8) = *(const bf16x8*)(Cst + r * 128 + cs * 8);
    }
    __syncthreads();
  }
}

// ---------------- conv as shifted 128x128 GEMM; K-outer / shift-inner for L1/L2 reuse ----------------
template <int CIN, int PAD, int SRCW, int SRCROWS, int CHECK, int TRANS>
__global__ __launch_bounds__(256, 2) void k_conv128(
    const bf16* __restrict__ A, const bf16* __restrict__ Bp,
    const float* __restrict__ bias, bf16* __restrict__ C,
    const bf16* __restrict__ zpage) {
  __shared__ alignas(16) bf16 SM[8192];
  bf16* As = SM;
  bf16* Bs = SM + 4096;
  const int t = threadIdx.x, wave = t >> 6;
  const int lane = t & 63, fr = lane & 15, kq = lane >> 4;
  const int wm = wave & 1, wn = wave >> 1;
  const int m0 = blockIdx.x * 128, n0 = blockIdx.y * 128;
  const int srow = t >> 2, kseg = (t & 3) * 8;
  f32x4 acc[4][4] = {};
  int bb[2], yy[2], xx[2];
  for (int hf = 0; hf < 2; ++hf) {
    int m = imin(m0 + hf * 64 + srow, 43199);
    int b = m / 900, p = m - b * 900;
    bb[hf] = b; yy[hf] = p / 30; xx[hf] = p - (p / 30) * 30;
  }
  bf16* sA0 = As + wave * 512;
  bf16* sA1 = As + 2048 + wave * 512;
  bf16* sB0 = Bs + wave * 512;
  bf16* sB1 = Bs + 2048 + wave * 512;
  for (int k0 = 0; k0 < CIN; k0 += 32) {
    for (int t9 = 0; t9 < 9; ++t9) {
      const int ky = t9 / 3, kx = t9 - ky * 3;
      const bf16* ga[2];
      for (int hf = 0; hf < 2; ++hf) {
        int sy = yy[hf] + ky - PAD, sx = xx[hf] + kx - PAD;
        bool valid = !CHECK || (sy >= 0 && sy < SRCW && sx >= 0 && sx < SRCW);
        ga[hf] = (valid ? A + (size_t)(bb[hf] * SRCROWS + sy * SRCW + sx) * CIN : zpage) + kseg;
      }
      const bf16* gb = Bp + (size_t)(t9 * 256 + n0 + srow) * CIN + kseg;
      gl2lds(ga[0] + k0, sA0);
      gl2lds(ga[1] + k0, sA1);
      gl2lds(gb + k0, sB0);
      gl2lds(gb + (size_t)64 * CIN + k0, sB1);
      __syncthreads();
      bf16x8 af[4], bw[4];
      for (int mt = 0; mt < 4; ++mt)
        af[mt] = *(const bf16x8*)(As + (wm * 64 + mt * 16 + fr) * 32 + kq * 8);
      for (int nt = 0; nt < 4; ++nt)
        bw[nt] = *(const bf16x8*)(Bs + (wn * 64 + nt * 16 + fr) * 32 + kq * 8);
      for (int mt = 0; mt < 4; ++mt)
        for (int nt = 0; nt < 4; ++nt)
          acc[mt][nt] = __builtin_amdgcn_mfma_f32_16x16x32_bf16(af[mt], bw[nt], acc[mt][nt], 0, 0, 0);
      __syncthreads();
    }
  }
  bf16* Cst = SM;
  for (int half = 0; half < 2; ++half) {
    if (wm == half) {
      for (int mt = 0; mt < 4; ++mt)
        for (int nt = 0; nt < 4; ++nt) {
          int n = n0 + wn * 64 + nt * 16 + fr;
          float bv = bias[n];
          for (int r = 0; r < 4; ++r) {
            float v = acc[mt][nt][r] + bv;
            if (TRANS)
              Cst[(wn * 64 + nt * 16 + fr) * 64 + mt * 16 + kq * 4 + r] = (bf16)v;
            else
              Cst[(mt * 16 + kq * 4 + r) * 128 + wn * 64 + nt * 16 + fr] = (bf16)v;
          }
        }
    }
    __syncthreads();
    if (TRANS) {
      for (int i = t; i < 2048; i += 256) {
        int oc = i >> 4, pc = i & 15;
        int gm = m0 + half * 64 + pc * 4;
        if (gm < 43200) {
          int b = gm / 900, p = gm - b * 900;
          *(bf16x4*)(C + (size_t)(b * 256 + n0 + oc) * 900 + p) = *(const bf16x4*)(Cst + oc * 64 + pc * 4);
        }
      }
    } else {
      for (int i = t; i < 1024; i += 256) {
        int r = i >> 4, cs = i & 15;
        int gm = m0 + half * 64 + r;
        if (gm < 43200)
          *(bf16x8*)(C + (size_t)gm * 256 + n0 + cs * 8) = *(const bf16x8*)(Cst + r * 128 + cs * 8);
      }
    }
    __syncthreads();
  }
}

// ---------------- attention logits z for one (s,h) ----------------
template <int MASKED>
__global__ __launch_bounds__(256, MASKED ? 4 : 5) void k_attn_z(
    const bf16* __restrict__ QKV, const bf16* __restrict__ RelT, bf16* __restrict__ Z,
    const bf16* __restrict__ L1p, const bf16* __restrict__ L2p,
    const float* __restrict__ l1b, const float* __restrict__ l2b) {
  __shared__ alignas(16) bf16 QKs[2][48 * 40];
  __shared__ float EMD[48 * 49];
  __shared__ alignas(16) bf16 zst[48 * 48];
  __shared__ alignas(16) bf16 Sc[MASKED ? 48 * 72 : 8];
  __shared__ alignas(16) bf16 T2b[MASKED ? 48 * 72 : 8];
  const int sh = blockIdx.x, s = sh >> 3, h = sh & 7;
  const int t = threadIdx.x, wave = t >> 6, lane = t & 63, fr = lane & 15, kq = lane >> 4;
  const float scale = 0.17677669529663687f;  // 1/sqrt(32)
  for (int c = t; c < 384; c += 256) {
    int half = c >= 192 ? 1 : 0, cc = c - half * 192;
    int row = cc >> 2, seg = cc & 3;
    *(bf16x8*)(&QKs[half][row * 40 + seg * 8]) =
        *(const bf16x8*)(QKV + (size_t)(s * 48 + row) * 768 + half * 256 + h * 32 + seg * 8);
  }
  if constexpr (MASKED) {
    for (int i = t; i < 768; i += 256) {
      int r = i >> 4, c = 48 + (i & 15);
      Sc[r * 72 + c] = (bf16)0.0f;
      T2b[r * 72 + c] = (bf16)0.0f;
    }
  }
  __syncthreads();
  const bf16* relb = RelT + (size_t)sh * 1536;
  f32x4 sreg[3];
  int u = 0;
  for (int t9 = wave; t9 < 9; t9 += 4, ++u) {
    int ti = t9 / 3, tj = t9 - ti * 3;
    bf16x8 af = *(const bf16x8*)(&QKs[0][(ti * 16 + fr) * 40 + kq * 8]);
    bf16x8 bk = *(const bf16x8*)(&QKs[1][(tj * 16 + fr) * 40 + kq * 8]);
    bf16x8 rf = *(const bf16x8*)(relb + (tj * 16 + fr) * 32 + kq * 8);
    f32x4 sacc = {}, eacc = {};
    sacc = __builtin_amdgcn_mfma_f32_16x16x32_bf16(af, bk, sacc, 0, 0, 0);
    eacc = __builtin_amdgcn_mfma_f32_16x16x32_bf16(af, rf, eacc, 0, 0, 0);
    for (int r = 0; r < 4; ++r)
      EMD[(ti * 16 + kq * 4 + r) * 49 + tj * 16 + fr] = eacc[r];
    if constexpr (MASKED) {
      for (int r = 0; r < 4; ++r)
        Sc[(ti * 16 + kq * 4 + r) * 72 + tj * 16 + fr] = (bf16)(sacc[r] * scale);
    } else {
      for (int r = 0; r < 4; ++r) sreg[u][r] = sacc[r] * scale;
    }
  }
  __syncthreads();
  if constexpr (!MASKED) {
    u = 0;
    for (int t9 = wave; t9 < 9; t9 += 4, ++u) {
      int ti = t9 / 3, tj = t9 - ti * 3;
      for (int r = 0; r < 4; ++r) {
        int i = ti * 16 + kq * 4 + r, j = tj * 16 + fr;
        float v = sreg[u][r];
        if (j <= i) v += EMD[i * 49 + 47 + j - i];
        zst[i * 48 + j] = (bf16)v;
      }
    }
  } else {
    for (int t9 = wave; t9 < 9; t9 += 4) {
      int ti = t9 / 3, tj = t9 - ti * 3;
      f32x4 a2 = {};
      for (int k0 = 0; k0 < 64; k0 += 32) {
        bf16x8 af = *(const bf16x8*)(Sc + (ti * 16 + fr) * 72 + k0 + kq * 8);
        bf16x8 bw = *(const bf16x8*)(L1p + (tj * 16 + fr) * 72 + k0 + kq * 8);
        a2 = __builtin_amdgcn_mfma_f32_16x16x32_bf16(af, bw, a2, 0, 0, 0);
      }
      for (int r = 0; r < 4; ++r) {
        int i = ti * 16 + kq * 4 + r, a = tj * 16 + fr;
        T2b[a * 72 + i] = (bf16)(a2[r] + l1b[a]);
      }
    }
    __syncthreads();
    for (int t9 = wave; t9 < 9; t9 += 4) {
      int ti = t9 / 3, tj = t9 - ti * 3;
      f32x4 a2 = {};
      for (int k0 = 0; k0 < 64; k0 += 32) {
        bf16x8 af = *(const bf16x8*)(T2b + (ti * 16 + fr) * 72 + k0 + kq * 8);
        bf16x8 bw = *(const bf16x8*)(L2p + (tj * 16 + fr) * 72 + k0 + kq * 8);
        a2 = __builtin_amdgcn_mfma_f32_16x16x32_bf16(af, bw, a2, 0, 0, 0);
      }
      for (int r = 0; r < 4; ++r) {
        int aa = ti * 16 + kq * 4 + r, cc = tj * 16 + fr;
        float v;
        if (cc > aa) v = -10000.0f;  // masked column -> exactly uniform after softmax
        else v = a2[r] + l2b[cc] + EMD[aa * 49 + 47 + cc - aa];
        zst[aa * 48 + cc] = (bf16)v;
      }
    }
  }
  __syncthreads();
  bf16* zb = Z + (size_t)sh * 2304;
  for (int c = t; c < 288; c += 256)
    *(bf16x8*)(zb + c * 8) = *(const bf16x8*)(zst + c * 8);
}

// ---------------- per-column (over s=900) online max & inverse-sum ----------------
// grid 144: 128 cols/block (8 per thread, bf16x8 loads) x 16 s-groups of 57
__global__ __launch_bounds__(256) void k_colstats(const bf16* __restrict__ Z,
                                                  float* __restrict__ Mc, float* __restrict__ Ic) {
  __shared__ float rm[16][136], rs[16][136];
  const int t = threadIdx.x, cg = t & 15, sg = t >> 4;
  const bf16* p = Z + blockIdx.x * 128 + cg * 8;
  const int s0 = sg * 57, s1 = imin(900, s0 + 57);
  float m[8], ss[8];
  for (int e = 0; e < 8; ++e) { m[e] = -FLT_MAX; ss[e] = 0.0f; }
  for (int s = s0; s < s1; ++s) {
    bf16x8 zv = *(const bf16x8*)(p + (size_t)s * 18432);
    for (int e = 0; e < 8; ++e) {
      float v = (float)zv[e];
      if (v > m[e]) { ss[e] *= __expf(m[e] - v); m[e] = v; }
      ss[e] += __expf(v - m[e]);
    }
  }
  for (int e = 0; e < 8; ++e) { rm[sg][cg * 8 + e] = m[e]; rs[sg][cg * 8 + e] = ss[e]; }
  __syncthreads();
  if (t < 128) {
    float M2 = -FLT_MAX;
    for (int g = 0; g < 16; ++g) M2 = fmaxf(M2, rm[g][t]);
    float S2 = 0.0f;
    for (int g = 0; g < 16; ++g) S2 += rs[g][t] * __expf(rm[g][t] - M2);
    Mc[blockIdx.x * 128 + t] = M2;
    Ic[blockIdx.x * 128 + t] = 1.0f / S2;
  }
}

// ---------------- O[s,h,i,d] = sum_j softmax(Z)[s,h,i,j] V[s,h,j,d] ----------------
__global__ __launch_bounds__(256, 6) void k_attn_av(
    const bf16* __restrict__ Z, const bf16* __restrict__ QKV,
    const float* __restrict__ Mc, const float* __restrict__ Ic, bf16* __restrict__ O) {
  __shared__ alignas(16) bf16 Ps[48 * 72];
  __shared__ alignas(16) bf16 Vt[32 * 72];
  __shared__ alignas(16) bf16 Ost[48 * 32];
  const int sh = blockIdx.x, s = sh >> 3, h = sh & 7;
  const int t = threadIdx.x, wave = t >> 6, lane = t & 63, fr = lane & 15, kq = lane >> 4;
  for (int i = t; i < 768; i += 256) Ps[(i >> 4) * 72 + 48 + (i & 15)] = (bf16)0.0f;
  for (int i = t; i < 512; i += 256) Vt[(i >> 4) * 72 + 48 + (i & 15)] = (bf16)0.0f;
  const bf16* zb = Z + (size_t)sh * 2304;
  const float* mc = Mc + h * 2304;
  const float* ic = Ic + h * 2304;
  for (int c = t; c < 288; c += 256) {
    int r = c / 6, seg = c - r * 6;
    int idx = r * 48 + seg * 8;
    bf16x8 zv = *(const bf16x8*)(zb + idx);
    f32x4 m0v = *(const f32x4*)(mc + idx), m1v = *(const f32x4*)(mc + idx + 4);
    f32x4 i0v = *(const f32x4*)(ic + idx), i1v = *(const f32x4*)(ic + idx + 4);
    bf16x8 pv;
    for (int e = 0; e < 4; ++e) pv[e] = (bf16)(__expf((float)zv[e] - m0v[e]) * i0v[e]);
    for (int e = 0; e < 4; ++e) pv[4 + e] = (bf16)(__expf((float)zv[4 + e] - m1v[e]) * i1v[e]);
    *(bf16x8*)(Ps + r * 72 + seg * 8) = pv;
  }
  for (int c = t; c < 192; c += 256) {
    int j = c >> 2, seg = c & 3;
    bf16x8 v = *(const bf16x8*)(QKV + (size_t)(s * 48 + j) * 768 + 512 + h * 32 + seg * 8);
    for (int e = 0; e < 8; ++e) Vt[(seg * 8 + e) * 72 + j] = v[e];
  }
  __syncthreads();
  for (int t6 = wave; t6 < 6; t6 += 4) {
    int ti = t6 >> 1, td = t6 & 1;
    f32x4 a2 = {};
    for (int k0 = 0; k0 < 64; k0 += 32) {
      bf16x8 af = *(const bf16x8*)(Ps + (ti * 16 + fr) * 72 + k0 + kq * 8);
      bf16x8 bv = *(const bf16x8*)(Vt + (td * 16 + fr) * 72 + k0 + kq * 8);
      a2 = __builtin_amdgcn_mfma_f32_16x16x32_bf16(af, bv, a2, 0, 0, 0);
    }
    for (int r = 0; r < 4; ++r)
      Ost[(ti * 16 + kq * 4 + r) * 32 + td * 16 + fr] = (bf16)a2[r];
  }
  __syncthreads();
  bf16* ob = O + (size_t)sh * 1536;
  for (int c = t; c < 192; c += 256)
    *(bf16x8*)(ob + c * 8) = *(const bf16x8*)(Ost + c * 8);
}

// ---------------- out = LN(Xa + Xb), rows of 256, bf16 ----------------
__global__ __launch_bounds__(256) void k_add_ln(
    const bf16* __restrict__ Xa, const bf16* __restrict__ Xb, bf16* __restrict__ out) {
  const int t = threadIdx.x, lane = t & 63, w = t >> 6;
  const size_t off = ((size_t)blockIdx.x * 4 + w) * 256 + lane * 4;
  bf16x4 av = *(const bf16x4*)(Xa + off);
  bf16x4 bv = *(const bf16x4*)(Xb + off);
  f32x4 x;
  for (int c = 0; c < 4; ++c) x[c] = (float)av[c] + (float)bv[c];
  float sum = x[0] + x[1] + x[2] + x[3];
  for (int o = 1; o < 64; o <<= 1) sum += __shfl_xor(sum, o);
  float mean = sum * (1.0f / 256.0f);
  float q = 0.0f;
  for (int c = 0; c < 4; ++c) { float d = x[c] - mean; q += d * d; }
  for (int o = 1; o < 64; o <<= 1) q += __shfl_xor(q, o);
  float rstd = rsqrtf(q * (1.0f / 256.0f) + 1e-5f);
  bf16x4 y;
  for (int c = 0; c < 4; ++c) y[c] = (bf16)((x[c] - mean) * rstd);
  *(bf16x4*)(out + off) = y;
}

// ---------------- y[m] = dot(H[m,:256], w) + b ----------------
__global__ __launch_bounds__(256) void k_ydot(
    const bf16* __restrict__ H, const float* __restrict__ w,
    const float* __restrict__ b, float* __restrict__ Y) {
  const int t = threadIdx.x, lane = t & 63, wv = t >> 6;
  const size_t row = (size_t)blockIdx.x * 4 + wv;
  bf16x4 hx = *(const bf16x4*)(H + row * 256 + lane * 4);
  f32x4 ww = *(const f32x4*)(w + lane * 4);
  float s = (float)hx[0] * ww[0] + (float)hx[1] * ww[1] + (float)hx[2] * ww[2] + (float)hx[3] * ww[3];
  for (int o = 1; o < 64; o <<= 1) s += __shfl_xor(s, o);
  if (lane == 0) Y[row] = s + b[0];
}

// ---------------- softmax over b (48) per column ----------------
__global__ void k_softmax48(const float* __restrict__ Y, float* __restrict__ O) {
  int ss = blockIdx.x * 256 + threadIdx.x;
  if (ss >= 900) return;
  float m = -FLT_MAX;
  for (int b = 0; b < 48; ++b) m = fmaxf(m, Y[b * 900 + ss]);
  float sum = 0.0f;
  for (int b = 0; b < 48; ++b) sum += __expf(Y[b * 900 + ss] - m);
  float inv = 1.0f / sum;
  for (int b = 0; b < 48; ++b) O[b * 900 + ss] = __expf(Y[b * 900 + ss] - m) * inv;
}

extern "C" void kernel_launch(void* const* d_in, const int* in_sizes, int n_in,
                              void* d_out, int out_size, void* d_ws, size_t ws_size,
                              hipStream_t stream) {
  (void)in_sizes; (void)n_in; (void)out_size;
  const float* X_en = (const float*)d_in[0];
  const float* X_de = (const float*)d_in[1];
  const float* conv1_w = (const float*)d_in[2];
  const float* conv1_b = (const float*)d_in[3];
  const float* conv2_w = (const float*)d_in[4];
  const float* conv2_b = (const float*)d_in[5];
  const float* enc_wq = (const float*)d_in[6];
  const float* enc_wk = (const float*)d_in[7];
  const float* enc_wv = (const float*)d_in[8];
  const float* enc_rel = (const float*)d_in[9];
  const float* enc_f1w = (const float*)d_in[10];
  const float* enc_f1b = (const float*)d_in[11];
  const float* enc_f2w = (const float*)d_in[12];
  const float* enc_f2b = (const float*)d_in[13];
  const float* dm_wq = (const float*)d_in[14];
  const float* dm_wk = (const float*)d_in[15];
  const float* dm_wv = (const float*)d_in[16];
  const float* dm_rel = (const float*)d_in[17];
  const float* dm_l1w = (const float*)d_in[18];
  const float* dm_l1b = (const float*)d_in[19];
  const float* dm_l2w = (const float*)d_in[20];
  const float* dm_l2b = (const float*)d_in[21];
  const float* dc_wq = (const float*)d_in[22];
  const float* dc_wk = (const float*)d_in[23];
  const float* dc_wv = (const float*)d_in[24];
  const float* dc_rel = (const float*)d_in[25];
  const float* d_f1w = (const float*)d_in[26];
  const float* d_f1b = (const float*)d_in[27];
  const float* d_f2w = (const float*)d_in[28];
  const float* d_f2b = (const float*)d_in[29];
  const float* out_w = (const float*)d_in[30];
  const float* out_b = (const float*)d_in[31];
  float* OUT = (float*)d_out;

  // ---- workspace layout ----
  const size_t SLOT = 22118400;  // 43200*256 bf16
  char* ws = (char*)d_ws;
  size_t o = 0;
  bf16* S1 = (bf16*)(ws + o); o += SLOT;  // XEb -> ENCb
  bf16* S2 = (bf16*)(ws + o); o += SLOT;  // XDb -> (cross stats)
  bf16* S3 = (bf16*)(ws + o); o += SLOT;  // (enc RelT) -> o1 -> (dm stats) -> (cross RelT) -> h2
  bf16* S4 = (bf16*)(ws + o); o += SLOT;  // (enc stats) -> h1 -> h3
  bf16* S5 = (bf16*)(ws + o); o += SLOT;  // attn-out / ffn-out / (dm RelT)
  char* U = ws + o; o += 33177600 + 3 * SLOT;  // Z + QKV, union { HID, XR+C1R }
  bf16* Zb = (bf16*)U;
  bf16* QKV = (bf16*)(U + 33177600);
  bf16* XR = (bf16*)U;                    // conv phase only
  bf16* C1R = (bf16*)(U + 3145728);       // conv phase only
  bf16* HID = (bf16*)U;                   // FFN phase only
  bf16* wa = (bf16*)(ws + o); o += 4603904 + 16384;
  float* Y = (float*)(ws + o); o += 172800;
  if (ws_size < o) return;

  bf16* zpage = (bf16*)Y;  // 512 B zero page; Y dead until k_ydot
  float* encM = (float*)S4; float* encI = encM + 18432;
  float* dmM  = (float*)S3; float* dmI  = dmM + 18432;
  float* crM  = (float*)S2; float* crI  = crM + 18432;
  bf16* encRel = S3;   // free until o1 written
  bf16* dmRel  = S5;   // free until dm attn_av writes S5
  bf16* crRel  = S3;   // o1 dead after enc_out

  // weight arena (element offsets)
  bf16* c1p = wa;
  bf16* c2p = wa + 73728;
  bf16* EQKVw = wa + 663552;
  bf16* MQKVw = wa + 860160;
  bf16* cqw = wa + 1056768;
  bf16* CKVw = wa + 1122304;
  bf16* ef1 = wa + 1253376;
  bf16* ef2 = wa + 1515520;
  bf16* df1 = wa + 1777664;
  bf16* df2 = wa + 2039808;
  bf16* L1p = wa + 2301952;
  bf16* L2p = wa + 2305408;

  auto gemm = [&](const bf16* A, const bf16* B, const float* bias, bf16* C,
                  int M, int N, int K, int relu, int ldc, int coff) {
    k_gemm128<<<dim3((M + 127) / 128, N / 128), dim3(256), 0, stream>>>(
        A, B, bias, C, M, N, K, relu, ldc, coff);
  };

  // ---- weight prep ----
  k_zero<<<dim3(1), dim3(256), 0, stream>>>(zpage);
  k_pack_conv<<<dim3(288), dim3(256), 0, stream>>>(conv1_w, c1p, 256, 32, 73728);
  k_pack_conv<<<dim3(2304), dim3(256), 0, stream>>>(conv2_w, c2p, 256, 256, 589824);
  k_prep_lin<<<dim3(1), dim3(256), 0, stream>>>(dm_l1w, dm_l2w, L1p, L2p);
  {
    CastSegs sg;
    const float* srcs[13] = {enc_wq, enc_wk, enc_wv, dm_wq, dm_wk, dm_wv, dc_wq,
                             dc_wk, dc_wv, enc_f1w, enc_f2w, d_f1w, d_f2w};
    bf16* dsts[13] = {EQKVw, EQKVw + 65536, EQKVw + 131072, MQKVw, MQKVw + 65536,
                      MQKVw + 131072, cqw, CKVw, CKVw + 65536, ef1, ef2, df1, df2};
    int ns[13] = {65536, 65536, 65536, 65536, 65536, 65536, 65536, 65536, 65536,
                  262144, 262144, 262144, 262144};
    int total = 0;
    for (int k = 0; k < 13; ++k) { sg.s[k] = srcs[k]; sg.d[k] = dsts[k]; sg.n[k] = ns[k]; total += ns[k]; }
    k_cast_all<<<dim3((total + 255) / 256), dim3(256), 0, stream>>>(sg, total);
  }

  // ---- conv chains ----
  auto conv_chain = [&](const float* X, bf16* outB) {
    k_prep_x<<<dim3(6144), dim3(256), 0, stream>>>(X, XR);
    k_conv128<32, 0, 32, 1024, 0, 0><<<dim3(338, 2), dim3(256), 0, stream>>>(XR, c1p, conv1_b, C1R, zpage);
    k_conv128<256, 1, 30, 900, 1, 1><<<dim3(338, 2), dim3(256), 0, stream>>>(C1R, c2p, conv2_b, outB, zpage);
  };
  conv_chain(X_en, S1);
  conv_chain(X_de, S2);

  // ---- encoder ----
  gemm(S1, EQKVw, nullptr, QKV, 43200, 768, 256, 0, 768, 0);
  k_prep_rel<<<dim3(900), dim3(256), 0, stream>>>(enc_rel, encRel);
  k_attn_z<0><<<dim3(7200), dim3(256), 0, stream>>>(QKV, encRel, Zb, nullptr, nullptr, nullptr, nullptr);
  k_colstats<<<dim3(144), dim3(256), 0, stream>>>(Zb, encM, encI);
  k_attn_av<<<dim3(7200), dim3(256), 0, stream>>>(Zb, QKV, encM, encI, S5);
  k_add_ln<<<dim3(10800), dim3(256), 0, stream>>>(S1, S5, S3);  // o1
  gemm(S3, ef1, enc_f1b, HID, 43200, 1024, 256, 1, 1024, 0);
  gemm(HID, ef2, enc_f2b, S5, 43200, 256, 1024, 0, 256, 0);
  k_add_ln<<<dim3(10800), dim3(256), 0, stream>>>(S3, S5, S1);  // enc_out

  // ---- decoder masked self-attention ----
  gemm(S2, MQKVw, nullptr, QKV, 43200, 768, 256, 0, 768, 0);
  k_prep_rel<<<dim3(900), dim3(256), 0, stream>>>(dm_rel, dmRel);
  k_attn_z<1><<<dim3(7200), dim3(256), 0, stream>>>(QKV, dmRel, Zb, L1p, L2p, dm_l1b, dm_l2b);
  k_colstats<<<dim3(144), dim3(256), 0, stream>>>(Zb, dmM, dmI);
  k_attn_av<<<dim3(7200), dim3(256), 0, stream>>>(Zb, QKV, dmM, dmI, S5);
  k_add_ln<<<dim3(10800), dim3(256), 0, stream>>>(S2, S5, S4);  // h1

  // ---- cross attention ----
  gemm(S4, cqw, nullptr, QKV, 43200, 256, 256, 0, 768, 0);
  gemm(S1, CKVw, nullptr, QKV, 43200, 512, 256, 0, 768, 256);
  k_prep_rel<<<dim3(900), dim3(256), 0, stream>>>(dc_rel, crRel);
  k_attn_z<0><<<dim3(7200), dim3(256), 0, stream>>>(QKV, crRel, Zb, nullptr, nullptr, nullptr, nullptr);
  k_colstats<<<dim3(144), dim3(256), 0, stream>>>(Zb, crM, crI);
  k_attn_av<<<dim3(7200), dim3(256), 0, stream>>>(Zb, QKV, crM, crI, S5);
  k_add_ln<<<dim3(10800), dim3(256), 0, stream>>>(S5, S4, S3);  // h2 = ln(c + h1)

  // ---- decoder FFN + head ----
  gemm(S3, df1, d_f1b, HID, 43200, 1024, 256, 1, 1024, 0);
  gemm(HID, df2, d_f2b, S5, 43200, 256, 1024, 0, 256, 0);
  k_add_ln<<<dim3(10800), dim3(256), 0, stream>>>(S3, S5, S4);  // h3
  k_ydot<<<dim3(10800), dim3(256), 0, stream>>>(S4, out_w, out_b, Y);
  k_softmax48<<<dim3(4), dim3(256), 0, stream>>>(Y, OUT);
}

// Round 7
// 1025.550 us; speedup vs baseline: 2.3232x; 1.0770x over previous
//
#include <hip/hip_runtime.h>
#include <float.h>

typedef __bf16 bf16;
typedef __attribute__((ext_vector_type(8))) __bf16 bf16x8;
typedef __attribute__((ext_vector_type(4))) __bf16 bf16x4;
typedef __attribute__((ext_vector_type(4))) float f32x4;

__device__ __forceinline__ int imin(int a, int b) { return a < b ? a : b; }

// async global->LDS, 16B per lane; LDS dest = wave-uniform base + lane*16
__device__ __forceinline__ void gl2lds(const bf16* g, bf16* l) {
  __builtin_amdgcn_global_load_lds(
      (const __attribute__((address_space(1))) void*)g,
      (__attribute__((address_space(3))) void*)l, 16, 0, 0);
}

// ---------------- zero-page + padded lin weights (fused tiny prep) ----------------
__global__ void k_prep_misc(bf16* zp, const float* __restrict__ l1w,
                            const float* __restrict__ l2w,
                            bf16* __restrict__ L1p, bf16* __restrict__ L2p) {
  zp[threadIdx.x] = (bf16)0.0f;
  for (int i = threadIdx.x; i < 3456; i += 256) {
    int r = i / 72, c = i - r * 72;
    L1p[i] = (c < 48) ? (bf16)l1w[r * 48 + c] : (bf16)0.0f;
    L2p[i] = (c < 48) ? (bf16)l2w[r * 48 + c] : (bf16)0.0f;
  }
}

// ---------------- fused f32->bf16 casts (13 segments) ----------------
struct CastSegs { const float* s[13]; bf16* d[13]; int n[13]; };
__global__ void k_cast_all(CastSegs sg, int total) {
  int i = blockIdx.x * 256 + threadIdx.x;
  if (i >= total) return;
  for (int k = 0; k < 13; ++k) {
    if (i < sg.n[k]) { sg.d[k][i] = (bf16)sg.s[k][i]; return; }
    i -= sg.n[k];
  }
}

// ---------------- rel transpose via LDS: (sh, k*48+j) fp32 -> (sh, j*32+k) bf16 ----------------
__global__ __launch_bounds__(256) void k_prep_rel(const float* __restrict__ rel,
                                                  bf16* __restrict__ RelT) {
  __shared__ float tile[32 * 49];
  const int t = threadIdx.x;
  for (int u = 0; u < 8; ++u) {
    const size_t sh = (size_t)blockIdx.x * 8 + u;
    const float* src = rel + sh * 1536;
    bf16* dst = RelT + sh * 1536;
    __syncthreads();
    for (int i = t; i < 1536; i += 256) {
      int k = i / 48, j = i - k * 48;
      tile[k * 49 + j] = src[i];
    }
    __syncthreads();
    for (int i = t; i < 1536; i += 256) {
      int j = i >> 5, k = i & 31;
      dst[i] = (bf16)tile[k * 49 + j];
    }
  }
}

// ---------------- X_en|X_de (b,32,32,32) -> XR rows (96*1024, 32ch) bf16 ----------------
__global__ void k_prep_x(const float* __restrict__ XE, const float* __restrict__ XD,
                         bf16* __restrict__ XR) {
  int idx = blockIdx.x * 256 + threadIdx.x;
  if (idx >= 96 * 1024 * 32) return;
  int b = idx >> 15, r = idx & 32767, pos = r >> 5, ic = r & 31;
  const float* X = (b < 48) ? XE : XD;
  int bl = (b < 48) ? b : b - 48;
  XR[idx] = (bf16)X[((size_t)(bl * 32 + ic) << 10) + pos];
}

// ---------------- conv weight pack: (OC,IC,3,3) -> 9 x (OC,IC) bf16 ----------------
__global__ void k_pack_conv(const float* __restrict__ w, bf16* __restrict__ dst,
                            int OC, int IC, int total) {
  int idx = blockIdx.x * 256 + threadIdx.x;
  if (idx >= total) return;
  int t = idx / (OC * IC);
  int rem = idx - t * OC * IC;
  int oc = rem / IC, ic = rem - oc * IC;
  dst[idx] = (bf16)w[(size_t)(oc * IC + ic) * 9 + t];
}

// ---------------- 128x128 GEMM, BK=64 (two-chunk unroll): C[m, coff+n] = A x B^T ----------------
// If n0 >= nsplit: use A2/B2 with local n (merged dual-GEMM launch). K%64==0, N%128==0.
__global__ __launch_bounds__(256, 2) void k_gemm128(
    const bf16* __restrict__ A, const bf16* __restrict__ A2,
    const bf16* __restrict__ B, const bf16* __restrict__ B2, int nsplit,
    const float* __restrict__ bias, bf16* __restrict__ C,
    int M, int N, int K, int relu, int ldc, int coff) {
  __shared__ alignas(16) bf16 SM[16384];
  bf16* As = SM;            // chunk0, 128x32
  bf16* Asx = SM + 4096;    // chunk1
  bf16* Bs = SM + 8192;
  bf16* Bsx = SM + 12288;
  const int t = threadIdx.x, wave = t >> 6;
  const int lane = t & 63, fr = lane & 15, kq = lane >> 4;
  const int wm = wave & 1, wn = wave >> 1;
  const int m0 = blockIdx.x * 128, n0 = blockIdx.y * 128;
  const int srow = t >> 2, kseg = (t & 3) * 8;
  const bf16* Ause = A; const bf16* Buse = B; int nloc = n0;
  if (n0 >= nsplit) { Ause = A2; Buse = B2; nloc = n0 - nsplit; }
  f32x4 acc[4][4] = {};
  const bf16* gA0 = Ause + (size_t)imin(m0 + srow, M - 1) * K + kseg;
  const bf16* gA1 = Ause + (size_t)imin(m0 + 64 + srow, M - 1) * K + kseg;
  const bf16* gB0 = Buse + (size_t)(nloc + srow) * K + kseg;
  const bf16* gB1 = Buse + (size_t)(nloc + 64 + srow) * K + kseg;
  bf16* sA0 = As + wave * 512;
  bf16* sA1 = As + 2048 + wave * 512;
  bf16* sB0 = Bs + wave * 512;
  bf16* sB1 = Bs + 2048 + wave * 512;
  for (int k0 = 0; k0 < K; k0 += 64) {
    gl2lds(gA0 + k0, sA0);          gl2lds(gA0 + k0 + 32, sA0 + 4096);
    gl2lds(gA1 + k0, sA1);          gl2lds(gA1 + k0 + 32, sA1 + 4096);
    gl2lds(gB0 + k0, sB0);          gl2lds(gB0 + k0 + 32, sB0 + 4096);
    gl2lds(gB1 + k0, sB1);          gl2lds(gB1 + k0 + 32, sB1 + 4096);
    __syncthreads();
    for (int ch = 0; ch < 2; ++ch) {
      const bf16* Ac = ch ? Asx : As;
      const bf16* Bc = ch ? Bsx : Bs;
      bf16x8 af[4], bw[4];
      for (int mt = 0; mt < 4; ++mt)
        af[mt] = *(const bf16x8*)(Ac + (wm * 64 + mt * 16 + fr) * 32 + kq * 8);
      for (int nt = 0; nt < 4; ++nt)
        bw[nt] = *(const bf16x8*)(Bc + (wn * 64 + nt * 16 + fr) * 32 + kq * 8);
      for (int mt = 0; mt < 4; ++mt)
        for (int nt = 0; nt < 4; ++nt)
          acc[mt][nt] = __builtin_amdgcn_mfma_f32_16x16x32_bf16(af[mt], bw[nt], acc[mt][nt], 0, 0, 0);
    }
    __syncthreads();
  }
  bf16* Cst = SM;  // 64 x 128
  for (int half = 0; half < 2; ++half) {
    if (wm == half) {
      for (int mt = 0; mt < 4; ++mt)
        for (int nt = 0; nt < 4; ++nt) {
          int n = n0 + wn * 64 + nt * 16 + fr;
          float bv = bias ? bias[n] : 0.0f;
          for (int r = 0; r < 4; ++r) {
            float v = acc[mt][nt][r] + bv;
            if (relu) v = fmaxf(v, 0.0f);
            Cst[(mt * 16 + kq * 4 + r) * 128 + wn * 64 + nt * 16 + fr] = (bf16)v;
          }
        }
    }
    __syncthreads();
    for (int i = t; i < 1024; i += 256) {
      int r = i >> 4, cs = i & 15;
      int gm = m0 + half * 64 + r;
      if (gm < M)
        *(bf16x8*)(C + (size_t)gm * ldc + coff + n0 + cs * 8) = *(const bf16x8*)(Cst + r * 128 + cs * 8);
    }
    __syncthreads();
  }
}

// ---------------- conv1 (BK=32): shifted 128x128 GEMM, merged 96 batches ----------------
template <int CIN, int PAD, int SRCW, int SRCROWS, int CHECK, int TRANS, int MTOT>
__global__ __launch_bounds__(256, 2) void k_conv128(
    const bf16* __restrict__ A, const bf16* __restrict__ Bp,
    const float* __restrict__ bias, bf16* __restrict__ C,
    const bf16* __restrict__ zpage) {
  __shared__ alignas(16) bf16 SM[8192];
  bf16* As = SM;
  bf16* Bs = SM + 4096;
  const int t = threadIdx.x, wave = t >> 6;
  const int lane = t & 63, fr = lane & 15, kq = lane >> 4;
  const int wm = wave & 1, wn = wave >> 1;
  const int m0 = blockIdx.x * 128, n0 = blockIdx.y * 128;
  const int srow = t >> 2, kseg = (t & 3) * 8;
  f32x4 acc[4][4] = {};
  int bb[2], yy[2], xx[2];
  for (int hf = 0; hf < 2; ++hf) {
    int m = imin(m0 + hf * 64 + srow, MTOT - 1);
    int b = m / 900, p = m - b * 900;
    bb[hf] = b; yy[hf] = p / 30; xx[hf] = p - (p / 30) * 30;
  }
  bf16* sA0 = As + wave * 512;
  bf16* sA1 = As + 2048 + wave * 512;
  bf16* sB0 = Bs + wave * 512;
  bf16* sB1 = Bs + 2048 + wave * 512;
  for (int k0 = 0; k0 < CIN; k0 += 32) {
    for (int t9 = 0; t9 < 9; ++t9) {
      const int ky = t9 / 3, kx = t9 - ky * 3;
      const bf16* ga[2];
      for (int hf = 0; hf < 2; ++hf) {
        int sy = yy[hf] + ky - PAD, sx = xx[hf] + kx - PAD;
        bool valid = !CHECK || (sy >= 0 && sy < SRCW && sx >= 0 && sx < SRCW);
        ga[hf] = (valid ? A + (size_t)(bb[hf] * SRCROWS + sy * SRCW + sx) * CIN : zpage) + kseg;
      }
      const bf16* gb = Bp + (size_t)(t9 * 256 + n0 + srow) * CIN + kseg;
      gl2lds(ga[0] + k0, sA0);
      gl2lds(ga[1] + k0, sA1);
      gl2lds(gb + k0, sB0);
      gl2lds(gb + (size_t)64 * CIN + k0, sB1);
      __syncthreads();
      bf16x8 af[4], bw[4];
      for (int mt = 0; mt < 4; ++mt)
        af[mt] = *(const bf16x8*)(As + (wm * 64 + mt * 16 + fr) * 32 + kq * 8);
      for (int nt = 0; nt < 4; ++nt)
        bw[nt] = *(const bf16x8*)(Bs + (wn * 64 + nt * 16 + fr) * 32 + kq * 8);
      for (int mt = 0; mt < 4; ++mt)
        for (int nt = 0; nt < 4; ++nt)
          acc[mt][nt] = __builtin_amdgcn_mfma_f32_16x16x32_bf16(af[mt], bw[nt], acc[mt][nt], 0, 0, 0);
      __syncthreads();
    }
  }
  bf16* Cst = SM;
  for (int half = 0; half < 2; ++half) {
    if (wm == half) {
      for (int mt = 0; mt < 4; ++mt)
        for (int nt = 0; nt < 4; ++nt) {
          int n = n0 + wn * 64 + nt * 16 + fr;
          float bv = bias[n];
          for (int r = 0; r < 4; ++r) {
            float v = acc[mt][nt][r] + bv;
            if (TRANS)
              Cst[(wn * 64 + nt * 16 + fr) * 64 + mt * 16 + kq * 4 + r] = (bf16)v;
            else
              Cst[(mt * 16 + kq * 4 + r) * 128 + wn * 64 + nt * 16 + fr] = (bf16)v;
          }
        }
    }
    __syncthreads();
    if (TRANS) {
      for (int i = t; i < 2048; i += 256) {
        int oc = i >> 4, pc = i & 15;
        int gm = m0 + half * 64 + pc * 4;
        if (gm < MTOT) {
          int b = gm / 900, p = gm - b * 900;
          *(bf16x4*)(C + (size_t)(b * 256 + n0 + oc) * 900 + p) = *(const bf16x4*)(Cst + oc * 64 + pc * 4);
        }
      }
    } else {
      for (int i = t; i < 1024; i += 256) {
        int r = i >> 4, cs = i & 15;
        int gm = m0 + half * 64 + r;
        if (gm < MTOT)
          *(bf16x8*)(C + (size_t)gm * 256 + n0 + cs * 8) = *(const bf16x8*)(Cst + r * 128 + cs * 8);
      }
    }
    __syncthreads();
  }
}

// ---------------- conv2 (CIN=256, pad=1), BK=64 two-chunk unroll, merged 96 batches ----------------
__global__ __launch_bounds__(256, 2) void k_conv2x(
    const bf16* __restrict__ A, const bf16* __restrict__ Bp,
    const float* __restrict__ bias, bf16* __restrict__ C,
    const bf16* __restrict__ zpage) {
  __shared__ alignas(16) bf16 SM[16384];
  bf16* As = SM;
  bf16* Bs = SM + 8192;
  const int t = threadIdx.x, wave = t >> 6;
  const int lane = t & 63, fr = lane & 15, kq = lane >> 4;
  const int wm = wave & 1, wn = wave >> 1;
  const int m0 = blockIdx.x * 128, n0 = blockIdx.y * 128;
  const int srow = t >> 2, kseg = (t & 3) * 8;
  f32x4 acc[4][4] = {};
  int bb[2], yy[2], xx[2];
  for (int hf = 0; hf < 2; ++hf) {
    int m = imin(m0 + hf * 64 + srow, 86399);
    int b = m / 900, p = m - b * 900;
    bb[hf] = b; yy[hf] = p / 30; xx[hf] = p - (p / 30) * 30;
  }
  bf16* sA0 = As + wave * 512;
  bf16* sA1 = As + 2048 + wave * 512;
  bf16* sB0 = Bs + wave * 512;
  bf16* sB1 = Bs + 2048 + wave * 512;
  for (int k0 = 0; k0 < 256; k0 += 64) {
    for (int t9 = 0; t9 < 9; ++t9) {
      const int ky = t9 / 3, kx = t9 - ky * 3;
      const bf16* ga[2];
      for (int hf = 0; hf < 2; ++hf) {
        int sy = yy[hf] + ky - 1, sx = xx[hf] + kx - 1;
        bool valid = (sy >= 0 && sy < 30 && sx >= 0 && sx < 30);
        ga[hf] = (valid ? A + (size_t)(bb[hf] * 900 + sy * 30 + sx) * 256 : zpage) + kseg;
      }
      const bf16* gb = Bp + (size_t)(t9 * 256 + n0 + srow) * 256 + kseg;
      gl2lds(ga[0] + k0, sA0);               gl2lds(ga[0] + k0 + 32, sA0 + 4096);
      gl2lds(ga[1] + k0, sA1);               gl2lds(ga[1] + k0 + 32, sA1 + 4096);
      gl2lds(gb + k0, sB0);                  gl2lds(gb + k0 + 32, sB0 + 4096);
      gl2lds(gb + 64 * 256 + k0, sB1);       gl2lds(gb + 64 * 256 + k0 + 32, sB1 + 4096);
      __syncthreads();
      for (int ch = 0; ch < 2; ++ch) {
        const bf16* Ac = As + ch * 4096;
        const bf16* Bc = Bs + ch * 4096;
        bf16x8 af[4], bw[4];
        for (int mt = 0; mt < 4; ++mt)
          af[mt] = *(const bf16x8*)(Ac + (wm * 64 + mt * 16 + fr) * 32 + kq * 8);
        for (int nt = 0; nt < 4; ++nt)
          bw[nt] = *(const bf16x8*)(Bc + (wn * 64 + nt * 16 + fr) * 32 + kq * 8);
        for (int mt = 0; mt < 4; ++mt)
          for (int nt = 0; nt < 4; ++nt)
            acc[mt][nt] = __builtin_amdgcn_mfma_f32_16x16x32_bf16(af[mt], bw[nt], acc[mt][nt], 0, 0, 0);
      }
      __syncthreads();
    }
  }
  bf16* Cst = SM;  // 128 oc x 64 p
  for (int half = 0; half < 2; ++half) {
    if (wm == half) {
      for (int mt = 0; mt < 4; ++mt)
        for (int nt = 0; nt < 4; ++nt) {
          int n = n0 + wn * 64 + nt * 16 + fr;
          float bv = bias[n];
          for (int r = 0; r < 4; ++r) {
            float v = acc[mt][nt][r] + bv;
            Cst[(wn * 64 + nt * 16 + fr) * 64 + mt * 16 + kq * 4 + r] = (bf16)v;
          }
        }
    }
    __syncthreads();
    for (int i = t; i < 2048; i += 256) {
      int oc = i >> 4, pc = i & 15;
      int gm = m0 + half * 64 + pc * 4;
      int b = gm / 900, p = gm - b * 900;
      *(bf16x4*)(C + (size_t)(b * 256 + n0 + oc) * 900 + p) = *(const bf16x4*)(Cst + oc * 64 + pc * 4);
    }
    __syncthreads();
  }
}

// ---------------- attention logits z for one (s,h) ----------------
template <int MASKED>
__global__ __launch_bounds__(256, MASKED ? 4 : 5) void k_attn_z(
    const bf16* __restrict__ QKV, const bf16* __restrict__ RelT, bf16* __restrict__ Z,
    const bf16* __restrict__ L1p, const bf16* __restrict__ L2p,
    const float* __restrict__ l1b, const float* __restrict__ l2b) {
  __shared__ alignas(16) bf16 QKs[2][48 * 40];
  __shared__ float EMD[48 * 49];
  __shared__ alignas(16) bf16 zst[48 * 48];
  __shared__ alignas(16) bf16 Sc[MASKED ? 48 * 72 : 8];
  __shared__ alignas(16) bf16 T2b[MASKED ? 48 * 72 : 8];
  const int sh = blockIdx.x, s = sh >> 3, h = sh & 7;
  const int t = threadIdx.x, wave = t >> 6, lane = t & 63, fr = lane & 15, kq = lane >> 4;
  const float scale = 0.17677669529663687f;  // 1/sqrt(32)
  for (int c = t; c < 384; c += 256) {
    int half = c >= 192 ? 1 : 0, cc = c - half * 192;
    int row = cc >> 2, seg = cc & 3;
    *(bf16x8*)(&QKs[half][row * 40 + seg * 8]) =
        *(const bf16x8*)(QKV + (size_t)(s * 48 + row) * 768 + half * 256 + h * 32 + seg * 8);
  }
  if constexpr (MASKED) {
    for (int i = t; i < 768; i += 256) {
      int r = i >> 4, c = 48 + (i & 15);
      Sc[r * 72 + c] = (bf16)0.0f;
      T2b[r * 72 + c] = (bf16)0.0f;
    }
  }
  __syncthreads();
  const bf16* relb = RelT + (size_t)sh * 1536;
  f32x4 sreg[3];
  int u = 0;
  for (int t9 = wave; t9 < 9; t9 += 4, ++u) {
    int ti = t9 / 3, tj = t9 - ti * 3;
    bf16x8 af = *(const bf16x8*)(&QKs[0][(ti * 16 + fr) * 40 + kq * 8]);
    bf16x8 bk = *(const bf16x8*)(&QKs[1][(tj * 16 + fr) * 40 + kq * 8]);
    bf16x8 rf = *(const bf16x8*)(relb + (tj * 16 + fr) * 32 + kq * 8);
    f32x4 sacc = {}, eacc = {};
    sacc = __builtin_amdgcn_mfma_f32_16x16x32_bf16(af, bk, sacc, 0, 0, 0);
    eacc = __builtin_amdgcn_mfma_f32_16x16x32_bf16(af, rf, eacc, 0, 0, 0);
    for (int r = 0; r < 4; ++r)
      EMD[(ti * 16 + kq * 4 + r) * 49 + tj * 16 + fr] = eacc[r];
    if constexpr (MASKED) {
      for (int r = 0; r < 4; ++r)
        Sc[(ti * 16 + kq * 4 + r) * 72 + tj * 16 + fr] = (bf16)(sacc[r] * scale);
    } else {
      for (int r = 0; r < 4; ++r) sreg[u][r] = sacc[r] * scale;
    }
  }
  __syncthreads();
  if constexpr (!MASKED) {
    u = 0;
    for (int t9 = wave; t9 < 9; t9 += 4, ++u) {
      int ti = t9 / 3, tj = t9 - ti * 3;
      for (int r = 0; r < 4; ++r) {
        int i = ti * 16 + kq * 4 + r, j = tj * 16 + fr;
        float v = sreg[u][r];
        if (j <= i) v += EMD[i * 49 + 47 + j - i];
        zst[i * 48 + j] = (bf16)v;
      }
    }
  } else {
    for (int t9 = wave; t9 < 9; t9 += 4) {
      int ti = t9 / 3, tj = t9 - ti * 3;
      f32x4 a2 = {};
      for (int k0 = 0; k0 < 64; k0 += 32) {
        bf16x8 af = *(const bf16x8*)(Sc + (ti * 16 + fr) * 72 + k0 + kq * 8);
        bf16x8 bw = *(const bf16x8*)(L1p + (tj * 16 + fr) * 72 + k0 + kq * 8);
        a2 = __builtin_amdgcn_mfma_f32_16x16x32_bf16(af, bw, a2, 0, 0, 0);
      }
      for (int r = 0; r < 4; ++r) {
        int i = ti * 16 + kq * 4 + r, a = tj * 16 + fr;
        T2b[a * 72 + i] = (bf16)(a2[r] + l1b[a]);
      }
    }
    __syncthreads();
    for (int t9 = wave; t9 < 9; t9 += 4) {
      int ti = t9 / 3, tj = t9 - ti * 3;
      f32x4 a2 = {};
      for (int k0 = 0; k0 < 64; k0 += 32) {
        bf16x8 af = *(const bf16x8*)(T2b + (ti * 16 + fr) * 72 + k0 + kq * 8);
        bf16x8 bw = *(const bf16x8*)(L2p + (tj * 16 + fr) * 72 + k0 + kq * 8);
        a2 = __builtin_amdgcn_mfma_f32_16x16x32_bf16(af, bw, a2, 0, 0, 0);
      }
      for (int r = 0; r < 4; ++r) {
        int aa = ti * 16 + kq * 4 + r, cc = tj * 16 + fr;
        float v;
        if (cc > aa) v = -10000.0f;  // masked column -> exactly uniform after softmax
        else v = a2[r] + l2b[cc] + EMD[aa * 49 + 47 + cc - aa];
        zst[aa * 48 + cc] = (bf16)v;
      }
    }
  }
  __syncthreads();
  bf16* zb = Z + (size_t)sh * 2304;
  for (int c = t; c < 288; c += 256)
    *(bf16x8*)(zb + c * 8) = *(const bf16x8*)(zst + c * 8);
}

// ---------------- per-column (over s=900) online max & inverse-sum ----------------
// grid 288: 64 cols/block (8 thr x 8 cols, bf16x8) x 32 s-groups of 29
__global__ __launch_bounds__(256) void k_colstats(const bf16* __restrict__ Z,
                                                  float* __restrict__ Mc, float* __restrict__ Ic) {
  __shared__ float rm[32][72], rs[32][72];
  const int t = threadIdx.x, cg = t & 7, sg = t >> 3;
  const bf16* p = Z + blockIdx.x * 64 + cg * 8;
  const int s0 = sg * 29, s1 = imin(900, s0 + 29);
  float m[8], ss[8];
  for (int e = 0; e < 8; ++e) { m[e] = -FLT_MAX; ss[e] = 0.0f; }
  for (int s = s0; s < s1; ++s) {
    bf16x8 zv = *(const bf16x8*)(p + (size_t)s * 18432);
    for (int e = 0; e < 8; ++e) {
      float v = (float)zv[e];
      if (v > m[e]) { ss[e] *= __expf(m[e] - v); m[e] = v; }
      ss[e] += __expf(v - m[e]);
    }
  }
  for (int e = 0; e < 8; ++e) { rm[sg][cg * 8 + e] = m[e]; rs[sg][cg * 8 + e] = ss[e]; }
  __syncthreads();
  if (t < 64) {
    float M2 = -FLT_MAX;
    for (int g = 0; g < 32; ++g) M2 = fmaxf(M2, rm[g][t]);
    float S2 = 0.0f;
    for (int g = 0; g < 32; ++g) S2 += rs[g][t] * __expf(rm[g][t] - M2);
    Mc[blockIdx.x * 64 + t] = M2;
    Ic[blockIdx.x * 64 + t] = 1.0f / S2;
  }
}

// ---------------- O[s,h,i,d] = sum_j softmax(Z)[s,h,i,j] V[s,h,j,d] ----------------
__global__ __launch_bounds__(256, 6) void k_attn_av(
    const bf16* __restrict__ Z, const bf16* __restrict__ QKV,
    const float* __restrict__ Mc, const float* __restrict__ Ic, bf16* __restrict__ O) {
  __shared__ alignas(16) bf16 Ps[48 * 72];
  __shared__ alignas(16) bf16 Vt[32 * 72];
  __shared__ alignas(16) bf16 Ost[48 * 32];
  const int sh = blockIdx.x, s = sh >> 3, h = sh & 7;
  const int t = threadIdx.x, wave = t >> 6, lane = t & 63, fr = lane & 15, kq = lane >> 4;
  for (int i = t; i < 768; i += 256) Ps[(i >> 4) * 72 + 48 + (i & 15)] = (bf16)0.0f;
  for (int i = t; i < 512; i += 256) Vt[(i >> 4) * 72 + 48 + (i & 15)] = (bf16)0.0f;
  const bf16* zb = Z + (size_t)sh * 2304;
  const float* mc = Mc + h * 2304;
  const float* ic = Ic + h * 2304;
  for (int c = t; c < 288; c += 256) {
    int r = c / 6, seg = c - r * 6;
    int idx = r * 48 + seg * 8;
    bf16x8 zv = *(const bf16x8*)(zb + idx);
    f32x4 m0v = *(const f32x4*)(mc + idx), m1v = *(const f32x4*)(mc + idx + 4);
    f32x4 i0v = *(const f32x4*)(ic + idx), i1v = *(const f32x4*)(ic + idx + 4);
    bf16x8 pv;
    for (int e = 0; e < 4; ++e) pv[e] = (bf16)(__expf((float)zv[e] - m0v[e]) * i0v[e]);
    for (int e = 0; e < 4; ++e) pv[4 + e] = (bf16)(__expf((float)zv[4 + e] - m1v[e]) * i1v[e]);
    *(bf16x8*)(Ps + r * 72 + seg * 8) = pv;
  }
  for (int c = t; c < 192; c += 256) {
    int j = c >> 2, seg = c & 3;
    bf16x8 v = *(const bf16x8*)(QKV + (size_t)(s * 48 + j) * 768 + 512 + h * 32 + seg * 8);
    for (int e = 0; e < 8; ++e) Vt[(seg * 8 + e) * 72 + j] = v[e];
  }
  __syncthreads();
  for (int t6 = wave; t6 < 6; t6 += 4) {
    int ti = t6 >> 1, td = t6 & 1;
    f32x4 a2 = {};
    for (int k0 = 0; k0 < 64; k0 += 32) {
      bf16x8 af = *(const bf16x8*)(Ps + (ti * 16 + fr) * 72 + k0 + kq * 8);
      bf16x8 bv = *(const bf16x8*)(Vt + (td * 16 + fr) * 72 + k0 + kq * 8);
      a2 = __builtin_amdgcn_mfma_f32_16x16x32_bf16(af, bv, a2, 0, 0, 0);
    }
    for (int r = 0; r < 4; ++r)
      Ost[(ti * 16 + kq * 4 + r) * 32 + td * 16 + fr] = (bf16)a2[r];
  }
  __syncthreads();
  bf16* ob = O + (size_t)sh * 1536;
  for (int c = t; c < 192; c += 256)
    *(bf16x8*)(ob + c * 8) = *(const bf16x8*)(Ost + c * 8);
}

// ---------------- out = LN(Xa + Xb), rows of 256, bf16 ----------------
__global__ __launch_bounds__(256) void k_add_ln(
    const bf16* __restrict__ Xa, const bf16* __restrict__ Xb, bf16* __restrict__ out) {
  const int t = threadIdx.x, lane = t & 63, w = t >> 6;
  const size_t off = ((size_t)blockIdx.x * 4 + w) * 256 + lane * 4;
  bf16x4 av = *(const bf16x4*)(Xa + off);
  bf16x4 bv = *(const bf16x4*)(Xb + off);
  f32x4 x;
  for (int c = 0; c < 4; ++c) x[c] = (float)av[c] + (float)bv[c];
  float sum = x[0] + x[1] + x[2] + x[3];
  for (int o = 1; o < 64; o <<= 1) sum += __shfl_xor(sum, o);
  float mean = sum * (1.0f / 256.0f);
  float q = 0.0f;
  for (int c = 0; c < 4; ++c) { float d = x[c] - mean; q += d * d; }
  for (int o = 1; o < 64; o <<= 1) q += __shfl_xor(q, o);
  float rstd = rsqrtf(q * (1.0f / 256.0f) + 1e-5f);
  bf16x4 y;
  for (int c = 0; c < 4; ++c) y[c] = (bf16)((x[c] - mean) * rstd);
  *(bf16x4*)(out + off) = y;
}

// ---------------- y[m] = dot(H[m,:256], w) + b ----------------
__global__ __launch_bounds__(256) void k_ydot(
    const bf16* __restrict__ H, const float* __restrict__ w,
    const float* __restrict__ b, float* __restrict__ Y) {
  const int t = threadIdx.x, lane = t & 63, wv = t >> 6;
  const size_t row = (size_t)blockIdx.x * 4 + wv;
  bf16x4 hx = *(const bf16x4*)(H + row * 256 + lane * 4);
  f32x4 ww = *(const f32x4*)(w + lane * 4);
  float s = (float)hx[0] * ww[0] + (float)hx[1] * ww[1] + (float)hx[2] * ww[2] + (float)hx[3] * ww[3];
  for (int o = 1; o < 64; o <<= 1) s += __shfl_xor(s, o);
  if (lane == 0) Y[row] = s + b[0];
}

// ---------------- softmax over b (48) per column ----------------
__global__ void k_softmax48(const float* __restrict__ Y, float* __restrict__ O) {
  int ss = blockIdx.x * 256 + threadIdx.x;
  if (ss >= 900) return;
  float m = -FLT_MAX;
  for (int b = 0; b < 48; ++b) m = fmaxf(m, Y[b * 900 + ss]);
  float sum = 0.0f;
  for (int b = 0; b < 48; ++b) sum += __expf(Y[b * 900 + ss] - m);
  float inv = 1.0f / sum;
  for (int b = 0; b < 48; ++b) O[b * 900 + ss] = __expf(Y[b * 900 + ss] - m) * inv;
}

extern "C" void kernel_launch(void* const* d_in, const int* in_sizes, int n_in,
                              void* d_out, int out_size, void* d_ws, size_t ws_size,
                              hipStream_t stream) {
  (void)in_sizes; (void)n_in; (void)out_size;
  const float* X_en = (const float*)d_in[0];
  const float* X_de = (const float*)d_in[1];
  const float* conv1_w = (const float*)d_in[2];
  const float* conv1_b = (const float*)d_in[3];
  const float* conv2_w = (const float*)d_in[4];
  const float* conv2_b = (const float*)d_in[5];
  const float* enc_wq = (const float*)d_in[6];
  const float* enc_wk = (const float*)d_in[7];
  const float* enc_wv = (const float*)d_in[8];
  const float* enc_rel = (const float*)d_in[9];
  const float* enc_f1w = (const float*)d_in[10];
  const float* enc_f1b = (const float*)d_in[11];
  const float* enc_f2w = (const float*)d_in[12];
  const float* enc_f2b = (const float*)d_in[13];
  const float* dm_wq = (const float*)d_in[14];
  const float* dm_wk = (const float*)d_in[15];
  const float* dm_wv = (const float*)d_in[16];
  const float* dm_rel = (const float*)d_in[17];
  const float* dm_l1w = (const float*)d_in[18];
  const float* dm_l1b = (const float*)d_in[19];
  const float* dm_l2w = (const float*)d_in[20];
  const float* dm_l2b = (const float*)d_in[21];
  const float* dc_wq = (const float*)d_in[22];
  const float* dc_wk = (const float*)d_in[23];
  const float* dc_wv = (const float*)d_in[24];
  const float* dc_rel = (const float*)d_in[25];
  const float* d_f1w = (const float*)d_in[26];
  const float* d_f1b = (const float*)d_in[27];
  const float* d_f2w = (const float*)d_in[28];
  const float* d_f2b = (const float*)d_in[29];
  const float* out_w = (const float*)d_in[30];
  const float* out_b = (const float*)d_in[31];
  float* OUT = (float*)d_out;

  // ---- workspace layout ----
  const size_t SLOT = 22118400;  // 43200*256 bf16
  char* ws = (char*)d_ws;
  size_t o = 0;
  bf16* S1 = (bf16*)(ws + o); o += SLOT;  // XEb -> ENCb
  bf16* S2 = (bf16*)(ws + o); o += SLOT;  // XDb -> (cross stats)
  bf16* S3 = (bf16*)(ws + o); o += SLOT;  // (enc RelT) -> o1 -> (dm stats) -> (cross RelT) -> h2
  bf16* S4 = (bf16*)(ws + o); o += SLOT;  // (enc stats) -> h1 -> h3
  bf16* S5 = (bf16*)(ws + o); o += SLOT;  // attn-out / ffn-out / (dm RelT)
  char* U = ws + o; o += 33177600 + 3 * SLOT;  // Z + QKV, union { HID, XR+C1R }
  bf16* Zb = (bf16*)U;
  bf16* QKV = (bf16*)(U + 33177600);
  bf16* XR = (bf16*)U;                    // conv phase: 96*1024*32 bf16 = 12.6 MB
  bf16* C1R = (bf16*)(U + 12582912);      // conv phase: 96*900*256 bf16 = 44.2 MB
  bf16* HID = (bf16*)U;                   // FFN phase only
  bf16* wa = (bf16*)(ws + o); o += 4603904 + 16384;
  float* Y = (float*)(ws + o); o += 172800;
  if (ws_size < o) return;

  bf16* zpage = (bf16*)Y;  // 512 B zero page; Y dead until k_ydot
  float* encM = (float*)S4; float* encI = encM + 18432;
  float* dmM  = (float*)S3; float* dmI  = dmM + 18432;
  float* crM  = (float*)S2; float* crI  = crM + 18432;
  bf16* encRel = S3;   // free until o1 written
  bf16* dmRel  = S5;   // free until dm attn_av writes S5
  bf16* crRel  = S3;   // o1 dead after enc_out

  // weight arena (element offsets)
  bf16* c1p = wa;
  bf16* c2p = wa + 73728;
  bf16* EQKVw = wa + 663552;
  bf16* MQKVw = wa + 860160;
  bf16* cqw = wa + 1056768;
  bf16* CKVw = wa + 1122304;
  bf16* ef1 = wa + 1253376;
  bf16* ef2 = wa + 1515520;
  bf16* df1 = wa + 1777664;
  bf16* df2 = wa + 2039808;
  bf16* L1p = wa + 2301952;
  bf16* L2p = wa + 2305408;

  auto gemm = [&](const bf16* A, const bf16* B, const float* bias, bf16* C,
                  int M, int N, int K, int relu, int ldc, int coff) {
    k_gemm128<<<dim3((M + 127) / 128, N / 128), dim3(256), 0, stream>>>(
        A, A, B, B, N, bias, C, M, N, K, relu, ldc, coff);
  };

  // ---- weight prep ----
  k_prep_misc<<<dim3(1), dim3(256), 0, stream>>>(zpage, dm_l1w, dm_l2w, L1p, L2p);
  k_pack_conv<<<dim3(288), dim3(256), 0, stream>>>(conv1_w, c1p, 256, 32, 73728);
  k_pack_conv<<<dim3(2304), dim3(256), 0, stream>>>(conv2_w, c2p, 256, 256, 589824);
  {
    CastSegs sg;
    const float* srcs[13] = {enc_wq, enc_wk, enc_wv, dm_wq, dm_wk, dm_wv, dc_wq,
                             dc_wk, dc_wv, enc_f1w, enc_f2w, d_f1w, d_f2w};
    bf16* dsts[13] = {EQKVw, EQKVw + 65536, EQKVw + 131072, MQKVw, MQKVw + 65536,
                      MQKVw + 131072, cqw, CKVw, CKVw + 65536, ef1, ef2, df1, df2};
    int ns[13] = {65536, 65536, 65536, 65536, 65536, 65536, 65536, 65536, 65536,
                  262144, 262144, 262144, 262144};
    int total = 0;
    for (int k = 0; k < 13; ++k) { sg.s[k] = srcs[k]; sg.d[k] = dsts[k]; sg.n[k] = ns[k]; total += ns[k]; }
    k_cast_all<<<dim3((total + 255) / 256), dim3(256), 0, stream>>>(sg, total);
  }

  // ---- merged conv chain (96 batches: en then de; conv2 writes S1||S2 contiguously) ----
  k_prep_x<<<dim3(12288), dim3(256), 0, stream>>>(X_en, X_de, XR);
  k_conv128<32, 0, 32, 1024, 0, 0, 86400><<<dim3(675, 2), dim3(256), 0, stream>>>(
      XR, c1p, conv1_b, C1R, zpage);
  k_conv2x<<<dim3(675, 2), dim3(256), 0, stream>>>(C1R, c2p, conv2_b, S1, zpage);

  // ---- encoder ----
  gemm(S1, EQKVw, nullptr, QKV, 43200, 768, 256, 0, 768, 0);
  k_prep_rel<<<dim3(900), dim3(256), 0, stream>>>(enc_rel, encRel);
  k_attn_z<0><<<dim3(7200), dim3(256), 0, stream>>>(QKV, encRel, Zb, nullptr, nullptr, nullptr, nullptr);
  k_colstats<<<dim3(288), dim3(256), 0, stream>>>(Zb, encM, encI);
  k_attn_av<<<dim3(7200), dim3(256), 0, stream>>>(Zb, QKV, encM, encI, S5);
  k_add_ln<<<dim3(10800), dim3(256), 0, stream>>>(S1, S5, S3);  // o1
  gemm(S3, ef1, enc_f1b, HID, 43200, 1024, 256, 1, 1024, 0);
  gemm(HID, ef2, enc_f2b, S5, 43200, 256, 1024, 0, 256, 0);
  k_add_ln<<<dim3(10800), dim3(256), 0, stream>>>(S3, S5, S1);  // enc_out

  // ---- decoder masked self-attention ----
  gemm(S2, MQKVw, nullptr, QKV, 43200, 768, 256, 0, 768, 0);
  k_prep_rel<<<dim3(900), dim3(256), 0, stream>>>(dm_rel, dmRel);
  k_attn_z<1><<<dim3(7200), dim3(256), 0, stream>>>(QKV, dmRel, Zb, L1p, L2p, dm_l1b, dm_l2b);
  k_colstats<<<dim3(288), dim3(256), 0, stream>>>(Zb, dmM, dmI);
  k_attn_av<<<dim3(7200), dim3(256), 0, stream>>>(Zb, QKV, dmM, dmI, S5);
  k_add_ln<<<dim3(10800), dim3(256), 0, stream>>>(S2, S5, S4);  // h1

  // ---- cross attention (q + kv merged into one dual-GEMM launch) ----
  k_gemm128<<<dim3(338, 6), dim3(256), 0, stream>>>(
      S4, S1, cqw, CKVw, 256, nullptr, QKV, 43200, 768, 256, 0, 768, 0);
  k_prep_rel<<<dim3(900), dim3(256), 0, stream>>>(dc_rel, crRel);
  k_attn_z<0><<<dim3(7200), dim3(256), 0, stream>>>(QKV, crRel, Zb, nullptr, nullptr, nullptr, nullptr);
  k_colstats<<<dim3(288), dim3(256), 0, stream>>>(Zb, crM, crI);
  k_attn_av<<<dim3(7200), dim3(256), 0, stream>>>(Zb, QKV, crM, crI, S5);
  k_add_ln<<<dim3(10800), dim3(256), 0, stream>>>(S5, S4, S3);  // h2 = ln(c + h1)

  // ---- decoder FFN + head ----
  gemm(S3, df1, d_f1b, HID, 43200, 1024, 256, 1, 1024, 0);
  gemm(HID, df2, d_f2b, S5, 43200, 256, 1024, 0, 256, 0);
  k_add_ln<<<dim3(10800), dim3(256), 0, stream>>>(S3, S5, S4);  // h3
  k_ydot<<<dim3(10800), dim3(256), 0, stream>>>(S4, out_w, out_b, Y);
  k_softmax48<<<dim3(4), dim3(256), 0, stream>>>(Y, OUT);
}